// Round 11
// baseline (584.718 us; speedup 1.0000x reference)
//
#include <hip/hip_runtime.h>
#include <hip/hip_bf16.h>

typedef short bf16x8 __attribute__((ext_vector_type(8)));
typedef float f32x4 __attribute__((ext_vector_type(4)));

__device__ inline float lrelu(float x) { return x > 0.f ? x : 0.2f * x; }

// fp32 -> bf16 (round-to-nearest-even)
__device__ inline unsigned short f2bf(float f) {
    unsigned u = __float_as_uint(f);
    u = u + 0x7FFFu + ((u >> 16) & 1u);
    return (unsigned short)(u >> 16);
}

// ---------- fold attention vectors through W: Walr[k][2H] ----------
__global__ void fold_attn(const float* __restrict__ W, const float* __restrict__ al,
                          const float* __restrict__ ar, float* __restrict__ Walr,
                          int H, int D) {
    int k = blockIdx.x;
    int lane = threadIdx.x;
    int C = H * D;
    for (int h = 0; h < H; ++h) {
        float sl = 0.f, sr = 0.f;
        for (int d = lane; d < D; d += 64) {
            float w = W[(size_t)k * C + h * D + d];
            sl += w * al[h * D + d];
            sr += w * ar[h * D + d];
        }
        for (int off = 32; off; off >>= 1) {
            sl += __shfl_down(sl, off);
            sr += __shfl_down(sr, off);
        }
        if (lane == 0) {
            Walr[k * 2 * H + h] = sl;
            Walr[k * 2 * H + H + h] = sr;
        }
    }
}

// ---------- el/er: THREAD per node. Walr is wave-uniform -> SGPR operands; ----------
// inner loop is pure v_fma. (round-11 fix: wave-per-node shuffle version spent
// 120 serial cross-lane ops per node; 64us -> expect ~5us.)
template <int H>
__global__ __launch_bounds__(256) void attn_node(const float* __restrict__ in,
                                                 const float* __restrict__ Walr,
                                                 float* __restrict__ el,
                                                 float* __restrict__ er, int N) {
    const int H2 = 2 * H;
    int stride = gridDim.x * blockDim.x;
    for (int n = blockIdx.x * blockDim.x + threadIdx.x; n < N; n += stride) {
        float acc[H2];
#pragma unroll
        for (int h = 0; h < H2; ++h) acc[h] = 0.f;
        const float* xr = in + (size_t)n * 64;
#pragma unroll
        for (int k4 = 0; k4 < 16; ++k4) {
            float4 xv = *reinterpret_cast<const float4*>(xr + k4 * 4);
#pragma unroll
            for (int h = 0; h < H2; ++h) {
                acc[h] += xv.x * Walr[(k4 * 4 + 0) * H2 + h]
                        + xv.y * Walr[(k4 * 4 + 1) * H2 + h]
                        + xv.z * Walr[(k4 * 4 + 2) * H2 + h]
                        + xv.w * Walr[(k4 * 4 + 3) * H2 + h];
            }
        }
#pragma unroll
        for (int h = 0; h < H; ++h) el[(size_t)n * H + h] = acc[h];
#pragma unroll
        for (int h = 0; h < H; ++h) er[(size_t)n * H + h] = acc[H + h];
    }
}

// ---------- CSR build ----------
__global__ void count_deg(const int* __restrict__ dst, int* __restrict__ deg, int E) {
    int stride = gridDim.x * blockDim.x;
    for (int i = blockIdx.x * blockDim.x + threadIdx.x; i < E; i += stride)
        atomicAdd(&deg[dst[i]], 1);
}

// ---------- hierarchical exclusive scan ----------
__global__ __launch_bounds__(256) void scan_local(const int* __restrict__ deg,
                                                  int* __restrict__ rowptr,
                                                  int* __restrict__ bsum, int N) {
    __shared__ int wsum[4];
    int t = threadIdx.x;
    int base = blockIdx.x * 2048 + t * 8;
    int v[8];
    int s = 0;
#pragma unroll
    for (int i = 0; i < 8; ++i) {
        int idx = base + i;
        v[i] = (idx < N) ? deg[idx] : 0;
        s += v[i];
    }
    int lane = t & 63, w = t >> 6;
    int incl = s;
    for (int off = 1; off < 64; off <<= 1) {
        int o = __shfl_up(incl, off);
        if (lane >= off) incl += o;
    }
    if (lane == 63) wsum[w] = incl;
    __syncthreads();
    int woff = 0;
    for (int i = 0; i < w; ++i) woff += wsum[i];
    int run = woff + incl - s;
#pragma unroll
    for (int i = 0; i < 8; ++i) {
        int idx = base + i;
        if (idx < N) rowptr[idx] = run;
        run += v[i];
    }
    if (t == 255) bsum[blockIdx.x] = woff + incl;
}

__global__ void scan_bsum(int* __restrict__ bsum, int* __restrict__ rowptrN, int nb) {
    int t = threadIdx.x;  // 64 threads
    int v = (t < nb) ? bsum[t] : 0;
    int incl = v;
    for (int off = 1; off < 64; off <<= 1) {
        int o = __shfl_up(incl, off);
        if (t >= off) incl += o;
    }
    if (t < nb) bsum[t] = incl - v;
    if (t == 63) *rowptrN = incl;
}

__global__ __launch_bounds__(256) void scan_add(int* __restrict__ rowptr,
                                                const int* __restrict__ bsum, int N) {
    int off = bsum[blockIdx.x];
    if (off == 0) return;
    int base = blockIdx.x * 2048 + threadIdx.x * 8;
#pragma unroll
    for (int i = 0; i < 8; ++i) {
        int idx = base + i;
        if (idx < N) rowptr[idx] += off;
    }
}

__global__ void fill_adj(const int* __restrict__ src, const int* __restrict__ dst,
                         int* __restrict__ cursor, int* __restrict__ adj,
                         int* __restrict__ dslot, int E) {
    int stride = gridDim.x * blockDim.x;
    for (int i = blockIdx.x * blockDim.x + threadIdx.x; i < E; i += stride) {
        int d = dst[i];
        int pos = atomicAdd(&cursor[d], 1);
        adj[pos] = src[i];
        dslot[pos] = d;
    }
}

// ---------- graph segment boundaries from SORTED gid ----------
__global__ void gstart_build(const int* __restrict__ gid, int* __restrict__ gstart,
                             int N, int NG) {
    int stride = gridDim.x * blockDim.x;
    for (int n = blockIdx.x * blockDim.x + threadIdx.x; n < N; n += stride) {
        int gcur = gid[n];
        int gprev = (n == 0) ? -1 : gid[n - 1];
        for (int g = gprev + 1; g <= gcur; ++g) gstart[g] = n;
        if (n == N - 1)
            for (int g = gcur + 1; g <= NG; ++g) gstart[g] = N;
    }
}

// ---------- per-slot raw attention logits ----------
template <int H>
__global__ void edge_e(const int* __restrict__ adj, const int* __restrict__ dslot,
                       const float* __restrict__ el, const float* __restrict__ er,
                       float* __restrict__ e, int E) {
    int stride = gridDim.x * blockDim.x;
    for (int i = blockIdx.x * blockDim.x + threadIdx.x; i < E; i += stride) {
        int s = adj[i], d = dslot[i];
        const float* els = el + (size_t)s * H;
        const float* erd = er + (size_t)d * H;
#pragma unroll
        for (int h = 0; h < H; ++h)
            e[(size_t)i * H + h] = lrelu(els[h] + erd[h]);
    }
}

// ---------- per-node softmax normalize ----------
template <int H>
__global__ void node_norm(const int* __restrict__ rowptr, const float* __restrict__ e,
                          float* __restrict__ alpha, int N) {
    int stride = gridDim.x * blockDim.x;
    for (int n = blockIdx.x * blockDim.x + threadIdx.x; n < N; n += stride) {
        int rbeg = rowptr[n], rend = rowptr[n + 1];
        if (rbeg == rend) continue;
        float m[H], den[H];
#pragma unroll
        for (int h = 0; h < H; ++h) { m[h] = -INFINITY; den[h] = 0.f; }
        for (int j = rbeg; j < rend; ++j) {
#pragma unroll
            for (int h = 0; h < H; ++h) {
                float ev = e[(size_t)j * H + h];
                float newm = fmaxf(m[h], ev);
                den[h] = den[h] * __expf(m[h] - newm) + __expf(ev - newm);
                m[h] = newm;
            }
        }
        float inv[H];
#pragma unroll
        for (int h = 0; h < H; ++h) inv[h] = 1.f / fmaxf(den[h], 1e-9f);
        for (int j = rbeg; j < rend; ++j) {
#pragma unroll
            for (int h = 0; h < H; ++h)
                alpha[(size_t)j * H + h] = __expf(e[(size_t)j * H + h] - m[h]) * inv[h];
        }
    }
}

// ---------- gather RAW input rows weighted by alpha ----------
template <int H>
__global__ __launch_bounds__(256, 8) void gather_z(
        const int* __restrict__ rowptr, const int* __restrict__ adj,
        const float* __restrict__ alpha, const float* __restrict__ x,
        float* __restrict__ z, int N) {
    int lane = threadIdx.x & 63;
    int w = threadIdx.x >> 6;
    int wpb = blockDim.x >> 6;
    int wstride = gridDim.x * wpb;
    for (int n = blockIdx.x * wpb + w; n < N; n += wstride) {
        int rbeg = __builtin_amdgcn_readfirstlane(rowptr[n]);
        int rend = __builtin_amdgcn_readfirstlane(rowptr[n + 1]);
        float acc[H];
#pragma unroll
        for (int h = 0; h < H; ++h) acc[h] = 0.f;
        for (int j = rbeg; j < rend; ++j) {
            int s = __builtin_amdgcn_readfirstlane(adj[j]);
            float xv = x[(size_t)s * 64 + lane];
            const float* al = alpha + (size_t)j * H;
#pragma unroll
            for (int h = 0; h < H; ++h) acc[h] += al[h] * xv;
        }
#pragma unroll
        for (int h = 0; h < H; ++h)
            z[(size_t)n * (H * 64) + h * 64 + lane] = acc[h];
    }
}

// ---------- pack W[64][C] into per-lane bf16 MFMA B-fragments ----------
__global__ void prep_wfrag(const float* __restrict__ W, unsigned short* __restrict__ F,
                           int C) {
    int total = (C >> 4) * 1024;
    int stride = gridDim.x * blockDim.x;
    for (int idx = blockIdx.x * blockDim.x + threadIdx.x; idx < total; idx += stride) {
        int j = idx & 7;
        int lane = (idx >> 3) & 63;
        int step = (idx >> 9) & 1;
        int CT = idx >> 10;
        int k = ((lane >> 4) << 3) + j + (step << 5);
        int col = (CT << 4) + (lane & 15);
        F[idx] = f2bf(W[(size_t)k * C + col]);
    }
}

// ---------- MFMA per-head projection + relu + head-sum ----------
template <int H>
__global__ __launch_bounds__(256) void gemm_heads_mfma(
        const float* __restrict__ z, const bf16x8* __restrict__ Wf,
        const float* __restrict__ bias, float* __restrict__ out, int N) {
    const int SA = H * 64;
    int lane = threadIdx.x & 63;
    int w = threadIdx.x >> 6;
    int row0 = blockIdx.x * 64 + w * 16;
    int arow = row0 + (lane & 15);
    if (arow > N - 1) arow = N - 1;
    int kb = (lane >> 4) * 8;
    int colL = lane & 15;

    f32x4 o0 = {0,0,0,0}, o1 = {0,0,0,0}, o2 = {0,0,0,0}, o3 = {0,0,0,0};

    for (int h = 0; h < H; ++h) {
        const float* zr = z + (size_t)arow * SA + h * 64 + kb;
        float4 a0 = *reinterpret_cast<const float4*>(zr);
        float4 a1 = *reinterpret_cast<const float4*>(zr + 4);
        float4 a2 = *reinterpret_cast<const float4*>(zr + 32);
        float4 a3 = *reinterpret_cast<const float4*>(zr + 36);
        bf16x8 A0, A1;
        A0[0] = (short)f2bf(a0.x); A0[1] = (short)f2bf(a0.y);
        A0[2] = (short)f2bf(a0.z); A0[3] = (short)f2bf(a0.w);
        A0[4] = (short)f2bf(a1.x); A0[5] = (short)f2bf(a1.y);
        A0[6] = (short)f2bf(a1.z); A0[7] = (short)f2bf(a1.w);
        A1[0] = (short)f2bf(a2.x); A1[1] = (short)f2bf(a2.y);
        A1[2] = (short)f2bf(a2.z); A1[3] = (short)f2bf(a2.w);
        A1[4] = (short)f2bf(a3.x); A1[5] = (short)f2bf(a3.y);
        A1[6] = (short)f2bf(a3.z); A1[7] = (short)f2bf(a3.w);

        f32x4 acc0 = {0,0,0,0}, acc1 = {0,0,0,0}, acc2 = {0,0,0,0}, acc3 = {0,0,0,0};
#define CT_STEP(accv, ct)                                                            \
        {                                                                            \
            bf16x8 B0 = Wf[((h * 4 + (ct)) * 2 + 0) * 64 + lane];                    \
            bf16x8 B1 = Wf[((h * 4 + (ct)) * 2 + 1) * 64 + lane];                    \
            accv = __builtin_amdgcn_mfma_f32_16x16x32_bf16(A0, B0, accv, 0, 0, 0);   \
            accv = __builtin_amdgcn_mfma_f32_16x16x32_bf16(A1, B1, accv, 0, 0, 0);   \
        }
        CT_STEP(acc0, 0) CT_STEP(acc1, 1) CT_STEP(acc2, 2) CT_STEP(acc3, 3)
#undef CT_STEP

#define EPI(ov, accv, ct)                                                            \
        {                                                                            \
            float bv = bias[h * 64 + (ct) * 16 + colL];                              \
            ov[0] += fmaxf(accv[0] + bv, 0.f);                                       \
            ov[1] += fmaxf(accv[1] + bv, 0.f);                                       \
            ov[2] += fmaxf(accv[2] + bv, 0.f);                                       \
            ov[3] += fmaxf(accv[3] + bv, 0.f);                                       \
        }
        EPI(o0, acc0, 0) EPI(o1, acc1, 1) EPI(o2, acc2, 2) EPI(o3, acc3, 3)
#undef EPI
    }

    int rbase = row0 + (lane >> 4) * 4;
#define ST(ov, ct)                                                                   \
    {                                                                                \
        _Pragma("unroll")                                                            \
        for (int r = 0; r < 4; ++r) {                                                \
            int row = rbase + r;                                                     \
            if (row < N) out[(size_t)row * 64 + (ct) * 16 + colL] = ov[r];           \
        }                                                                            \
    }
    ST(o0, 0) ST(o1, 1) ST(o2, 2) ST(o3, 3)
#undef ST
}

// ---------- MFMA layer-2 GEMM: rst2 = relu(z2[N,64] @ W2[64,128] + bias) ----------
__global__ __launch_bounds__(256) void gemm_relu_mfma(
        const float* __restrict__ z, const bf16x8* __restrict__ Wf,
        const float* __restrict__ bias, float* __restrict__ out, int N) {
    int lane = threadIdx.x & 63;
    int w = threadIdx.x >> 6;
    int row0 = blockIdx.x * 64 + w * 16;
    int arow = row0 + (lane & 15);
    if (arow > N - 1) arow = N - 1;
    int kb = (lane >> 4) * 8;
    int colL = lane & 15;

    const float* zr = z + (size_t)arow * 64 + kb;
    float4 a0 = *reinterpret_cast<const float4*>(zr);
    float4 a1 = *reinterpret_cast<const float4*>(zr + 4);
    float4 a2 = *reinterpret_cast<const float4*>(zr + 32);
    float4 a3 = *reinterpret_cast<const float4*>(zr + 36);
    bf16x8 A0, A1;
    A0[0] = (short)f2bf(a0.x); A0[1] = (short)f2bf(a0.y);
    A0[2] = (short)f2bf(a0.z); A0[3] = (short)f2bf(a0.w);
    A0[4] = (short)f2bf(a1.x); A0[5] = (short)f2bf(a1.y);
    A0[6] = (short)f2bf(a1.z); A0[7] = (short)f2bf(a1.w);
    A1[0] = (short)f2bf(a2.x); A1[1] = (short)f2bf(a2.y);
    A1[2] = (short)f2bf(a2.z); A1[3] = (short)f2bf(a2.w);
    A1[4] = (short)f2bf(a3.x); A1[5] = (short)f2bf(a3.y);
    A1[6] = (short)f2bf(a3.z); A1[7] = (short)f2bf(a3.w);

    int rbase = row0 + (lane >> 4) * 4;
#define DO_CT(ct)                                                                    \
    {                                                                                \
        bf16x8 B0 = Wf[((ct) * 2 + 0) * 64 + lane];                                  \
        bf16x8 B1 = Wf[((ct) * 2 + 1) * 64 + lane];                                  \
        f32x4 acc = {0, 0, 0, 0};                                                    \
        acc = __builtin_amdgcn_mfma_f32_16x16x32_bf16(A0, B0, acc, 0, 0, 0);         \
        acc = __builtin_amdgcn_mfma_f32_16x16x32_bf16(A1, B1, acc, 0, 0, 0);         \
        float bv = bias[(ct) * 16 + colL];                                           \
        _Pragma("unroll")                                                            \
        for (int r = 0; r < 4; ++r) {                                                \
            int row = rbase + r;                                                     \
            if (row < N)                                                             \
                out[(size_t)row * 128 + (ct) * 16 + colL] = fmaxf(acc[r] + bv, 0.f); \
        }                                                                            \
    }
    DO_CT(0) DO_CT(1) DO_CT(2) DO_CT(3) DO_CT(4) DO_CT(5) DO_CT(6) DO_CT(7)
#undef DO_CT
}

// ---------- per-graph column max, no atomics ----------
__global__ __launch_bounds__(128) void graph_max(const float* __restrict__ rst2,
                                                 const int* __restrict__ gstart,
                                                 float* __restrict__ gm) {
    int g = blockIdx.x, sp = blockIdx.y;
    int t = threadIdx.x;
    int rb = gstart[g], re = gstart[g + 1];
    float m = -INFINITY;
    for (int r = rb + sp; r < re; r += 8)
        m = fmaxf(m, rst2[(size_t)r * 128 + t]);
    gm[(size_t)sp * 4096 + g * 128 + t] = m;
}

// ---------- head MLP ----------
__global__ void mlp_head(const float* __restrict__ gml, const float* __restrict__ gmr,
                         const float* __restrict__ W1, const float* __restrict__ b1,
                         const float* __restrict__ W2, const float* __restrict__ b2,
                         float* __restrict__ out) {
    __shared__ float hcat[32][256];
    __shared__ float h[32][128];
    int t = threadIdx.x;
    for (int i = t; i < 32 * 128; i += 256) {
        int r = i / 128, c = i % 128;
        float ml = -INFINITY, mr = -INFINITY;
#pragma unroll
        for (int sp = 0; sp < 8; ++sp) {
            ml = fmaxf(ml, gml[sp * 4096 + i]);
            mr = fmaxf(mr, gmr[sp * 4096 + i]);
        }
        hcat[r][c] = fmaxf(ml, 0.f);
        hcat[r][128 + c] = fmaxf(mr, 0.f);
    }
    __syncthreads();
    for (int i = t; i < 32 * 128; i += 256) {
        int r = i / 128, c = i % 128;
        float acc = b1[c];
        for (int k = 0; k < 256; ++k) acc += hcat[r][k] * W1[k * 128 + c];
        h[r][c] = acc > 0.f ? acc : 0.f;
    }
    __syncthreads();
    if (t < 32) {
        float acc = b2[0];
        for (int k = 0; k < 128; ++k) acc += h[t][k] * W2[k];
        out[t] = acc > 0.f ? acc : 0.f;
    }
}

// ---------- launch ----------
static inline unsigned nblk_elem(long long total) {
    long long b = (total + 255) / 256;
    if (b > 65535) b = 65535;
    if (b < 1) b = 1;
    return (unsigned)b;
}
static inline unsigned nblk_gather(long long nodes) {
    long long b = (nodes + 3) / 4;
    if (b > 65535) b = 65535;
    if (b < 1) b = 1;
    return (unsigned)b;
}

extern "C" void kernel_launch(void* const* d_in, const int* in_sizes, int n_in,
                              void* d_out, int out_size, void* d_ws, size_t ws_size,
                              hipStream_t stream) {
    const float* lig_x = (const float*)d_in[0];
    const int* lig_src = (const int*)d_in[1];
    const int* lig_dst = (const int*)d_in[2];
    const int* lig_gid = (const int*)d_in[3];
    const float* rec_x = (const float*)d_in[4];
    const int* rec_src = (const int*)d_in[5];
    const int* rec_dst = (const int*)d_in[6];
    const int* rec_gid = (const int*)d_in[7];
    const float* W1l = (const float*)d_in[8];
    const float* al1l = (const float*)d_in[9];
    const float* ar1l = (const float*)d_in[10];
    const float* b1l = (const float*)d_in[11];
    const float* W2l = (const float*)d_in[12];
    const float* al2l = (const float*)d_in[13];
    const float* ar2l = (const float*)d_in[14];
    const float* b2l = (const float*)d_in[15];
    const float* W1r = (const float*)d_in[16];
    const float* al1r = (const float*)d_in[17];
    const float* ar1r = (const float*)d_in[18];
    const float* b1r = (const float*)d_in[19];
    const float* W2r = (const float*)d_in[20];
    const float* al2r = (const float*)d_in[21];
    const float* ar2r = (const float*)d_in[22];
    const float* b2r = (const float*)d_in[23];
    const float* Wlin1 = (const float*)d_in[24];
    const float* blin1 = (const float*)d_in[25];
    const float* Wlin2 = (const float*)d_in[26];
    const float* blin2 = (const float*)d_in[27];

    int Nl = in_sizes[0] / 64, El = in_sizes[1];
    int Nr = in_sizes[4] / 64, Er = in_sizes[5];
    long long Nmax = Nl > Nr ? Nl : Nr;
    long long Emax = El > Er ? El : Er;

    // workspace layout
    char* ws = (char*)d_ws;
    float* z = (float*)ws;           ws += Nmax * 640 * 4;
    float* h1 = (float*)ws;          ws += Nmax * 64 * 4;
    float* elb = (float*)ws;         ws += Nmax * 10 * 4;
    float* erb = (float*)ws;         ws += Nmax * 10 * 4;
    int* deg = (int*)ws;             ws += Nmax * 4;
    int* cursor = (int*)ws;          ws += Nmax * 4;
    int* rowptr = (int*)ws;          ws += (Nmax + 1) * 4;
    int* adj = (int*)ws;             ws += Emax * 4;
    int* dslot = (int*)ws;           ws += Emax * 4;
    float* ebuf = (float*)ws;        ws += Emax * 10 * 4;
    float* alpha = (float*)ws;       ws += Emax * 10 * 4;
    float* gml = (float*)ws;         ws += 8 * 32 * 128 * 4;
    float* gmr = (float*)ws;         ws += 8 * 32 * 128 * 4;
    float* Walr = (float*)ws;        ws += 64 * 32 * 4;
    int* gstart = (int*)ws;          ws += 40 * 4;
    int* bsum = (int*)ws;            ws += 64 * 4;
    unsigned short* wf1 = (unsigned short*)ws;  ws += 40960 * 2;
    unsigned short* wf2 = (unsigned short*)ws;  ws += 8192 * 2;
    float* z2 = z;                    // [N,64]
    float* rst2 = z + Nmax * 64;      // [N,128]

    auto run_branch = [&](const float* x, const int* src, const int* dst, const int* gid,
                          const float* W1, const float* al1, const float* ar1, const float* b1,
                          const float* W2, const float* al2, const float* ar2, const float* b2,
                          float* gm, int N, int E) {
        int nb = (N + 2047) / 2048;
        // CSR + graph boundaries + weight fragments
        hipMemsetAsync(deg, 0, (size_t)N * 4, stream);
        count_deg<<<nblk_elem(E), 256, 0, stream>>>(dst, deg, E);
        scan_local<<<nb, 256, 0, stream>>>(deg, rowptr, bsum, N);
        scan_bsum<<<1, 64, 0, stream>>>(bsum, rowptr + N, nb);
        scan_add<<<nb, 256, 0, stream>>>(rowptr, bsum, N);
        hipMemcpyAsync(cursor, rowptr, (size_t)N * 4, hipMemcpyDeviceToDevice, stream);
        fill_adj<<<nblk_elem(E), 256, 0, stream>>>(src, dst, cursor, adj, dslot, E);
        gstart_build<<<nblk_elem(N), 256, 0, stream>>>(gid, gstart, N, 32);
        prep_wfrag<<<40, 256, 0, stream>>>(W1, wf1, 640);
        prep_wfrag<<<8, 256, 0, stream>>>(W2, wf2, 128);

        // ---- layer 1: H=10, aggregate x then project (MFMA) ----
        fold_attn<<<64, 64, 0, stream>>>(W1, al1, ar1, Walr, 10, 64);
        attn_node<10><<<nblk_elem(N), 256, 0, stream>>>(x, Walr, elb, erb, N);
        edge_e<10><<<nblk_elem(E), 256, 0, stream>>>(adj, dslot, elb, erb, ebuf, E);
        node_norm<10><<<nblk_elem(N), 256, 0, stream>>>(rowptr, ebuf, alpha, N);
        gather_z<10><<<nblk_gather(N), 256, 0, stream>>>(rowptr, adj, alpha, x, z, N);
        gemm_heads_mfma<10><<<(N + 63) / 64, 256, 0, stream>>>(z, (const bf16x8*)wf1, b1, h1, N);

        // ---- layer 2: H=1, aggregate h1 then project (MFMA), atomic-free graph max ----
        fold_attn<<<64, 64, 0, stream>>>(W2, al2, ar2, Walr, 1, 128);
        attn_node<1><<<nblk_elem(N), 256, 0, stream>>>(h1, Walr, elb, erb, N);
        edge_e<1><<<nblk_elem(E), 256, 0, stream>>>(adj, dslot, elb, erb, ebuf, E);
        node_norm<1><<<nblk_elem(N), 256, 0, stream>>>(rowptr, ebuf, alpha, N);
        gather_z<1><<<nblk_gather(N), 256, 0, stream>>>(rowptr, adj, alpha, h1, z2, N);
        gemm_relu_mfma<<<(N + 63) / 64, 256, 0, stream>>>(z2, (const bf16x8*)wf2, b2, rst2, N);
        graph_max<<<dim3(32, 8), 128, 0, stream>>>(rst2, gstart, gm);
    };

    run_branch(lig_x, lig_src, lig_dst, lig_gid, W1l, al1l, ar1l, b1l, W2l, al2l, ar2l, b2l,
               gml, Nl, El);
    run_branch(rec_x, rec_src, rec_dst, rec_gid, W1r, al1r, ar1r, b1r, W2r, al2r, ar2r, b2r,
               gmr, Nr, Er);

    mlp_head<<<1, 256, 0, stream>>>(gml, gmr, Wlin1, blin1, Wlin2, blin2, (float*)d_out);
}

// Round 12
// 502.741 us; speedup vs baseline: 1.1631x; 1.1631x over previous
//
#include <hip/hip_runtime.h>
#include <hip/hip_bf16.h>

typedef short bf16x8 __attribute__((ext_vector_type(8)));
typedef float f32x4 __attribute__((ext_vector_type(4)));

__device__ inline float lrelu(float x) { return x > 0.f ? x : 0.2f * x; }

// fp32 -> bf16 (round-to-nearest-even)
__device__ inline unsigned short f2bf(float f) {
    unsigned u = __float_as_uint(f);
    u = u + 0x7FFFu + ((u >> 16) & 1u);
    return (unsigned short)(u >> 16);
}

// ---------- fold attention vectors through W: Walr[k][2H] ----------
__global__ void fold_attn(const float* __restrict__ W, const float* __restrict__ al,
                          const float* __restrict__ ar, float* __restrict__ Walr,
                          int H, int D) {
    int k = blockIdx.x;
    int lane = threadIdx.x;
    int C = H * D;
    for (int h = 0; h < H; ++h) {
        float sl = 0.f, sr = 0.f;
        for (int d = lane; d < D; d += 64) {
            float w = W[(size_t)k * C + h * D + d];
            sl += w * al[h * D + d];
            sr += w * ar[h * D + d];
        }
        for (int off = 32; off; off >>= 1) {
            sl += __shfl_down(sl, off);
            sr += __shfl_down(sr, off);
        }
        if (lane == 0) {
            Walr[k * 2 * H + h] = sl;
            Walr[k * 2 * H + H + h] = sr;
        }
    }
}

// ---------- pack Walr[64][C2] into bf16 MFMA B-fragments, zero-pad cols to 16 ----------
// same k-mapping as prep_wfrag (verified by round-9 MFMA GEMMs).
__global__ void prep_walr(const float* __restrict__ Walr, unsigned short* __restrict__ F,
                          int C2) {
    int NCT = (C2 + 15) / 16;
    int total = NCT * 1024;
    int stride = gridDim.x * blockDim.x;
    for (int idx = blockIdx.x * blockDim.x + threadIdx.x; idx < total; idx += stride) {
        int j = idx & 7;
        int lane = (idx >> 3) & 63;
        int step = (idx >> 9) & 1;
        int CT = idx >> 10;
        int k = ((lane >> 4) << 3) + j + (step << 5);
        int col = (CT << 4) + (lane & 15);
        F[idx] = (col < C2) ? f2bf(Walr[k * C2 + col]) : 0;
    }
}

// ---------- el/er via MFMA: x[N,64] @ Walr[64,2H] (round-12 fix) ----------
// round-11 attn_node was latency-bound (serialized Walr loads, 115us); this
// reuses the verified MFMA fragment pattern. ~2-4 MFMAs per wave, no LDS.
template <int H>
__global__ __launch_bounds__(256) void attn_mfma(const float* __restrict__ x,
                                                 const bf16x8* __restrict__ Wf,
                                                 float* __restrict__ el,
                                                 float* __restrict__ er, int N) {
    const int NCT = (2 * H + 15) / 16;
    int lane = threadIdx.x & 63;
    int w = threadIdx.x >> 6;
    int row0 = blockIdx.x * 64 + w * 16;
    int arow = row0 + (lane & 15);
    if (arow > N - 1) arow = N - 1;
    int kb = (lane >> 4) * 8;
    int colL = lane & 15;

    const float* xr = x + (size_t)arow * 64 + kb;
    float4 a0 = *reinterpret_cast<const float4*>(xr);
    float4 a1 = *reinterpret_cast<const float4*>(xr + 4);
    float4 a2 = *reinterpret_cast<const float4*>(xr + 32);
    float4 a3 = *reinterpret_cast<const float4*>(xr + 36);
    bf16x8 A0, A1;
    A0[0] = (short)f2bf(a0.x); A0[1] = (short)f2bf(a0.y);
    A0[2] = (short)f2bf(a0.z); A0[3] = (short)f2bf(a0.w);
    A0[4] = (short)f2bf(a1.x); A0[5] = (short)f2bf(a1.y);
    A0[6] = (short)f2bf(a1.z); A0[7] = (short)f2bf(a1.w);
    A1[0] = (short)f2bf(a2.x); A1[1] = (short)f2bf(a2.y);
    A1[2] = (short)f2bf(a2.z); A1[3] = (short)f2bf(a2.w);
    A1[4] = (short)f2bf(a3.x); A1[5] = (short)f2bf(a3.y);
    A1[6] = (short)f2bf(a3.z); A1[7] = (short)f2bf(a3.w);

    int rbase = row0 + (lane >> 4) * 4;
#pragma unroll
    for (int ct = 0; ct < NCT; ++ct) {
        bf16x8 B0 = Wf[(ct * 2 + 0) * 64 + lane];
        bf16x8 B1 = Wf[(ct * 2 + 1) * 64 + lane];
        f32x4 acc = {0, 0, 0, 0};
        acc = __builtin_amdgcn_mfma_f32_16x16x32_bf16(A0, B0, acc, 0, 0, 0);
        acc = __builtin_amdgcn_mfma_f32_16x16x32_bf16(A1, B1, acc, 0, 0, 0);
        int col = ct * 16 + colL;
#pragma unroll
        for (int r = 0; r < 4; ++r) {
            int row = rbase + r;
            if (row < N) {
                if (col < H) el[(size_t)row * H + col] = acc[r];
                else if (col < 2 * H) er[(size_t)row * H + col - H] = acc[r];
            }
        }
    }
}

// ---------- CSR build ----------
__global__ void count_deg(const int* __restrict__ dst, int* __restrict__ deg, int E) {
    int stride = gridDim.x * blockDim.x;
    for (int i = blockIdx.x * blockDim.x + threadIdx.x; i < E; i += stride)
        atomicAdd(&deg[dst[i]], 1);
}

// ---------- hierarchical exclusive scan ----------
__global__ __launch_bounds__(256) void scan_local(const int* __restrict__ deg,
                                                  int* __restrict__ rowptr,
                                                  int* __restrict__ bsum, int N) {
    __shared__ int wsum[4];
    int t = threadIdx.x;
    int base = blockIdx.x * 2048 + t * 8;
    int v[8];
    int s = 0;
#pragma unroll
    for (int i = 0; i < 8; ++i) {
        int idx = base + i;
        v[i] = (idx < N) ? deg[idx] : 0;
        s += v[i];
    }
    int lane = t & 63, w = t >> 6;
    int incl = s;
    for (int off = 1; off < 64; off <<= 1) {
        int o = __shfl_up(incl, off);
        if (lane >= off) incl += o;
    }
    if (lane == 63) wsum[w] = incl;
    __syncthreads();
    int woff = 0;
    for (int i = 0; i < w; ++i) woff += wsum[i];
    int run = woff + incl - s;
#pragma unroll
    for (int i = 0; i < 8; ++i) {
        int idx = base + i;
        if (idx < N) rowptr[idx] = run;
        run += v[i];
    }
    if (t == 255) bsum[blockIdx.x] = woff + incl;
}

__global__ void scan_bsum(int* __restrict__ bsum, int* __restrict__ rowptrN, int nb) {
    int t = threadIdx.x;  // 64 threads
    int v = (t < nb) ? bsum[t] : 0;
    int incl = v;
    for (int off = 1; off < 64; off <<= 1) {
        int o = __shfl_up(incl, off);
        if (t >= off) incl += o;
    }
    if (t < nb) bsum[t] = incl - v;
    if (t == 63) *rowptrN = incl;
}

__global__ __launch_bounds__(256) void scan_add(int* __restrict__ rowptr,
                                                const int* __restrict__ bsum, int N) {
    int off = bsum[blockIdx.x];
    if (off == 0) return;
    int base = blockIdx.x * 2048 + threadIdx.x * 8;
#pragma unroll
    for (int i = 0; i < 8; ++i) {
        int idx = base + i;
        if (idx < N) rowptr[idx] += off;
    }
}

__global__ void fill_adj(const int* __restrict__ src, const int* __restrict__ dst,
                         int* __restrict__ cursor, int* __restrict__ adj,
                         int* __restrict__ dslot, int E) {
    int stride = gridDim.x * blockDim.x;
    for (int i = blockIdx.x * blockDim.x + threadIdx.x; i < E; i += stride) {
        int d = dst[i];
        int pos = atomicAdd(&cursor[d], 1);
        adj[pos] = src[i];
        dslot[pos] = d;
    }
}

// ---------- graph segment boundaries from SORTED gid ----------
__global__ void gstart_build(const int* __restrict__ gid, int* __restrict__ gstart,
                             int N, int NG) {
    int stride = gridDim.x * blockDim.x;
    for (int n = blockIdx.x * blockDim.x + threadIdx.x; n < N; n += stride) {
        int gcur = gid[n];
        int gprev = (n == 0) ? -1 : gid[n - 1];
        for (int g = gprev + 1; g <= gcur; ++g) gstart[g] = n;
        if (n == N - 1)
            for (int g = gcur + 1; g <= NG; ++g) gstart[g] = N;
    }
}

// ---------- per-slot raw attention logits ----------
template <int H>
__global__ void edge_e(const int* __restrict__ adj, const int* __restrict__ dslot,
                       const float* __restrict__ el, const float* __restrict__ er,
                       float* __restrict__ e, int E) {
    int stride = gridDim.x * blockDim.x;
    for (int i = blockIdx.x * blockDim.x + threadIdx.x; i < E; i += stride) {
        int s = adj[i], d = dslot[i];
        const float* els = el + (size_t)s * H;
        const float* erd = er + (size_t)d * H;
#pragma unroll
        for (int h = 0; h < H; ++h)
            e[(size_t)i * H + h] = lrelu(els[h] + erd[h]);
    }
}

// ---------- per-node softmax normalize ----------
template <int H>
__global__ void node_norm(const int* __restrict__ rowptr, const float* __restrict__ e,
                          float* __restrict__ alpha, int N) {
    int stride = gridDim.x * blockDim.x;
    for (int n = blockIdx.x * blockDim.x + threadIdx.x; n < N; n += stride) {
        int rbeg = rowptr[n], rend = rowptr[n + 1];
        if (rbeg == rend) continue;
        float m[H], den[H];
#pragma unroll
        for (int h = 0; h < H; ++h) { m[h] = -INFINITY; den[h] = 0.f; }
        for (int j = rbeg; j < rend; ++j) {
#pragma unroll
            for (int h = 0; h < H; ++h) {
                float ev = e[(size_t)j * H + h];
                float newm = fmaxf(m[h], ev);
                den[h] = den[h] * __expf(m[h] - newm) + __expf(ev - newm);
                m[h] = newm;
            }
        }
        float inv[H];
#pragma unroll
        for (int h = 0; h < H; ++h) inv[h] = 1.f / fmaxf(den[h], 1e-9f);
        for (int j = rbeg; j < rend; ++j) {
#pragma unroll
            for (int h = 0; h < H; ++h)
                alpha[(size_t)j * H + h] = __expf(e[(size_t)j * H + h] - m[h]) * inv[h];
        }
    }
}

// ---------- gather RAW input rows weighted by alpha ----------
template <int H>
__global__ __launch_bounds__(256, 8) void gather_z(
        const int* __restrict__ rowptr, const int* __restrict__ adj,
        const float* __restrict__ alpha, const float* __restrict__ x,
        float* __restrict__ z, int N) {
    int lane = threadIdx.x & 63;
    int w = threadIdx.x >> 6;
    int wpb = blockDim.x >> 6;
    int wstride = gridDim.x * wpb;
    for (int n = blockIdx.x * wpb + w; n < N; n += wstride) {
        int rbeg = __builtin_amdgcn_readfirstlane(rowptr[n]);
        int rend = __builtin_amdgcn_readfirstlane(rowptr[n + 1]);
        float acc[H];
#pragma unroll
        for (int h = 0; h < H; ++h) acc[h] = 0.f;
        for (int j = rbeg; j < rend; ++j) {
            int s = __builtin_amdgcn_readfirstlane(adj[j]);
            float xv = x[(size_t)s * 64 + lane];
            const float* al = alpha + (size_t)j * H;
#pragma unroll
            for (int h = 0; h < H; ++h) acc[h] += al[h] * xv;
        }
#pragma unroll
        for (int h = 0; h < H; ++h)
            z[(size_t)n * (H * 64) + h * 64 + lane] = acc[h];
    }
}

// ---------- pack W[64][C] into per-lane bf16 MFMA B-fragments ----------
__global__ void prep_wfrag(const float* __restrict__ W, unsigned short* __restrict__ F,
                           int C) {
    int total = (C >> 4) * 1024;
    int stride = gridDim.x * blockDim.x;
    for (int idx = blockIdx.x * blockDim.x + threadIdx.x; idx < total; idx += stride) {
        int j = idx & 7;
        int lane = (idx >> 3) & 63;
        int step = (idx >> 9) & 1;
        int CT = idx >> 10;
        int k = ((lane >> 4) << 3) + j + (step << 5);
        int col = (CT << 4) + (lane & 15);
        F[idx] = f2bf(W[(size_t)k * C + col]);
    }
}

// ---------- MFMA per-head projection + relu + head-sum ----------
template <int H>
__global__ __launch_bounds__(256) void gemm_heads_mfma(
        const float* __restrict__ z, const bf16x8* __restrict__ Wf,
        const float* __restrict__ bias, float* __restrict__ out, int N) {
    const int SA = H * 64;
    int lane = threadIdx.x & 63;
    int w = threadIdx.x >> 6;
    int row0 = blockIdx.x * 64 + w * 16;
    int arow = row0 + (lane & 15);
    if (arow > N - 1) arow = N - 1;
    int kb = (lane >> 4) * 8;
    int colL = lane & 15;

    f32x4 o0 = {0,0,0,0}, o1 = {0,0,0,0}, o2 = {0,0,0,0}, o3 = {0,0,0,0};

    for (int h = 0; h < H; ++h) {
        const float* zr = z + (size_t)arow * SA + h * 64 + kb;
        float4 a0 = *reinterpret_cast<const float4*>(zr);
        float4 a1 = *reinterpret_cast<const float4*>(zr + 4);
        float4 a2 = *reinterpret_cast<const float4*>(zr + 32);
        float4 a3 = *reinterpret_cast<const float4*>(zr + 36);
        bf16x8 A0, A1;
        A0[0] = (short)f2bf(a0.x); A0[1] = (short)f2bf(a0.y);
        A0[2] = (short)f2bf(a0.z); A0[3] = (short)f2bf(a0.w);
        A0[4] = (short)f2bf(a1.x); A0[5] = (short)f2bf(a1.y);
        A0[6] = (short)f2bf(a1.z); A0[7] = (short)f2bf(a1.w);
        A1[0] = (short)f2bf(a2.x); A1[1] = (short)f2bf(a2.y);
        A1[2] = (short)f2bf(a2.z); A1[3] = (short)f2bf(a2.w);
        A1[4] = (short)f2bf(a3.x); A1[5] = (short)f2bf(a3.y);
        A1[6] = (short)f2bf(a3.z); A1[7] = (short)f2bf(a3.w);

        f32x4 acc0 = {0,0,0,0}, acc1 = {0,0,0,0}, acc2 = {0,0,0,0}, acc3 = {0,0,0,0};
#define CT_STEP(accv, ct)                                                            \
        {                                                                            \
            bf16x8 B0 = Wf[((h * 4 + (ct)) * 2 + 0) * 64 + lane];                    \
            bf16x8 B1 = Wf[((h * 4 + (ct)) * 2 + 1) * 64 + lane];                    \
            accv = __builtin_amdgcn_mfma_f32_16x16x32_bf16(A0, B0, accv, 0, 0, 0);   \
            accv = __builtin_amdgcn_mfma_f32_16x16x32_bf16(A1, B1, accv, 0, 0, 0);   \
        }
        CT_STEP(acc0, 0) CT_STEP(acc1, 1) CT_STEP(acc2, 2) CT_STEP(acc3, 3)
#undef CT_STEP

#define EPI(ov, accv, ct)                                                            \
        {                                                                            \
            float bv = bias[h * 64 + (ct) * 16 + colL];                              \
            ov[0] += fmaxf(accv[0] + bv, 0.f);                                       \
            ov[1] += fmaxf(accv[1] + bv, 0.f);                                       \
            ov[2] += fmaxf(accv[2] + bv, 0.f);                                       \
            ov[3] += fmaxf(accv[3] + bv, 0.f);                                       \
        }
        EPI(o0, acc0, 0) EPI(o1, acc1, 1) EPI(o2, acc2, 2) EPI(o3, acc3, 3)
#undef EPI
    }

    int rbase = row0 + (lane >> 4) * 4;
#define ST(ov, ct)                                                                   \
    {                                                                                \
        _Pragma("unroll")                                                            \
        for (int r = 0; r < 4; ++r) {                                                \
            int row = rbase + r;                                                     \
            if (row < N) out[(size_t)row * 64 + (ct) * 16 + colL] = ov[r];           \
        }                                                                            \
    }
    ST(o0, 0) ST(o1, 1) ST(o2, 2) ST(o3, 3)
#undef ST
}

// ---------- MFMA layer-2 GEMM: rst2 = relu(z2[N,64] @ W2[64,128] + bias) ----------
__global__ __launch_bounds__(256) void gemm_relu_mfma(
        const float* __restrict__ z, const bf16x8* __restrict__ Wf,
        const float* __restrict__ bias, float* __restrict__ out, int N) {
    int lane = threadIdx.x & 63;
    int w = threadIdx.x >> 6;
    int row0 = blockIdx.x * 64 + w * 16;
    int arow = row0 + (lane & 15);
    if (arow > N - 1) arow = N - 1;
    int kb = (lane >> 4) * 8;
    int colL = lane & 15;

    const float* zr = z + (size_t)arow * 64 + kb;
    float4 a0 = *reinterpret_cast<const float4*>(zr);
    float4 a1 = *reinterpret_cast<const float4*>(zr + 4);
    float4 a2 = *reinterpret_cast<const float4*>(zr + 32);
    float4 a3 = *reinterpret_cast<const float4*>(zr + 36);
    bf16x8 A0, A1;
    A0[0] = (short)f2bf(a0.x); A0[1] = (short)f2bf(a0.y);
    A0[2] = (short)f2bf(a0.z); A0[3] = (short)f2bf(a0.w);
    A0[4] = (short)f2bf(a1.x); A0[5] = (short)f2bf(a1.y);
    A0[6] = (short)f2bf(a1.z); A0[7] = (short)f2bf(a1.w);
    A1[0] = (short)f2bf(a2.x); A1[1] = (short)f2bf(a2.y);
    A1[2] = (short)f2bf(a2.z); A1[3] = (short)f2bf(a2.w);
    A1[4] = (short)f2bf(a3.x); A1[5] = (short)f2bf(a3.y);
    A1[6] = (short)f2bf(a3.z); A1[7] = (short)f2bf(a3.w);

    int rbase = row0 + (lane >> 4) * 4;
#define DO_CT(ct)                                                                    \
    {                                                                                \
        bf16x8 B0 = Wf[((ct) * 2 + 0) * 64 + lane];                                  \
        bf16x8 B1 = Wf[((ct) * 2 + 1) * 64 + lane];                                  \
        f32x4 acc = {0, 0, 0, 0};                                                    \
        acc = __builtin_amdgcn_mfma_f32_16x16x32_bf16(A0, B0, acc, 0, 0, 0);         \
        acc = __builtin_amdgcn_mfma_f32_16x16x32_bf16(A1, B1, acc, 0, 0, 0);         \
        float bv = bias[(ct) * 16 + colL];                                           \
        _Pragma("unroll")                                                            \
        for (int r = 0; r < 4; ++r) {                                                \
            int row = rbase + r;                                                     \
            if (row < N)                                                             \
                out[(size_t)row * 128 + (ct) * 16 + colL] = fmaxf(acc[r] + bv, 0.f); \
        }                                                                            \
    }
    DO_CT(0) DO_CT(1) DO_CT(2) DO_CT(3) DO_CT(4) DO_CT(5) DO_CT(6) DO_CT(7)
#undef DO_CT
}

// ---------- per-graph column max, no atomics ----------
__global__ __launch_bounds__(128) void graph_max(const float* __restrict__ rst2,
                                                 const int* __restrict__ gstart,
                                                 float* __restrict__ gm) {
    int g = blockIdx.x, sp = blockIdx.y;
    int t = threadIdx.x;
    int rb = gstart[g], re = gstart[g + 1];
    float m = -INFINITY;
    for (int r = rb + sp; r < re; r += 8)
        m = fmaxf(m, rst2[(size_t)r * 128 + t]);
    gm[(size_t)sp * 4096 + g * 128 + t] = m;
}

// ---------- head MLP ----------
__global__ void mlp_head(const float* __restrict__ gml, const float* __restrict__ gmr,
                         const float* __restrict__ W1, const float* __restrict__ b1,
                         const float* __restrict__ W2, const float* __restrict__ b2,
                         float* __restrict__ out) {
    __shared__ float hcat[32][256];
    __shared__ float h[32][128];
    int t = threadIdx.x;
    for (int i = t; i < 32 * 128; i += 256) {
        int r = i / 128, c = i % 128;
        float ml = -INFINITY, mr = -INFINITY;
#pragma unroll
        for (int sp = 0; sp < 8; ++sp) {
            ml = fmaxf(ml, gml[sp * 4096 + i]);
            mr = fmaxf(mr, gmr[sp * 4096 + i]);
        }
        hcat[r][c] = fmaxf(ml, 0.f);
        hcat[r][128 + c] = fmaxf(mr, 0.f);
    }
    __syncthreads();
    for (int i = t; i < 32 * 128; i += 256) {
        int r = i / 128, c = i % 128;
        float acc = b1[c];
        for (int k = 0; k < 256; ++k) acc += hcat[r][k] * W1[k * 128 + c];
        h[r][c] = acc > 0.f ? acc : 0.f;
    }
    __syncthreads();
    if (t < 32) {
        float acc = b2[0];
        for (int k = 0; k < 128; ++k) acc += h[t][k] * W2[k];
        out[t] = acc > 0.f ? acc : 0.f;
    }
}

// ---------- launch ----------
static inline unsigned nblk_elem(long long total) {
    long long b = (total + 255) / 256;
    if (b > 65535) b = 65535;
    if (b < 1) b = 1;
    return (unsigned)b;
}
static inline unsigned nblk_gather(long long nodes) {
    long long b = (nodes + 3) / 4;
    if (b > 65535) b = 65535;
    if (b < 1) b = 1;
    return (unsigned)b;
}

extern "C" void kernel_launch(void* const* d_in, const int* in_sizes, int n_in,
                              void* d_out, int out_size, void* d_ws, size_t ws_size,
                              hipStream_t stream) {
    const float* lig_x = (const float*)d_in[0];
    const int* lig_src = (const int*)d_in[1];
    const int* lig_dst = (const int*)d_in[2];
    const int* lig_gid = (const int*)d_in[3];
    const float* rec_x = (const float*)d_in[4];
    const int* rec_src = (const int*)d_in[5];
    const int* rec_dst = (const int*)d_in[6];
    const int* rec_gid = (const int*)d_in[7];
    const float* W1l = (const float*)d_in[8];
    const float* al1l = (const float*)d_in[9];
    const float* ar1l = (const float*)d_in[10];
    const float* b1l = (const float*)d_in[11];
    const float* W2l = (const float*)d_in[12];
    const float* al2l = (const float*)d_in[13];
    const float* ar2l = (const float*)d_in[14];
    const float* b2l = (const float*)d_in[15];
    const float* W1r = (const float*)d_in[16];
    const float* al1r = (const float*)d_in[17];
    const float* ar1r = (const float*)d_in[18];
    const float* b1r = (const float*)d_in[19];
    const float* W2r = (const float*)d_in[20];
    const float* al2r = (const float*)d_in[21];
    const float* ar2r = (const float*)d_in[22];
    const float* b2r = (const float*)d_in[23];
    const float* Wlin1 = (const float*)d_in[24];
    const float* blin1 = (const float*)d_in[25];
    const float* Wlin2 = (const float*)d_in[26];
    const float* blin2 = (const float*)d_in[27];

    int Nl = in_sizes[0] / 64, El = in_sizes[1];
    int Nr = in_sizes[4] / 64, Er = in_sizes[5];
    long long Nmax = Nl > Nr ? Nl : Nr;
    long long Emax = El > Er ? El : Er;

    // workspace layout
    char* ws = (char*)d_ws;
    float* z = (float*)ws;           ws += Nmax * 640 * 4;
    float* h1 = (float*)ws;          ws += Nmax * 64 * 4;
    float* elb = (float*)ws;         ws += Nmax * 10 * 4;
    float* erb = (float*)ws;         ws += Nmax * 10 * 4;
    int* deg = (int*)ws;             ws += Nmax * 4;
    int* cursor = (int*)ws;          ws += Nmax * 4;
    int* rowptr = (int*)ws;          ws += (Nmax + 1) * 4;
    int* adj = (int*)ws;             ws += Emax * 4;
    int* dslot = (int*)ws;           ws += Emax * 4;
    float* ebuf = (float*)ws;        ws += Emax * 10 * 4;
    float* alpha = (float*)ws;       ws += Emax * 10 * 4;
    float* gml = (float*)ws;         ws += 8 * 32 * 128 * 4;
    float* gmr = (float*)ws;         ws += 8 * 32 * 128 * 4;
    float* Walr = (float*)ws;        ws += 64 * 32 * 4;
    int* gstart = (int*)ws;          ws += 40 * 4;
    int* bsum = (int*)ws;            ws += 64 * 4;
    unsigned short* wf1 = (unsigned short*)ws;  ws += 40960 * 2;
    unsigned short* wf2 = (unsigned short*)ws;  ws += 8192 * 2;
    unsigned short* wfa = (unsigned short*)ws;  ws += 2048 * 2;  // Walr fragments
    float* z2 = z;                    // [N,64]
    float* rst2 = z + Nmax * 64;      // [N,128]

    auto run_branch = [&](const float* x, const int* src, const int* dst, const int* gid,
                          const float* W1, const float* al1, const float* ar1, const float* b1,
                          const float* W2, const float* al2, const float* ar2, const float* b2,
                          float* gm, int N, int E) {
        int nb = (N + 2047) / 2048;
        // CSR + graph boundaries + weight fragments
        hipMemsetAsync(deg, 0, (size_t)N * 4, stream);
        count_deg<<<nblk_elem(E), 256, 0, stream>>>(dst, deg, E);
        scan_local<<<nb, 256, 0, stream>>>(deg, rowptr, bsum, N);
        scan_bsum<<<1, 64, 0, stream>>>(bsum, rowptr + N, nb);
        scan_add<<<nb, 256, 0, stream>>>(rowptr, bsum, N);
        hipMemcpyAsync(cursor, rowptr, (size_t)N * 4, hipMemcpyDeviceToDevice, stream);
        fill_adj<<<nblk_elem(E), 256, 0, stream>>>(src, dst, cursor, adj, dslot, E);
        gstart_build<<<nblk_elem(N), 256, 0, stream>>>(gid, gstart, N, 32);
        prep_wfrag<<<40, 256, 0, stream>>>(W1, wf1, 640);
        prep_wfrag<<<8, 256, 0, stream>>>(W2, wf2, 128);

        // ---- layer 1: H=10, aggregate x then project (MFMA) ----
        fold_attn<<<64, 64, 0, stream>>>(W1, al1, ar1, Walr, 10, 64);
        prep_walr<<<8, 256, 0, stream>>>(Walr, wfa, 20);
        attn_mfma<10><<<(N + 63) / 64, 256, 0, stream>>>(x, (const bf16x8*)wfa, elb, erb, N);
        edge_e<10><<<nblk_elem(E), 256, 0, stream>>>(adj, dslot, elb, erb, ebuf, E);
        node_norm<10><<<nblk_elem(N), 256, 0, stream>>>(rowptr, ebuf, alpha, N);
        gather_z<10><<<nblk_gather(N), 256, 0, stream>>>(rowptr, adj, alpha, x, z, N);
        gemm_heads_mfma<10><<<(N + 63) / 64, 256, 0, stream>>>(z, (const bf16x8*)wf1, b1, h1, N);

        // ---- layer 2: H=1, aggregate h1 then project (MFMA), atomic-free graph max ----
        fold_attn<<<64, 64, 0, stream>>>(W2, al2, ar2, Walr, 1, 128);
        prep_walr<<<4, 256, 0, stream>>>(Walr, wfa, 2);
        attn_mfma<1><<<(N + 63) / 64, 256, 0, stream>>>(h1, (const bf16x8*)wfa, elb, erb, N);
        edge_e<1><<<nblk_elem(E), 256, 0, stream>>>(adj, dslot, elb, erb, ebuf, E);
        node_norm<1><<<nblk_elem(N), 256, 0, stream>>>(rowptr, ebuf, alpha, N);
        gather_z<1><<<nblk_gather(N), 256, 0, stream>>>(rowptr, adj, alpha, h1, z2, N);
        gemm_relu_mfma<<<(N + 63) / 64, 256, 0, stream>>>(z2, (const bf16x8*)wf2, b2, rst2, N);
        graph_max<<<dim3(32, 8), 128, 0, stream>>>(rst2, gstart, gm);
    };

    run_branch(lig_x, lig_src, lig_dst, lig_gid, W1l, al1l, ar1l, b1l, W2l, al2l, ar2l, b2l,
               gml, Nl, El);
    run_branch(rec_x, rec_src, rec_dst, rec_gid, W1r, al1r, ar1r, b1r, W2r, al2r, ar2r, b2r,
               gmr, Nr, Er);

    mlp_head<<<1, 256, 0, stream>>>(gml, gmr, Wlin1, blin1, Wlin2, blin2, (float*)d_out);
}

// Round 13
// 461.360 us; speedup vs baseline: 1.2674x; 1.0897x over previous
//
#include <hip/hip_runtime.h>
#include <hip/hip_bf16.h>

typedef short bf16x8 __attribute__((ext_vector_type(8)));
typedef float f32x4 __attribute__((ext_vector_type(4)));

__device__ inline float lrelu(float x) { return x > 0.f ? x : 0.2f * x; }

// fp32 -> bf16 (round-to-nearest-even)
__device__ inline unsigned short f2bf(float f) {
    unsigned u = __float_as_uint(f);
    u = u + 0x7FFFu + ((u >> 16) & 1u);
    return (unsigned short)(u >> 16);
}

// ---------- fold attention vectors through W: Walr[k][2H] ----------
__global__ void fold_attn(const float* __restrict__ W, const float* __restrict__ al,
                          const float* __restrict__ ar, float* __restrict__ Walr,
                          int H, int D) {
    int k = blockIdx.x;
    int lane = threadIdx.x;
    int C = H * D;
    for (int h = 0; h < H; ++h) {
        float sl = 0.f, sr = 0.f;
        for (int d = lane; d < D; d += 64) {
            float w = W[(size_t)k * C + h * D + d];
            sl += w * al[h * D + d];
            sr += w * ar[h * D + d];
        }
        for (int off = 32; off; off >>= 1) {
            sl += __shfl_down(sl, off);
            sr += __shfl_down(sr, off);
        }
        if (lane == 0) {
            Walr[k * 2 * H + h] = sl;
            Walr[k * 2 * H + H + h] = sr;
        }
    }
}

// ---------- pack Walr[64][C2] into bf16 MFMA B-fragments, zero-pad cols to 16 ----------
__global__ void prep_walr(const float* __restrict__ Walr, unsigned short* __restrict__ F,
                          int C2) {
    int NCT = (C2 + 15) / 16;
    int total = NCT * 1024;
    int stride = gridDim.x * blockDim.x;
    for (int idx = blockIdx.x * blockDim.x + threadIdx.x; idx < total; idx += stride) {
        int j = idx & 7;
        int lane = (idx >> 3) & 63;
        int step = (idx >> 9) & 1;
        int CT = idx >> 10;
        int k = ((lane >> 4) << 3) + j + (step << 5);
        int col = (CT << 4) + (lane & 15);
        F[idx] = (col < C2) ? f2bf(Walr[k * C2 + col]) : 0;
    }
}

// ---------- el/er via MFMA: x[N,64] @ Walr[64,2H] ----------
template <int H>
__global__ __launch_bounds__(256) void attn_mfma(const float* __restrict__ x,
                                                 const bf16x8* __restrict__ Wf,
                                                 float* __restrict__ el,
                                                 float* __restrict__ er, int N) {
    const int NCT = (2 * H + 15) / 16;
    int lane = threadIdx.x & 63;
    int w = threadIdx.x >> 6;
    int row0 = blockIdx.x * 64 + w * 16;
    int arow = row0 + (lane & 15);
    if (arow > N - 1) arow = N - 1;
    int kb = (lane >> 4) * 8;
    int colL = lane & 15;

    const float* xr = x + (size_t)arow * 64 + kb;
    float4 a0 = *reinterpret_cast<const float4*>(xr);
    float4 a1 = *reinterpret_cast<const float4*>(xr + 4);
    float4 a2 = *reinterpret_cast<const float4*>(xr + 32);
    float4 a3 = *reinterpret_cast<const float4*>(xr + 36);
    bf16x8 A0, A1;
    A0[0] = (short)f2bf(a0.x); A0[1] = (short)f2bf(a0.y);
    A0[2] = (short)f2bf(a0.z); A0[3] = (short)f2bf(a0.w);
    A0[4] = (short)f2bf(a1.x); A0[5] = (short)f2bf(a1.y);
    A0[6] = (short)f2bf(a1.z); A0[7] = (short)f2bf(a1.w);
    A1[0] = (short)f2bf(a2.x); A1[1] = (short)f2bf(a2.y);
    A1[2] = (short)f2bf(a2.z); A1[3] = (short)f2bf(a2.w);
    A1[4] = (short)f2bf(a3.x); A1[5] = (short)f2bf(a3.y);
    A1[6] = (short)f2bf(a3.z); A1[7] = (short)f2bf(a3.w);

    int rbase = row0 + (lane >> 4) * 4;
#pragma unroll
    for (int ct = 0; ct < NCT; ++ct) {
        bf16x8 B0 = Wf[(ct * 2 + 0) * 64 + lane];
        bf16x8 B1 = Wf[(ct * 2 + 1) * 64 + lane];
        f32x4 acc = {0, 0, 0, 0};
        acc = __builtin_amdgcn_mfma_f32_16x16x32_bf16(A0, B0, acc, 0, 0, 0);
        acc = __builtin_amdgcn_mfma_f32_16x16x32_bf16(A1, B1, acc, 0, 0, 0);
        int col = ct * 16 + colL;
#pragma unroll
        for (int r = 0; r < 4; ++r) {
            int row = rbase + r;
            if (row < N) {
                if (col < H) el[(size_t)row * H + col] = acc[r];
                else if (col < 2 * H) er[(size_t)row * H + col - H] = acc[r];
            }
        }
    }
}

// ---------- CSR build ----------
__global__ void count_deg(const int* __restrict__ dst, int* __restrict__ deg, int E) {
    int stride = gridDim.x * blockDim.x;
    for (int i = blockIdx.x * blockDim.x + threadIdx.x; i < E; i += stride)
        atomicAdd(&deg[dst[i]], 1);
}

// ---------- hierarchical exclusive scan ----------
__global__ __launch_bounds__(256) void scan_local(const int* __restrict__ deg,
                                                  int* __restrict__ rowptr,
                                                  int* __restrict__ bsum, int N) {
    __shared__ int wsum[4];
    int t = threadIdx.x;
    int base = blockIdx.x * 2048 + t * 8;
    int v[8];
    int s = 0;
#pragma unroll
    for (int i = 0; i < 8; ++i) {
        int idx = base + i;
        v[i] = (idx < N) ? deg[idx] : 0;
        s += v[i];
    }
    int lane = t & 63, w = t >> 6;
    int incl = s;
    for (int off = 1; off < 64; off <<= 1) {
        int o = __shfl_up(incl, off);
        if (lane >= off) incl += o;
    }
    if (lane == 63) wsum[w] = incl;
    __syncthreads();
    int woff = 0;
    for (int i = 0; i < w; ++i) woff += wsum[i];
    int run = woff + incl - s;
#pragma unroll
    for (int i = 0; i < 8; ++i) {
        int idx = base + i;
        if (idx < N) rowptr[idx] = run;
        run += v[i];
    }
    if (t == 255) bsum[blockIdx.x] = woff + incl;
}

__global__ void scan_bsum(int* __restrict__ bsum, int* __restrict__ rowptrN, int nb) {
    int t = threadIdx.x;  // 64 threads
    int v = (t < nb) ? bsum[t] : 0;
    int incl = v;
    for (int off = 1; off < 64; off <<= 1) {
        int o = __shfl_up(incl, off);
        if (t >= off) incl += o;
    }
    if (t < nb) bsum[t] = incl - v;
    if (t == 63) *rowptrN = incl;
}

__global__ __launch_bounds__(256) void scan_add(int* __restrict__ rowptr,
                                                const int* __restrict__ bsum, int N) {
    int off = bsum[blockIdx.x];
    if (off == 0) return;
    int base = blockIdx.x * 2048 + threadIdx.x * 8;
#pragma unroll
    for (int i = 0; i < 8; ++i) {
        int idx = base + i;
        if (idx < N) rowptr[idx] += off;
    }
}

__global__ void fill_adj(const int* __restrict__ src, const int* __restrict__ dst,
                         int* __restrict__ cursor, int* __restrict__ adj,
                         int* __restrict__ dslot, int E) {
    int stride = gridDim.x * blockDim.x;
    for (int i = blockIdx.x * blockDim.x + threadIdx.x; i < E; i += stride) {
        int d = dst[i];
        int pos = atomicAdd(&cursor[d], 1);
        adj[pos] = src[i];
        dslot[pos] = d;
    }
}

// ---------- graph segment boundaries from SORTED gid ----------
__global__ void gstart_build(const int* __restrict__ gid, int* __restrict__ gstart,
                             int N, int NG) {
    int stride = gridDim.x * blockDim.x;
    for (int n = blockIdx.x * blockDim.x + threadIdx.x; n < N; n += stride) {
        int gcur = gid[n];
        int gprev = (n == 0) ? -1 : gid[n - 1];
        for (int g = gprev + 1; g <= gcur; ++g) gstart[g] = n;
        if (n == N - 1)
            for (int g = gcur + 1; g <= NG; ++g) gstart[g] = N;
    }
}

// ---------- per-slot raw attention logits ----------
template <int H>
__global__ void edge_e(const int* __restrict__ adj, const int* __restrict__ dslot,
                       const float* __restrict__ el, const float* __restrict__ er,
                       float* __restrict__ e, int E) {
    int stride = gridDim.x * blockDim.x;
    for (int i = blockIdx.x * blockDim.x + threadIdx.x; i < E; i += stride) {
        int s = adj[i], d = dslot[i];
        const float* els = el + (size_t)s * H;
        const float* erd = er + (size_t)d * H;
#pragma unroll
        for (int h = 0; h < H; ++h)
            e[(size_t)i * H + h] = lrelu(els[h] + erd[h]);
    }
}

// ---------- per-node softmax normalize ----------
template <int H>
__global__ void node_norm(const int* __restrict__ rowptr, const float* __restrict__ e,
                          float* __restrict__ alpha, int N) {
    int stride = gridDim.x * blockDim.x;
    for (int n = blockIdx.x * blockDim.x + threadIdx.x; n < N; n += stride) {
        int rbeg = rowptr[n], rend = rowptr[n + 1];
        if (rbeg == rend) continue;
        float m[H], den[H];
#pragma unroll
        for (int h = 0; h < H; ++h) { m[h] = -INFINITY; den[h] = 0.f; }
        for (int j = rbeg; j < rend; ++j) {
#pragma unroll
            for (int h = 0; h < H; ++h) {
                float ev = e[(size_t)j * H + h];
                float newm = fmaxf(m[h], ev);
                den[h] = den[h] * __expf(m[h] - newm) + __expf(ev - newm);
                m[h] = newm;
            }
        }
        float inv[H];
#pragma unroll
        for (int h = 0; h < H; ++h) inv[h] = 1.f / fmaxf(den[h], 1e-9f);
        for (int j = rbeg; j < rend; ++j) {
#pragma unroll
            for (int h = 0; h < H; ++h)
                alpha[(size_t)j * H + h] = __expf(e[(size_t)j * H + h] - m[h]) * inv[h];
        }
    }
}

// ---------- gather RAW input rows weighted by alpha ----------
template <int H>
__global__ __launch_bounds__(256, 8) void gather_z(
        const int* __restrict__ rowptr, const int* __restrict__ adj,
        const float* __restrict__ alpha, const float* __restrict__ x,
        float* __restrict__ z, int N) {
    int lane = threadIdx.x & 63;
    int w = threadIdx.x >> 6;
    int wpb = blockDim.x >> 6;
    int wstride = gridDim.x * wpb;
    for (int n = blockIdx.x * wpb + w; n < N; n += wstride) {
        int rbeg = __builtin_amdgcn_readfirstlane(rowptr[n]);
        int rend = __builtin_amdgcn_readfirstlane(rowptr[n + 1]);
        float acc[H];
#pragma unroll
        for (int h = 0; h < H; ++h) acc[h] = 0.f;
        for (int j = rbeg; j < rend; ++j) {
            int s = __builtin_amdgcn_readfirstlane(adj[j]);
            float xv = x[(size_t)s * 64 + lane];
            const float* al = alpha + (size_t)j * H;
#pragma unroll
            for (int h = 0; h < H; ++h) acc[h] += al[h] * xv;
        }
#pragma unroll
        for (int h = 0; h < H; ++h)
            z[(size_t)n * (H * 64) + h * 64 + lane] = acc[h];
    }
}

// ---------- pack W[64][C] into per-lane bf16 MFMA B-fragments ----------
__global__ void prep_wfrag(const float* __restrict__ W, unsigned short* __restrict__ F,
                           int C) {
    int total = (C >> 4) * 1024;
    int stride = gridDim.x * blockDim.x;
    for (int idx = blockIdx.x * blockDim.x + threadIdx.x; idx < total; idx += stride) {
        int j = idx & 7;
        int lane = (idx >> 3) & 63;
        int step = (idx >> 9) & 1;
        int CT = idx >> 10;
        int k = ((lane >> 4) << 3) + j + (step << 5);
        int col = (CT << 4) + (lane & 15);
        F[idx] = f2bf(W[(size_t)k * C + col]);
    }
}

// ---------- MFMA per-head projection + relu + head-sum ----------
template <int H>
__global__ __launch_bounds__(256) void gemm_heads_mfma(
        const float* __restrict__ z, const bf16x8* __restrict__ Wf,
        const float* __restrict__ bias, float* __restrict__ out, int N) {
    const int SA = H * 64;
    int lane = threadIdx.x & 63;
    int w = threadIdx.x >> 6;
    int row0 = blockIdx.x * 64 + w * 16;
    int arow = row0 + (lane & 15);
    if (arow > N - 1) arow = N - 1;
    int kb = (lane >> 4) * 8;
    int colL = lane & 15;

    f32x4 o0 = {0,0,0,0}, o1 = {0,0,0,0}, o2 = {0,0,0,0}, o3 = {0,0,0,0};

    for (int h = 0; h < H; ++h) {
        const float* zr = z + (size_t)arow * SA + h * 64 + kb;
        float4 a0 = *reinterpret_cast<const float4*>(zr);
        float4 a1 = *reinterpret_cast<const float4*>(zr + 4);
        float4 a2 = *reinterpret_cast<const float4*>(zr + 32);
        float4 a3 = *reinterpret_cast<const float4*>(zr + 36);
        bf16x8 A0, A1;
        A0[0] = (short)f2bf(a0.x); A0[1] = (short)f2bf(a0.y);
        A0[2] = (short)f2bf(a0.z); A0[3] = (short)f2bf(a0.w);
        A0[4] = (short)f2bf(a1.x); A0[5] = (short)f2bf(a1.y);
        A0[6] = (short)f2bf(a1.z); A0[7] = (short)f2bf(a1.w);
        A1[0] = (short)f2bf(a2.x); A1[1] = (short)f2bf(a2.y);
        A1[2] = (short)f2bf(a2.z); A1[3] = (short)f2bf(a2.w);
        A1[4] = (short)f2bf(a3.x); A1[5] = (short)f2bf(a3.y);
        A1[6] = (short)f2bf(a3.z); A1[7] = (short)f2bf(a3.w);

        f32x4 acc0 = {0,0,0,0}, acc1 = {0,0,0,0}, acc2 = {0,0,0,0}, acc3 = {0,0,0,0};
#define CT_STEP(accv, ct)                                                            \
        {                                                                            \
            bf16x8 B0 = Wf[((h * 4 + (ct)) * 2 + 0) * 64 + lane];                    \
            bf16x8 B1 = Wf[((h * 4 + (ct)) * 2 + 1) * 64 + lane];                    \
            accv = __builtin_amdgcn_mfma_f32_16x16x32_bf16(A0, B0, accv, 0, 0, 0);   \
            accv = __builtin_amdgcn_mfma_f32_16x16x32_bf16(A1, B1, accv, 0, 0, 0);   \
        }
        CT_STEP(acc0, 0) CT_STEP(acc1, 1) CT_STEP(acc2, 2) CT_STEP(acc3, 3)
#undef CT_STEP

#define EPI(ov, accv, ct)                                                            \
        {                                                                            \
            float bv = bias[h * 64 + (ct) * 16 + colL];                              \
            ov[0] += fmaxf(accv[0] + bv, 0.f);                                       \
            ov[1] += fmaxf(accv[1] + bv, 0.f);                                       \
            ov[2] += fmaxf(accv[2] + bv, 0.f);                                       \
            ov[3] += fmaxf(accv[3] + bv, 0.f);                                       \
        }
        EPI(o0, acc0, 0) EPI(o1, acc1, 1) EPI(o2, acc2, 2) EPI(o3, acc3, 3)
#undef EPI
    }

    int rbase = row0 + (lane >> 4) * 4;
#define ST(ov, ct)                                                                   \
    {                                                                                \
        _Pragma("unroll")                                                            \
        for (int r = 0; r < 4; ++r) {                                                \
            int row = rbase + r;                                                     \
            if (row < N) out[(size_t)row * 64 + (ct) * 16 + colL] = ov[r];           \
        }                                                                            \
    }
    ST(o0, 0) ST(o1, 1) ST(o2, 2) ST(o3, 3)
#undef ST
}

// ---------- MFMA layer-2 GEMM: rst2 = relu(z2[N,64] @ W2[64,128] + bias) ----------
__global__ __launch_bounds__(256) void gemm_relu_mfma(
        const float* __restrict__ z, const bf16x8* __restrict__ Wf,
        const float* __restrict__ bias, float* __restrict__ out, int N) {
    int lane = threadIdx.x & 63;
    int w = threadIdx.x >> 6;
    int row0 = blockIdx.x * 64 + w * 16;
    int arow = row0 + (lane & 15);
    if (arow > N - 1) arow = N - 1;
    int kb = (lane >> 4) * 8;
    int colL = lane & 15;

    const float* zr = z + (size_t)arow * 64 + kb;
    float4 a0 = *reinterpret_cast<const float4*>(zr);
    float4 a1 = *reinterpret_cast<const float4*>(zr + 4);
    float4 a2 = *reinterpret_cast<const float4*>(zr + 32);
    float4 a3 = *reinterpret_cast<const float4*>(zr + 36);
    bf16x8 A0, A1;
    A0[0] = (short)f2bf(a0.x); A0[1] = (short)f2bf(a0.y);
    A0[2] = (short)f2bf(a0.z); A0[3] = (short)f2bf(a0.w);
    A0[4] = (short)f2bf(a1.x); A0[5] = (short)f2bf(a1.y);
    A0[6] = (short)f2bf(a1.z); A0[7] = (short)f2bf(a1.w);
    A1[0] = (short)f2bf(a2.x); A1[1] = (short)f2bf(a2.y);
    A1[2] = (short)f2bf(a2.z); A1[3] = (short)f2bf(a2.w);
    A1[4] = (short)f2bf(a3.x); A1[5] = (short)f2bf(a3.y);
    A1[6] = (short)f2bf(a3.z); A1[7] = (short)f2bf(a3.w);

    int rbase = row0 + (lane >> 4) * 4;
#define DO_CT(ct)                                                                    \
    {                                                                                \
        bf16x8 B0 = Wf[((ct) * 2 + 0) * 64 + lane];                                  \
        bf16x8 B1 = Wf[((ct) * 2 + 1) * 64 + lane];                                  \
        f32x4 acc = {0, 0, 0, 0};                                                    \
        acc = __builtin_amdgcn_mfma_f32_16x16x32_bf16(A0, B0, acc, 0, 0, 0);         \
        acc = __builtin_amdgcn_mfma_f32_16x16x32_bf16(A1, B1, acc, 0, 0, 0);         \
        float bv = bias[(ct) * 16 + colL];                                           \
        _Pragma("unroll")                                                            \
        for (int r = 0; r < 4; ++r) {                                                \
            int row = rbase + r;                                                     \
            if (row < N)                                                             \
                out[(size_t)row * 128 + (ct) * 16 + colL] = fmaxf(acc[r] + bv, 0.f); \
        }                                                                            \
    }
    DO_CT(0) DO_CT(1) DO_CT(2) DO_CT(3) DO_CT(4) DO_CT(5) DO_CT(6) DO_CT(7)
#undef DO_CT
}

// ---------- per-graph column max, no atomics ----------
__global__ __launch_bounds__(128) void graph_max(const float* __restrict__ rst2,
                                                 const int* __restrict__ gstart,
                                                 float* __restrict__ gm) {
    int g = blockIdx.x, sp = blockIdx.y;
    int t = threadIdx.x;
    int rb = gstart[g], re = gstart[g + 1];
    float m = -INFINITY;
    for (int r = rb + sp; r < re; r += 8)
        m = fmaxf(m, rst2[(size_t)r * 128 + t]);
    gm[(size_t)sp * 4096 + g * 128 + t] = m;
}

// ---------- head MLP v2: one block PER GRAPH (round-13 fix: single-block version
// was latency-bound at 58us, 0.06% VALUBusy; 32 blocks hide W1 load latency) ----------
__global__ __launch_bounds__(256) void mlp_head2(
        const float* __restrict__ gml, const float* __restrict__ gmr,
        const float* __restrict__ W1, const float* __restrict__ b1,
        const float* __restrict__ W2, const float* __restrict__ b2,
        float* __restrict__ out) {
    __shared__ float hcat[256];
    __shared__ float part[256];
    __shared__ float h[128];
    int g = blockIdx.x;
    int t = threadIdx.x;
    // fold 8 graph-max partials; relu outputs >=0, so fmax(m,0) handles empty graphs
    {
        const float* gsrc = (t < 128) ? gml : gmr;
        int c = t & 127;
        float m = -INFINITY;
#pragma unroll
        for (int sp = 0; sp < 8; ++sp) m = fmaxf(m, gsrc[sp * 4096 + g * 128 + c]);
        hcat[t < 128 ? c : 128 + c] = fmaxf(m, 0.f);
    }
    __syncthreads();
    // fc1: thread t computes half of output column c = t&127 (k-range by t>>7)
    {
        int c = t & 127;
        int k0 = (t >> 7) << 7;
        float acc = 0.f;
#pragma unroll 4
        for (int k = 0; k < 128; ++k)
            acc += hcat[k0 + k] * W1[(size_t)(k0 + k) * 128 + c];
        part[t] = acc;
    }
    __syncthreads();
    if (t < 128) h[t] = fmaxf(part[t] + part[t + 128] + b1[t], 0.f);
    __syncthreads();
    // fc2: 128 products, 2-wave shuffle reduce
    if (t < 128) {
        float v = h[t] * W2[t];
        for (int off = 32; off; off >>= 1) v += __shfl_down(v, off);
        if ((t & 63) == 0) part[t >> 6] = v;
    }
    __syncthreads();
    if (t == 0) out[g] = fmaxf(part[0] + part[1] + b2[0], 0.f);
}

// ---------- launch ----------
static inline unsigned nblk_elem(long long total) {
    long long b = (total + 255) / 256;
    if (b > 65535) b = 65535;
    if (b < 1) b = 1;
    return (unsigned)b;
}
static inline unsigned nblk_gather(long long nodes) {
    long long b = (nodes + 3) / 4;
    if (b > 65535) b = 65535;
    if (b < 1) b = 1;
    return (unsigned)b;
}

extern "C" void kernel_launch(void* const* d_in, const int* in_sizes, int n_in,
                              void* d_out, int out_size, void* d_ws, size_t ws_size,
                              hipStream_t stream) {
    const float* lig_x = (const float*)d_in[0];
    const int* lig_src = (const int*)d_in[1];
    const int* lig_dst = (const int*)d_in[2];
    const int* lig_gid = (const int*)d_in[3];
    const float* rec_x = (const float*)d_in[4];
    const int* rec_src = (const int*)d_in[5];
    const int* rec_dst = (const int*)d_in[6];
    const int* rec_gid = (const int*)d_in[7];
    const float* W1l = (const float*)d_in[8];
    const float* al1l = (const float*)d_in[9];
    const float* ar1l = (const float*)d_in[10];
    const float* b1l = (const float*)d_in[11];
    const float* W2l = (const float*)d_in[12];
    const float* al2l = (const float*)d_in[13];
    const float* ar2l = (const float*)d_in[14];
    const float* b2l = (const float*)d_in[15];
    const float* W1r = (const float*)d_in[16];
    const float* al1r = (const float*)d_in[17];
    const float* ar1r = (const float*)d_in[18];
    const float* b1r = (const float*)d_in[19];
    const float* W2r = (const float*)d_in[20];
    const float* al2r = (const float*)d_in[21];
    const float* ar2r = (const float*)d_in[22];
    const float* b2r = (const float*)d_in[23];
    const float* Wlin1 = (const float*)d_in[24];
    const float* blin1 = (const float*)d_in[25];
    const float* Wlin2 = (const float*)d_in[26];
    const float* blin2 = (const float*)d_in[27];

    int Nl = in_sizes[0] / 64, El = in_sizes[1];
    int Nr = in_sizes[4] / 64, Er = in_sizes[5];
    long long Nmax = Nl > Nr ? Nl : Nr;
    long long Emax = El > Er ? El : Er;

    // workspace layout
    char* ws = (char*)d_ws;
    float* z = (float*)ws;           ws += Nmax * 640 * 4;
    float* h1 = (float*)ws;          ws += Nmax * 64 * 4;
    float* elb = (float*)ws;         ws += Nmax * 10 * 4;
    float* erb = (float*)ws;         ws += Nmax * 10 * 4;
    int* deg = (int*)ws;             ws += Nmax * 4;
    int* cursor = (int*)ws;          ws += Nmax * 4;
    int* rowptr = (int*)ws;          ws += (Nmax + 1) * 4;
    int* adj = (int*)ws;             ws += Emax * 4;
    int* dslot = (int*)ws;           ws += Emax * 4;
    float* ebuf = (float*)ws;        ws += Emax * 10 * 4;
    float* alpha = (float*)ws;       ws += Emax * 10 * 4;
    float* gml = (float*)ws;         ws += 8 * 32 * 128 * 4;
    float* gmr = (float*)ws;         ws += 8 * 32 * 128 * 4;
    float* Walr = (float*)ws;        ws += 64 * 32 * 4;
    int* gstart = (int*)ws;          ws += 40 * 4;
    int* bsum = (int*)ws;            ws += 64 * 4;
    unsigned short* wf1 = (unsigned short*)ws;  ws += 40960 * 2;
    unsigned short* wf2 = (unsigned short*)ws;  ws += 8192 * 2;
    unsigned short* wfa = (unsigned short*)ws;  ws += 2048 * 2;  // Walr fragments
    float* z2 = z;                    // [N,64]
    float* rst2 = z + Nmax * 64;      // [N,128]

    auto run_branch = [&](const float* x, const int* src, const int* dst, const int* gid,
                          const float* W1, const float* al1, const float* ar1, const float* b1,
                          const float* W2, const float* al2, const float* ar2, const float* b2,
                          float* gm, int N, int E) {
        int nb = (N + 2047) / 2048;
        // CSR + graph boundaries + weight fragments
        hipMemsetAsync(deg, 0, (size_t)N * 4, stream);
        count_deg<<<nblk_elem(E), 256, 0, stream>>>(dst, deg, E);
        scan_local<<<nb, 256, 0, stream>>>(deg, rowptr, bsum, N);
        scan_bsum<<<1, 64, 0, stream>>>(bsum, rowptr + N, nb);
        scan_add<<<nb, 256, 0, stream>>>(rowptr, bsum, N);
        hipMemcpyAsync(cursor, rowptr, (size_t)N * 4, hipMemcpyDeviceToDevice, stream);
        fill_adj<<<nblk_elem(E), 256, 0, stream>>>(src, dst, cursor, adj, dslot, E);
        gstart_build<<<nblk_elem(N), 256, 0, stream>>>(gid, gstart, N, 32);
        prep_wfrag<<<40, 256, 0, stream>>>(W1, wf1, 640);
        prep_wfrag<<<8, 256, 0, stream>>>(W2, wf2, 128);

        // ---- layer 1: H=10, aggregate x then project (MFMA) ----
        fold_attn<<<64, 64, 0, stream>>>(W1, al1, ar1, Walr, 10, 64);
        prep_walr<<<8, 256, 0, stream>>>(Walr, wfa, 20);
        attn_mfma<10><<<(N + 63) / 64, 256, 0, stream>>>(x, (const bf16x8*)wfa, elb, erb, N);
        edge_e<10><<<nblk_elem(E), 256, 0, stream>>>(adj, dslot, elb, erb, ebuf, E);
        node_norm<10><<<nblk_elem(N), 256, 0, stream>>>(rowptr, ebuf, alpha, N);
        gather_z<10><<<nblk_gather(N), 256, 0, stream>>>(rowptr, adj, alpha, x, z, N);
        gemm_heads_mfma<10><<<(N + 63) / 64, 256, 0, stream>>>(z, (const bf16x8*)wf1, b1, h1, N);

        // ---- layer 2: H=1, aggregate h1 then project (MFMA), atomic-free graph max ----
        fold_attn<<<64, 64, 0, stream>>>(W2, al2, ar2, Walr, 1, 128);
        prep_walr<<<4, 256, 0, stream>>>(Walr, wfa, 2);
        attn_mfma<1><<<(N + 63) / 64, 256, 0, stream>>>(h1, (const bf16x8*)wfa, elb, erb, N);
        edge_e<1><<<nblk_elem(E), 256, 0, stream>>>(adj, dslot, elb, erb, ebuf, E);
        node_norm<1><<<nblk_elem(N), 256, 0, stream>>>(rowptr, ebuf, alpha, N);
        gather_z<1><<<nblk_gather(N), 256, 0, stream>>>(rowptr, adj, alpha, h1, z2, N);
        gemm_relu_mfma<<<(N + 63) / 64, 256, 0, stream>>>(z2, (const bf16x8*)wf2, b2, rst2, N);
        graph_max<<<dim3(32, 8), 128, 0, stream>>>(rst2, gstart, gm);
    };

    run_branch(lig_x, lig_src, lig_dst, lig_gid, W1l, al1l, ar1l, b1l, W2l, al2l, ar2l, b2l,
               gml, Nl, El);
    run_branch(rec_x, rec_src, rec_dst, rec_gid, W1r, al1r, ar1r, b1r, W2r, al2r, ar2r, b2r,
               gmr, Nr, Er);

    mlp_head2<<<32, 256, 0, stream>>>(gml, gmr, Wlin1, blin1, Wlin2, blin2, (float*)d_out);
}

// Round 14
// 389.820 us; speedup vs baseline: 1.5000x; 1.1835x over previous
//
#include <hip/hip_runtime.h>
#include <hip/hip_bf16.h>

typedef short bf16x8 __attribute__((ext_vector_type(8)));
typedef float f32x4 __attribute__((ext_vector_type(4)));

__device__ inline float lrelu(float x) { return x > 0.f ? x : 0.2f * x; }

// fp32 -> bf16 (round-to-nearest-even)
__device__ inline unsigned short f2bf(float f) {
    unsigned u = __float_as_uint(f);
    u = u + 0x7FFFu + ((u >> 16) & 1u);
    return (unsigned short)(u >> 16);
}

// ---------- concat lig_x and rec_x into xcat ----------
__global__ void copy_x2(const float4* __restrict__ a, int na4,
                        const float4* __restrict__ b, int nb4, float4* __restrict__ o) {
    int total = na4 + nb4;
    int stride = gridDim.x * blockDim.x;
    for (int i = blockIdx.x * blockDim.x + threadIdx.x; i < total; i += stride)
        o[i] = (i < na4) ? a[i] : b[i - na4];
}

// ---------- fold attention vectors through W: Walr[k][2H] ----------
__global__ void fold_attn(const float* __restrict__ W, const float* __restrict__ al,
                          const float* __restrict__ ar, float* __restrict__ Walr,
                          int H, int D) {
    int k = blockIdx.x;
    int lane = threadIdx.x;
    int C = H * D;
    for (int h = 0; h < H; ++h) {
        float sl = 0.f, sr = 0.f;
        for (int d = lane; d < D; d += 64) {
            float w = W[(size_t)k * C + h * D + d];
            sl += w * al[h * D + d];
            sr += w * ar[h * D + d];
        }
        for (int off = 32; off; off >>= 1) {
            sl += __shfl_down(sl, off);
            sr += __shfl_down(sr, off);
        }
        if (lane == 0) {
            Walr[k * 2 * H + h] = sl;
            Walr[k * 2 * H + H + h] = sr;
        }
    }
}

// ---------- pack Walr[64][C2] into bf16 MFMA B-fragments, zero-pad cols to 16 ----------
__global__ void prep_walr(const float* __restrict__ Walr, unsigned short* __restrict__ F,
                          int C2) {
    int NCT = (C2 + 15) / 16;
    int total = NCT * 1024;
    int stride = gridDim.x * blockDim.x;
    for (int idx = blockIdx.x * blockDim.x + threadIdx.x; idx < total; idx += stride) {
        int j = idx & 7;
        int lane = (idx >> 3) & 63;
        int step = (idx >> 9) & 1;
        int CT = idx >> 10;
        int k = ((lane >> 4) << 3) + j + (step << 5);
        int col = (CT << 4) + (lane & 15);
        F[idx] = (col < C2) ? f2bf(Walr[k * C2 + col]) : 0;
    }
}

// ---------- el/er via MFMA: x[N,64] @ Walr[64,2H] ----------
template <int H>
__global__ __launch_bounds__(256) void attn_mfma(const float* __restrict__ x,
                                                 const bf16x8* __restrict__ Wf,
                                                 float* __restrict__ el,
                                                 float* __restrict__ er, int N) {
    const int NCT = (2 * H + 15) / 16;
    int lane = threadIdx.x & 63;
    int w = threadIdx.x >> 6;
    int row0 = blockIdx.x * 64 + w * 16;
    int arow = row0 + (lane & 15);
    if (arow > N - 1) arow = N - 1;
    int kb = (lane >> 4) * 8;
    int colL = lane & 15;

    const float* xr = x + (size_t)arow * 64 + kb;
    float4 a0 = *reinterpret_cast<const float4*>(xr);
    float4 a1 = *reinterpret_cast<const float4*>(xr + 4);
    float4 a2 = *reinterpret_cast<const float4*>(xr + 32);
    float4 a3 = *reinterpret_cast<const float4*>(xr + 36);
    bf16x8 A0, A1;
    A0[0] = (short)f2bf(a0.x); A0[1] = (short)f2bf(a0.y);
    A0[2] = (short)f2bf(a0.z); A0[3] = (short)f2bf(a0.w);
    A0[4] = (short)f2bf(a1.x); A0[5] = (short)f2bf(a1.y);
    A0[6] = (short)f2bf(a1.z); A0[7] = (short)f2bf(a1.w);
    A1[0] = (short)f2bf(a2.x); A1[1] = (short)f2bf(a2.y);
    A1[2] = (short)f2bf(a2.z); A1[3] = (short)f2bf(a2.w);
    A1[4] = (short)f2bf(a3.x); A1[5] = (short)f2bf(a3.y);
    A1[6] = (short)f2bf(a3.z); A1[7] = (short)f2bf(a3.w);

    int rbase = row0 + (lane >> 4) * 4;
#pragma unroll
    for (int ct = 0; ct < NCT; ++ct) {
        bf16x8 B0 = Wf[(ct * 2 + 0) * 64 + lane];
        bf16x8 B1 = Wf[(ct * 2 + 1) * 64 + lane];
        f32x4 acc = {0, 0, 0, 0};
        acc = __builtin_amdgcn_mfma_f32_16x16x32_bf16(A0, B0, acc, 0, 0, 0);
        acc = __builtin_amdgcn_mfma_f32_16x16x32_bf16(A1, B1, acc, 0, 0, 0);
        int col = ct * 16 + colL;
#pragma unroll
        for (int r = 0; r < 4; ++r) {
            int row = rbase + r;
            if (row < N) {
                if (col < H) el[(size_t)row * H + col] = acc[r];
                else if (col < 2 * H) er[(size_t)row * H + col - H] = acc[r];
            }
        }
    }
}

// ---------- CSR build over the DISJOINT UNION graph (rec ids offset by Nl) ----------
__global__ void count_deg2(const int* __restrict__ dl, const int* __restrict__ dr,
                           int* __restrict__ deg, int El, int Er, int Nl) {
    int total = El + Er;
    int stride = gridDim.x * blockDim.x;
    for (int i = blockIdx.x * blockDim.x + threadIdx.x; i < total; i += stride) {
        int d = (i < El) ? dl[i] : (dr[i - El] + Nl);
        atomicAdd(&deg[d], 1);
    }
}

__global__ __launch_bounds__(256) void scan_local(const int* __restrict__ deg,
                                                  int* __restrict__ rowptr,
                                                  int* __restrict__ bsum, int N) {
    __shared__ int wsum[4];
    int t = threadIdx.x;
    int base = blockIdx.x * 2048 + t * 8;
    int v[8];
    int s = 0;
#pragma unroll
    for (int i = 0; i < 8; ++i) {
        int idx = base + i;
        v[i] = (idx < N) ? deg[idx] : 0;
        s += v[i];
    }
    int lane = t & 63, w = t >> 6;
    int incl = s;
    for (int off = 1; off < 64; off <<= 1) {
        int o = __shfl_up(incl, off);
        if (lane >= off) incl += o;
    }
    if (lane == 63) wsum[w] = incl;
    __syncthreads();
    int woff = 0;
    for (int i = 0; i < w; ++i) woff += wsum[i];
    int run = woff + incl - s;
#pragma unroll
    for (int i = 0; i < 8; ++i) {
        int idx = base + i;
        if (idx < N) rowptr[idx] = run;
        run += v[i];
    }
    if (t == 255) bsum[blockIdx.x] = woff + incl;
}

__global__ void scan_bsum(int* __restrict__ bsum, int* __restrict__ rowptrN, int nb) {
    int t = threadIdx.x;  // 64 threads
    int v = (t < nb) ? bsum[t] : 0;
    int incl = v;
    for (int off = 1; off < 64; off <<= 1) {
        int o = __shfl_up(incl, off);
        if (t >= off) incl += o;
    }
    if (t < nb) bsum[t] = incl - v;
    if (t == 63) *rowptrN = incl;
}

__global__ __launch_bounds__(256) void scan_add(int* __restrict__ rowptr,
                                                const int* __restrict__ bsum, int N) {
    int off = bsum[blockIdx.x];
    if (off == 0) return;
    int base = blockIdx.x * 2048 + threadIdx.x * 8;
#pragma unroll
    for (int i = 0; i < 8; ++i) {
        int idx = base + i;
        if (idx < N) rowptr[idx] += off;
    }
}

__global__ void fill_adj2(const int* __restrict__ sl, const int* __restrict__ dl,
                          const int* __restrict__ sr, const int* __restrict__ dr,
                          int* __restrict__ cursor, int* __restrict__ adj,
                          int* __restrict__ dslot, int El, int Er, int Nl) {
    int total = El + Er;
    int stride = gridDim.x * blockDim.x;
    for (int i = blockIdx.x * blockDim.x + threadIdx.x; i < total; i += stride) {
        int s, d;
        if (i < El) { s = sl[i]; d = dl[i]; }
        else        { s = sr[i - El] + Nl; d = dr[i - El] + Nl; }
        int pos = atomicAdd(&cursor[d], 1);
        adj[pos] = s;
        dslot[pos] = d;
    }
}

// ---------- graph boundaries for both branches: gs[0..32]=lig, gs[33..65]=rec ----------
__global__ void gstart_build2(const int* __restrict__ gidL, const int* __restrict__ gidR,
                              int* __restrict__ gs, int Nl, int Nr) {
    int Nc = Nl + Nr;
    int stride = gridDim.x * blockDim.x;
    for (int n = blockIdx.x * blockDim.x + threadIdx.x; n < Nc; n += stride) {
        if (n < Nl) {
            int gcur = gidL[n];
            int gprev = (n == 0) ? -1 : gidL[n - 1];
            for (int g = gprev + 1; g <= gcur; ++g) gs[g] = n;
            if (n == Nl - 1)
                for (int g = gcur + 1; g <= 32; ++g) gs[g] = Nl;
        } else {
            int ln = n - Nl;
            int gcur = gidR[ln];
            int gprev = (ln == 0) ? -1 : gidR[ln - 1];
            for (int g = gprev + 1; g <= gcur; ++g) gs[33 + g] = n;
            if (ln == Nr - 1)
                for (int g = gcur + 1; g <= 32; ++g) gs[33 + g] = Nc;
        }
    }
}

// ---------- per-slot raw attention logits (combined edges) ----------
template <int H>
__global__ void edge_e(const int* __restrict__ adj, const int* __restrict__ dslot,
                       const float* __restrict__ el, const float* __restrict__ er,
                       float* __restrict__ e, int E) {
    int stride = gridDim.x * blockDim.x;
    for (int i = blockIdx.x * blockDim.x + threadIdx.x; i < E; i += stride) {
        int s = adj[i], d = dslot[i];
        const float* els = el + (size_t)s * H;
        const float* erd = er + (size_t)d * H;
#pragma unroll
        for (int h = 0; h < H; ++h)
            e[(size_t)i * H + h] = lrelu(els[h] + erd[h]);
    }
}

// ---------- per-node softmax normalize (combined nodes) ----------
template <int H>
__global__ void node_norm(const int* __restrict__ rowptr, const float* __restrict__ e,
                          float* __restrict__ alpha, int N) {
    int stride = gridDim.x * blockDim.x;
    for (int n = blockIdx.x * blockDim.x + threadIdx.x; n < N; n += stride) {
        int rbeg = rowptr[n], rend = rowptr[n + 1];
        if (rbeg == rend) continue;
        float m[H], den[H];
#pragma unroll
        for (int h = 0; h < H; ++h) { m[h] = -INFINITY; den[h] = 0.f; }
        for (int j = rbeg; j < rend; ++j) {
#pragma unroll
            for (int h = 0; h < H; ++h) {
                float ev = e[(size_t)j * H + h];
                float newm = fmaxf(m[h], ev);
                den[h] = den[h] * __expf(m[h] - newm) + __expf(ev - newm);
                m[h] = newm;
            }
        }
        float inv[H];
#pragma unroll
        for (int h = 0; h < H; ++h) inv[h] = 1.f / fmaxf(den[h], 1e-9f);
        for (int j = rbeg; j < rend; ++j) {
#pragma unroll
            for (int h = 0; h < H; ++h)
                alpha[(size_t)j * H + h] = __expf(e[(size_t)j * H + h] - m[h]) * inv[h];
        }
    }
}

// ---------- gather x rows weighted by alpha; z stored BF16 (round-14: conversion
// moved here from the GEMM's f2bf -> bit-identical, half the z traffic) ----------
template <int H>
__global__ __launch_bounds__(256, 8) void gather_z_b(
        const int* __restrict__ rowptr, const int* __restrict__ adj,
        const float* __restrict__ alpha, const float* __restrict__ x,
        unsigned short* __restrict__ z, int N) {
    int lane = threadIdx.x & 63;
    int w = threadIdx.x >> 6;
    int wpb = blockDim.x >> 6;
    int wstride = gridDim.x * wpb;
    for (int n = blockIdx.x * wpb + w; n < N; n += wstride) {
        int rbeg = __builtin_amdgcn_readfirstlane(rowptr[n]);
        int rend = __builtin_amdgcn_readfirstlane(rowptr[n + 1]);
        float acc[H];
#pragma unroll
        for (int h = 0; h < H; ++h) acc[h] = 0.f;
        for (int j = rbeg; j < rend; ++j) {
            int s = __builtin_amdgcn_readfirstlane(adj[j]);
            float xv = x[(size_t)s * 64 + lane];
            const float* al = alpha + (size_t)j * H;
#pragma unroll
            for (int h = 0; h < H; ++h) acc[h] += al[h] * xv;
        }
#pragma unroll
        for (int h = 0; h < H; ++h)
            z[(size_t)n * (H * 64) + h * 64 + lane] = f2bf(acc[h]);
    }
}

// ---------- pack W[64][C] into per-lane bf16 MFMA B-fragments ----------
__global__ void prep_wfrag(const float* __restrict__ W, unsigned short* __restrict__ F,
                           int C) {
    int total = (C >> 4) * 1024;
    int stride = gridDim.x * blockDim.x;
    for (int idx = blockIdx.x * blockDim.x + threadIdx.x; idx < total; idx += stride) {
        int j = idx & 7;
        int lane = (idx >> 3) & 63;
        int step = (idx >> 9) & 1;
        int CT = idx >> 10;
        int k = ((lane >> 4) << 3) + j + (step << 5);
        int col = (CT << 4) + (lane & 15);
        F[idx] = f2bf(W[(size_t)k * C + col]);
    }
}

// ---------- MFMA per-head projection + relu + head-sum, bf16 A ----------
template <int H>
__global__ __launch_bounds__(256) void gemm_heads_mfma_b(
        const unsigned short* __restrict__ z, const bf16x8* __restrict__ Wf,
        const float* __restrict__ bias, float* __restrict__ out, int N) {
    const int SA = H * 64;
    int lane = threadIdx.x & 63;
    int w = threadIdx.x >> 6;
    int row0 = blockIdx.x * 64 + w * 16;
    int arow = row0 + (lane & 15);
    if (arow > N - 1) arow = N - 1;
    int kb = (lane >> 4) * 8;
    int colL = lane & 15;

    f32x4 o0 = {0,0,0,0}, o1 = {0,0,0,0}, o2 = {0,0,0,0}, o3 = {0,0,0,0};

    for (int h = 0; h < H; ++h) {
        const unsigned short* zr = z + (size_t)arow * SA + h * 64 + kb;
        bf16x8 A0 = *reinterpret_cast<const bf16x8*>(zr);
        bf16x8 A1 = *reinterpret_cast<const bf16x8*>(zr + 32);

        f32x4 acc0 = {0,0,0,0}, acc1 = {0,0,0,0}, acc2 = {0,0,0,0}, acc3 = {0,0,0,0};
#define CT_STEP(accv, ct)                                                            \
        {                                                                            \
            bf16x8 B0 = Wf[((h * 4 + (ct)) * 2 + 0) * 64 + lane];                    \
            bf16x8 B1 = Wf[((h * 4 + (ct)) * 2 + 1) * 64 + lane];                    \
            accv = __builtin_amdgcn_mfma_f32_16x16x32_bf16(A0, B0, accv, 0, 0, 0);   \
            accv = __builtin_amdgcn_mfma_f32_16x16x32_bf16(A1, B1, accv, 0, 0, 0);   \
        }
        CT_STEP(acc0, 0) CT_STEP(acc1, 1) CT_STEP(acc2, 2) CT_STEP(acc3, 3)
#undef CT_STEP

#define EPI(ov, accv, ct)                                                            \
        {                                                                            \
            float bv = bias[h * 64 + (ct) * 16 + colL];                              \
            ov[0] += fmaxf(accv[0] + bv, 0.f);                                       \
            ov[1] += fmaxf(accv[1] + bv, 0.f);                                       \
            ov[2] += fmaxf(accv[2] + bv, 0.f);                                       \
            ov[3] += fmaxf(accv[3] + bv, 0.f);                                       \
        }
        EPI(o0, acc0, 0) EPI(o1, acc1, 1) EPI(o2, acc2, 2) EPI(o3, acc3, 3)
#undef EPI
    }

    int rbase = row0 + (lane >> 4) * 4;
#define ST(ov, ct)                                                                   \
    {                                                                                \
        _Pragma("unroll")                                                            \
        for (int r = 0; r < 4; ++r) {                                                \
            int row = rbase + r;                                                     \
            if (row < N) out[(size_t)row * 64 + (ct) * 16 + colL] = ov[r];           \
        }                                                                            \
    }
    ST(o0, 0) ST(o1, 1) ST(o2, 2) ST(o3, 3)
#undef ST
}

// ---------- MFMA layer-2 GEMM, bf16 A: rst2 = relu(z2[N,64] @ W2 + bias) ----------
__global__ __launch_bounds__(256) void gemm_relu_mfma_b(
        const unsigned short* __restrict__ z, const bf16x8* __restrict__ Wf,
        const float* __restrict__ bias, float* __restrict__ out, int N) {
    int lane = threadIdx.x & 63;
    int w = threadIdx.x >> 6;
    int row0 = blockIdx.x * 64 + w * 16;
    int arow = row0 + (lane & 15);
    if (arow > N - 1) arow = N - 1;
    int kb = (lane >> 4) * 8;
    int colL = lane & 15;

    const unsigned short* zr = z + (size_t)arow * 64 + kb;
    bf16x8 A0 = *reinterpret_cast<const bf16x8*>(zr);
    bf16x8 A1 = *reinterpret_cast<const bf16x8*>(zr + 32);

    int rbase = row0 + (lane >> 4) * 4;
#define DO_CT(ct)                                                                    \
    {                                                                                \
        bf16x8 B0 = Wf[((ct) * 2 + 0) * 64 + lane];                                  \
        bf16x8 B1 = Wf[((ct) * 2 + 1) * 64 + lane];                                  \
        f32x4 acc = {0, 0, 0, 0};                                                    \
        acc = __builtin_amdgcn_mfma_f32_16x16x32_bf16(A0, B0, acc, 0, 0, 0);         \
        acc = __builtin_amdgcn_mfma_f32_16x16x32_bf16(A1, B1, acc, 0, 0, 0);         \
        float bv = bias[(ct) * 16 + colL];                                           \
        _Pragma("unroll")                                                            \
        for (int r = 0; r < 4; ++r) {                                                \
            int row = rbase + r;                                                     \
            if (row < N)                                                             \
                out[(size_t)row * 128 + (ct) * 16 + colL] = fmaxf(acc[r] + bv, 0.f); \
        }                                                                            \
    }
    DO_CT(0) DO_CT(1) DO_CT(2) DO_CT(3) DO_CT(4) DO_CT(5) DO_CT(6) DO_CT(7)
#undef DO_CT
}

// ---------- per-graph column max, both branches: grid (64 graphs, 8 splits) ----------
__global__ __launch_bounds__(128) void graph_max2(const float* __restrict__ rst2,
                                                  const int* __restrict__ gstart,
                                                  float* __restrict__ gm) {
    int g = blockIdx.x;            // 0..63
    int b = g >> 5, gl = g & 31;
    int sp = blockIdx.y;
    int t = threadIdx.x;
    const int* gs = gstart + 33 * b;
    int rb = gs[gl], re = gs[gl + 1];
    float m = -INFINITY;
    for (int r = rb + sp; r < re; r += 8)
        m = fmaxf(m, rst2[(size_t)r * 128 + t]);
    gm[(size_t)((b * 8 + sp) * 32 + gl) * 128 + t] = m;
}

// ---------- head MLP: one block per graph ----------
__global__ __launch_bounds__(256) void mlp_head2(
        const float* __restrict__ gml, const float* __restrict__ gmr,
        const float* __restrict__ W1, const float* __restrict__ b1,
        const float* __restrict__ W2, const float* __restrict__ b2,
        float* __restrict__ out) {
    __shared__ float hcat[256];
    __shared__ float part[256];
    __shared__ float h[128];
    int g = blockIdx.x;
    int t = threadIdx.x;
    {
        const float* gsrc = (t < 128) ? gml : gmr;
        int c = t & 127;
        float m = -INFINITY;
#pragma unroll
        for (int sp = 0; sp < 8; ++sp) m = fmaxf(m, gsrc[sp * 4096 + g * 128 + c]);
        hcat[t < 128 ? c : 128 + c] = fmaxf(m, 0.f);
    }
    __syncthreads();
    {
        int c = t & 127;
        int k0 = (t >> 7) << 7;
        float acc = 0.f;
#pragma unroll 4
        for (int k = 0; k < 128; ++k)
            acc += hcat[k0 + k] * W1[(size_t)(k0 + k) * 128 + c];
        part[t] = acc;
    }
    __syncthreads();
    if (t < 128) h[t] = fmaxf(part[t] + part[t + 128] + b1[t], 0.f);
    __syncthreads();
    if (t < 128) {
        float v = h[t] * W2[t];
        for (int off = 32; off; off >>= 1) v += __shfl_down(v, off);
        if ((t & 63) == 0) part[t >> 6] = v;
    }
    __syncthreads();
    if (t == 0) out[g] = fmaxf(part[0] + part[1] + b2[0], 0.f);
}

// ---------- launch ----------
static inline unsigned nblk_elem(long long total) {
    long long b = (total + 255) / 256;
    if (b > 65535) b = 65535;
    if (b < 1) b = 1;
    return (unsigned)b;
}
static inline unsigned nblk_gather(long long nodes) {
    long long b = (nodes + 3) / 4;
    if (b > 65535) b = 65535;
    if (b < 1) b = 1;
    return (unsigned)b;
}

extern "C" void kernel_launch(void* const* d_in, const int* in_sizes, int n_in,
                              void* d_out, int out_size, void* d_ws, size_t ws_size,
                              hipStream_t stream) {
    const float* lig_x = (const float*)d_in[0];
    const int* lig_src = (const int*)d_in[1];
    const int* lig_dst = (const int*)d_in[2];
    const int* lig_gid = (const int*)d_in[3];
    const float* rec_x = (const float*)d_in[4];
    const int* rec_src = (const int*)d_in[5];
    const int* rec_dst = (const int*)d_in[6];
    const int* rec_gid = (const int*)d_in[7];
    const float* W1l = (const float*)d_in[8];
    const float* al1l = (const float*)d_in[9];
    const float* ar1l = (const float*)d_in[10];
    const float* b1l = (const float*)d_in[11];
    const float* W2l = (const float*)d_in[12];
    const float* al2l = (const float*)d_in[13];
    const float* ar2l = (const float*)d_in[14];
    const float* b2l = (const float*)d_in[15];
    const float* W1r = (const float*)d_in[16];
    const float* al1r = (const float*)d_in[17];
    const float* ar1r = (const float*)d_in[18];
    const float* b1r = (const float*)d_in[19];
    const float* W2r = (const float*)d_in[20];
    const float* al2r = (const float*)d_in[21];
    const float* ar2r = (const float*)d_in[22];
    const float* b2r = (const float*)d_in[23];
    const float* Wlin1 = (const float*)d_in[24];
    const float* blin1 = (const float*)d_in[25];
    const float* Wlin2 = (const float*)d_in[26];
    const float* blin2 = (const float*)d_in[27];

    int Nl = in_sizes[0] / 64, El = in_sizes[1];
    int Nr = in_sizes[4] / 64, Er = in_sizes[5];
    int Nc = Nl + Nr;
    int Ec = El + Er;

    // workspace layout (combined disjoint-union graph)
    char* ws = (char*)d_ws;
    float* xcat = (float*)ws;        ws += (size_t)Nc * 64 * 4;
    unsigned short* zb = (unsigned short*)ws;   ws += (size_t)Nc * 640 * 2;
    unsigned short* z2b = (unsigned short*)ws;  ws += (size_t)Nc * 64 * 2;
    float* h1 = (float*)ws;          ws += (size_t)Nc * 64 * 4;
    float* rst2 = (float*)ws;        ws += (size_t)Nc * 128 * 4;
    float* elb = (float*)ws;         ws += (size_t)Nc * 10 * 4;
    float* erb = (float*)ws;         ws += (size_t)Nc * 10 * 4;
    int* deg = (int*)ws;             ws += (size_t)Nc * 4;
    int* cursor = (int*)ws;          ws += (size_t)Nc * 4;
    int* rowptr = (int*)ws;          ws += (size_t)(Nc + 1) * 4;
    int* adj = (int*)ws;             ws += (size_t)Ec * 4;
    int* dslot = (int*)ws;           ws += (size_t)Ec * 4;
    float* ebuf = (float*)ws;        ws += (size_t)Ec * 10 * 4;
    float* alpha = (float*)ws;       ws += (size_t)Ec * 10 * 4;
    float* gm = (float*)ws;          ws += 2 * 8 * 32 * 128 * 4;
    int* gstart = (int*)ws;          ws += 66 * 4;
    int* bsum = (int*)ws;            ws += 64 * 4;
    float* walr1l = (float*)ws;      ws += 64 * 20 * 4;
    float* walr1r = (float*)ws;      ws += 64 * 20 * 4;
    float* walr2l = (float*)ws;      ws += 64 * 2 * 4;
    float* walr2r = (float*)ws;      ws += 64 * 2 * 4;
    unsigned short* wf1l = (unsigned short*)ws;  ws += 40960 * 2;
    unsigned short* wf1r = (unsigned short*)ws;  ws += 40960 * 2;
    unsigned short* wf2l = (unsigned short*)ws;  ws += 8192 * 2;
    unsigned short* wf2r = (unsigned short*)ws;  ws += 8192 * 2;
    unsigned short* wfa1l = (unsigned short*)ws; ws += 2048 * 2;
    unsigned short* wfa1r = (unsigned short*)ws; ws += 2048 * 2;
    unsigned short* wfa2l = (unsigned short*)ws; ws += 1024 * 2;
    unsigned short* wfa2r = (unsigned short*)ws; ws += 1024 * 2;

    int nb = (Nc + 2047) / 2048;

    // ---- weight prep (input-only deps) ----
    prep_wfrag<<<40, 256, 0, stream>>>(W1l, wf1l, 640);
    prep_wfrag<<<40, 256, 0, stream>>>(W1r, wf1r, 640);
    prep_wfrag<<<8, 256, 0, stream>>>(W2l, wf2l, 128);
    prep_wfrag<<<8, 256, 0, stream>>>(W2r, wf2r, 128);
    fold_attn<<<64, 64, 0, stream>>>(W1l, al1l, ar1l, walr1l, 10, 64);
    fold_attn<<<64, 64, 0, stream>>>(W1r, al1r, ar1r, walr1r, 10, 64);
    fold_attn<<<64, 64, 0, stream>>>(W2l, al2l, ar2l, walr2l, 1, 128);
    fold_attn<<<64, 64, 0, stream>>>(W2r, al2r, ar2r, walr2r, 1, 128);
    prep_walr<<<8, 256, 0, stream>>>(walr1l, wfa1l, 20);
    prep_walr<<<8, 256, 0, stream>>>(walr1r, wfa1r, 20);
    prep_walr<<<4, 256, 0, stream>>>(walr2l, wfa2l, 2);
    prep_walr<<<4, 256, 0, stream>>>(walr2r, wfa2r, 2);

    // ---- combined CSR + graph boundaries ----
    copy_x2<<<nblk_elem((long long)Nc * 16), 256, 0, stream>>>(
        (const float4*)lig_x, Nl * 16, (const float4*)rec_x, Nr * 16, (float4*)xcat);
    hipMemsetAsync(deg, 0, (size_t)Nc * 4, stream);
    count_deg2<<<nblk_elem(Ec), 256, 0, stream>>>(lig_dst, rec_dst, deg, El, Er, Nl);
    scan_local<<<nb, 256, 0, stream>>>(deg, rowptr, bsum, Nc);
    scan_bsum<<<1, 64, 0, stream>>>(bsum, rowptr + Nc, nb);
    scan_add<<<nb, 256, 0, stream>>>(rowptr, bsum, Nc);
    hipMemcpyAsync(cursor, rowptr, (size_t)Nc * 4, hipMemcpyDeviceToDevice, stream);
    fill_adj2<<<nblk_elem(Ec), 256, 0, stream>>>(lig_src, lig_dst, rec_src, rec_dst,
                                                 cursor, adj, dslot, El, Er, Nl);
    gstart_build2<<<nblk_elem(Nc), 256, 0, stream>>>(lig_gid, rec_gid, gstart, Nl, Nr);

    // ---- layer 1: H=10 ----
    attn_mfma<10><<<(Nl + 63) / 64, 256, 0, stream>>>(xcat, (const bf16x8*)wfa1l,
                                                      elb, erb, Nl);
    attn_mfma<10><<<(Nr + 63) / 64, 256, 0, stream>>>(xcat + (size_t)Nl * 64,
                                                      (const bf16x8*)wfa1r,
                                                      elb + (size_t)Nl * 10,
                                                      erb + (size_t)Nl * 10, Nr);
    edge_e<10><<<nblk_elem(Ec), 256, 0, stream>>>(adj, dslot, elb, erb, ebuf, Ec);
    node_norm<10><<<nblk_elem(Nc), 256, 0, stream>>>(rowptr, ebuf, alpha, Nc);
    gather_z_b<10><<<nblk_gather(Nc), 256, 0, stream>>>(rowptr, adj, alpha, xcat, zb, Nc);
    gemm_heads_mfma_b<10><<<(Nl + 63) / 64, 256, 0, stream>>>(zb, (const bf16x8*)wf1l,
                                                              b1l, h1, Nl);
    gemm_heads_mfma_b<10><<<(Nr + 63) / 64, 256, 0, stream>>>(zb + (size_t)Nl * 640,
                                                              (const bf16x8*)wf1r, b1r,
                                                              h1 + (size_t)Nl * 64, Nr);

    // ---- layer 2: H=1 ----
    attn_mfma<1><<<(Nl + 63) / 64, 256, 0, stream>>>(h1, (const bf16x8*)wfa2l,
                                                     elb, erb, Nl);
    attn_mfma<1><<<(Nr + 63) / 64, 256, 0, stream>>>(h1 + (size_t)Nl * 64,
                                                     (const bf16x8*)wfa2r,
                                                     elb + Nl, erb + Nl, Nr);
    edge_e<1><<<nblk_elem(Ec), 256, 0, stream>>>(adj, dslot, elb, erb, ebuf, Ec);
    node_norm<1><<<nblk_elem(Nc), 256, 0, stream>>>(rowptr, ebuf, alpha, Nc);
    gather_z_b<1><<<nblk_gather(Nc), 256, 0, stream>>>(rowptr, adj, alpha, h1, z2b, Nc);
    gemm_relu_mfma_b<<<(Nl + 63) / 64, 256, 0, stream>>>(z2b, (const bf16x8*)wf2l,
                                                         b2l, rst2, Nl);
    gemm_relu_mfma_b<<<(Nr + 63) / 64, 256, 0, stream>>>(z2b + (size_t)Nl * 64,
                                                         (const bf16x8*)wf2r, b2r,
                                                         rst2 + (size_t)Nl * 128, Nr);
    graph_max2<<<dim3(64, 8), 128, 0, stream>>>(rst2, gstart, gm);
    mlp_head2<<<32, 256, 0, stream>>>(gm, gm + 8 * 32 * 128, Wlin1, blin1, Wlin2, blin2,
                                      (float*)d_out);
}

// Round 15
// 356.703 us; speedup vs baseline: 1.6392x; 1.0928x over previous
//
#include <hip/hip_runtime.h>
#include <hip/hip_bf16.h>

typedef short bf16x8 __attribute__((ext_vector_type(8)));
typedef float f32x4 __attribute__((ext_vector_type(4)));

__device__ inline float lrelu(float x) { return x > 0.f ? x : 0.2f * x; }

// fp32 -> bf16 (round-to-nearest-even)
__device__ inline unsigned short f2bf(float f) {
    unsigned u = __float_as_uint(f);
    u = u + 0x7FFFu + ((u >> 16) & 1u);
    return (unsigned short)(u >> 16);
}

// ---------- concat lig_x and rec_x into xcat ----------
__global__ void copy_x2(const float4* __restrict__ a, int na4,
                        const float4* __restrict__ b, int nb4, float4* __restrict__ o) {
    int total = na4 + nb4;
    int stride = gridDim.x * blockDim.x;
    for (int i = blockIdx.x * blockDim.x + threadIdx.x; i < total; i += stride)
        o[i] = (i < na4) ? a[i] : b[i - na4];
}

// ---------- fold attention vectors through W: Walr[k][2H] ----------
__global__ void fold_attn(const float* __restrict__ W, const float* __restrict__ al,
                          const float* __restrict__ ar, float* __restrict__ Walr,
                          int H, int D) {
    int k = blockIdx.x;
    int lane = threadIdx.x;
    int C = H * D;
    for (int h = 0; h < H; ++h) {
        float sl = 0.f, sr = 0.f;
        for (int d = lane; d < D; d += 64) {
            float w = W[(size_t)k * C + h * D + d];
            sl += w * al[h * D + d];
            sr += w * ar[h * D + d];
        }
        for (int off = 32; off; off >>= 1) {
            sl += __shfl_down(sl, off);
            sr += __shfl_down(sr, off);
        }
        if (lane == 0) {
            Walr[k * 2 * H + h] = sl;
            Walr[k * 2 * H + H + h] = sr;
        }
    }
}

// ---------- pack Walr[64][C2] into bf16 MFMA B-fragments, zero-pad cols to 16 ----------
__global__ void prep_walr(const float* __restrict__ Walr, unsigned short* __restrict__ F,
                          int C2) {
    int NCT = (C2 + 15) / 16;
    int total = NCT * 1024;
    int stride = gridDim.x * blockDim.x;
    for (int idx = blockIdx.x * blockDim.x + threadIdx.x; idx < total; idx += stride) {
        int j = idx & 7;
        int lane = (idx >> 3) & 63;
        int step = (idx >> 9) & 1;
        int CT = idx >> 10;
        int k = ((lane >> 4) << 3) + j + (step << 5);
        int col = (CT << 4) + (lane & 15);
        F[idx] = (col < C2) ? f2bf(Walr[k * C2 + col]) : 0;
    }
}

// ---------- el/er via MFMA: x[N,64] @ Walr[64,2H] ----------
template <int H>
__global__ __launch_bounds__(256) void attn_mfma(const float* __restrict__ x,
                                                 const bf16x8* __restrict__ Wf,
                                                 float* __restrict__ el,
                                                 float* __restrict__ er, int N) {
    const int NCT = (2 * H + 15) / 16;
    int lane = threadIdx.x & 63;
    int w = threadIdx.x >> 6;
    int row0 = blockIdx.x * 64 + w * 16;
    int arow = row0 + (lane & 15);
    if (arow > N - 1) arow = N - 1;
    int kb = (lane >> 4) * 8;
    int colL = lane & 15;

    const float* xr = x + (size_t)arow * 64 + kb;
    float4 a0 = *reinterpret_cast<const float4*>(xr);
    float4 a1 = *reinterpret_cast<const float4*>(xr + 4);
    float4 a2 = *reinterpret_cast<const float4*>(xr + 32);
    float4 a3 = *reinterpret_cast<const float4*>(xr + 36);
    bf16x8 A0, A1;
    A0[0] = (short)f2bf(a0.x); A0[1] = (short)f2bf(a0.y);
    A0[2] = (short)f2bf(a0.z); A0[3] = (short)f2bf(a0.w);
    A0[4] = (short)f2bf(a1.x); A0[5] = (short)f2bf(a1.y);
    A0[6] = (short)f2bf(a1.z); A0[7] = (short)f2bf(a1.w);
    A1[0] = (short)f2bf(a2.x); A1[1] = (short)f2bf(a2.y);
    A1[2] = (short)f2bf(a2.z); A1[3] = (short)f2bf(a2.w);
    A1[4] = (short)f2bf(a3.x); A1[5] = (short)f2bf(a3.y);
    A1[6] = (short)f2bf(a3.z); A1[7] = (short)f2bf(a3.w);

    int rbase = row0 + (lane >> 4) * 4;
#pragma unroll
    for (int ct = 0; ct < NCT; ++ct) {
        bf16x8 B0 = Wf[(ct * 2 + 0) * 64 + lane];
        bf16x8 B1 = Wf[(ct * 2 + 1) * 64 + lane];
        f32x4 acc = {0, 0, 0, 0};
        acc = __builtin_amdgcn_mfma_f32_16x16x32_bf16(A0, B0, acc, 0, 0, 0);
        acc = __builtin_amdgcn_mfma_f32_16x16x32_bf16(A1, B1, acc, 0, 0, 0);
        int col = ct * 16 + colL;
#pragma unroll
        for (int r = 0; r < 4; ++r) {
            int row = rbase + r;
            if (row < N) {
                if (col < H) el[(size_t)row * H + col] = acc[r];
                else if (col < 2 * H) er[(size_t)row * H + col - H] = acc[r];
            }
        }
    }
}

// ---------- CSR build over the DISJOINT UNION graph (rec ids offset by Nl) ----------
__global__ void count_deg2(const int* __restrict__ dl, const int* __restrict__ dr,
                           int* __restrict__ deg, int El, int Er, int Nl) {
    int total = El + Er;
    int stride = gridDim.x * blockDim.x;
    for (int i = blockIdx.x * blockDim.x + threadIdx.x; i < total; i += stride) {
        int d = (i < El) ? dl[i] : (dr[i - El] + Nl);
        atomicAdd(&deg[d], 1);
    }
}

__global__ __launch_bounds__(256) void scan_local(const int* __restrict__ deg,
                                                  int* __restrict__ rowptr,
                                                  int* __restrict__ bsum, int N) {
    __shared__ int wsum[4];
    int t = threadIdx.x;
    int base = blockIdx.x * 2048 + t * 8;
    int v[8];
    int s = 0;
#pragma unroll
    for (int i = 0; i < 8; ++i) {
        int idx = base + i;
        v[i] = (idx < N) ? deg[idx] : 0;
        s += v[i];
    }
    int lane = t & 63, w = t >> 6;
    int incl = s;
    for (int off = 1; off < 64; off <<= 1) {
        int o = __shfl_up(incl, off);
        if (lane >= off) incl += o;
    }
    if (lane == 63) wsum[w] = incl;
    __syncthreads();
    int woff = 0;
    for (int i = 0; i < w; ++i) woff += wsum[i];
    int run = woff + incl - s;
#pragma unroll
    for (int i = 0; i < 8; ++i) {
        int idx = base + i;
        if (idx < N) rowptr[idx] = run;
        run += v[i];
    }
    if (t == 255) bsum[blockIdx.x] = woff + incl;
}

__global__ void scan_bsum(int* __restrict__ bsum, int* __restrict__ rowptrN, int nb) {
    int t = threadIdx.x;  // 64 threads
    int v = (t < nb) ? bsum[t] : 0;
    int incl = v;
    for (int off = 1; off < 64; off <<= 1) {
        int o = __shfl_up(incl, off);
        if (t >= off) incl += o;
    }
    if (t < nb) bsum[t] = incl - v;
    if (t == 63) *rowptrN = incl;
}

__global__ __launch_bounds__(256) void scan_add(int* __restrict__ rowptr,
                                                const int* __restrict__ bsum, int N) {
    int off = bsum[blockIdx.x];
    if (off == 0) return;
    int base = blockIdx.x * 2048 + threadIdx.x * 8;
#pragma unroll
    for (int i = 0; i < 8; ++i) {
        int idx = base + i;
        if (idx < N) rowptr[idx] += off;
    }
}

__global__ void fill_adj2(const int* __restrict__ sl, const int* __restrict__ dl,
                          const int* __restrict__ sr, const int* __restrict__ dr,
                          int* __restrict__ cursor, int* __restrict__ adj,
                          int* __restrict__ dslot, int El, int Er, int Nl) {
    int total = El + Er;
    int stride = gridDim.x * blockDim.x;
    for (int i = blockIdx.x * blockDim.x + threadIdx.x; i < total; i += stride) {
        int s, d;
        if (i < El) { s = sl[i]; d = dl[i]; }
        else        { s = sr[i - El] + Nl; d = dr[i - El] + Nl; }
        int pos = atomicAdd(&cursor[d], 1);
        adj[pos] = s;
        dslot[pos] = d;
    }
}

// ---------- graph boundaries for both branches: gs[0..32]=lig, gs[33..65]=rec ----------
__global__ void gstart_build2(const int* __restrict__ gidL, const int* __restrict__ gidR,
                              int* __restrict__ gs, int Nl, int Nr) {
    int Nc = Nl + Nr;
    int stride = gridDim.x * blockDim.x;
    for (int n = blockIdx.x * blockDim.x + threadIdx.x; n < Nc; n += stride) {
        if (n < Nl) {
            int gcur = gidL[n];
            int gprev = (n == 0) ? -1 : gidL[n - 1];
            for (int g = gprev + 1; g <= gcur; ++g) gs[g] = n;
            if (n == Nl - 1)
                for (int g = gcur + 1; g <= 32; ++g) gs[g] = Nl;
        } else {
            int ln = n - Nl;
            int gcur = gidR[ln];
            int gprev = (ln == 0) ? -1 : gidR[ln - 1];
            for (int g = gprev + 1; g <= gcur; ++g) gs[33 + g] = n;
            if (ln == Nr - 1)
                for (int g = gcur + 1; g <= 32; ++g) gs[33 + g] = Nc;
        }
    }
}

// ---------- per-slot raw attention logits (combined edges) ----------
template <int H>
__global__ void edge_e(const int* __restrict__ adj, const int* __restrict__ dslot,
                       const float* __restrict__ el, const float* __restrict__ er,
                       float* __restrict__ e, int E) {
    int stride = gridDim.x * blockDim.x;
    for (int i = blockIdx.x * blockDim.x + threadIdx.x; i < E; i += stride) {
        int s = adj[i], d = dslot[i];
        const float* els = el + (size_t)s * H;
        const float* erd = er + (size_t)d * H;
#pragma unroll
        for (int h = 0; h < H; ++h)
            e[(size_t)i * H + h] = lrelu(els[h] + erd[h]);
    }
}

// ---------- per-node softmax normalize (combined nodes) ----------
template <int H>
__global__ void node_norm(const int* __restrict__ rowptr, const float* __restrict__ e,
                          float* __restrict__ alpha, int N) {
    int stride = gridDim.x * blockDim.x;
    for (int n = blockIdx.x * blockDim.x + threadIdx.x; n < N; n += stride) {
        int rbeg = rowptr[n], rend = rowptr[n + 1];
        if (rbeg == rend) continue;
        float m[H], den[H];
#pragma unroll
        for (int h = 0; h < H; ++h) { m[h] = -INFINITY; den[h] = 0.f; }
        for (int j = rbeg; j < rend; ++j) {
#pragma unroll
            for (int h = 0; h < H; ++h) {
                float ev = e[(size_t)j * H + h];
                float newm = fmaxf(m[h], ev);
                den[h] = den[h] * __expf(m[h] - newm) + __expf(ev - newm);
                m[h] = newm;
            }
        }
        float inv[H];
#pragma unroll
        for (int h = 0; h < H; ++h) inv[h] = 1.f / fmaxf(den[h], 1e-9f);
        for (int j = rbeg; j < rend; ++j) {
#pragma unroll
            for (int h = 0; h < H; ++h)
                alpha[(size_t)j * H + h] = __expf(e[(size_t)j * H + h] - m[h]) * inv[h];
        }
    }
}

// ---------- gather x rows weighted by alpha; z stored bf16.
// round-15: adj prefetched lane-parallel (shuffle broadcast, no per-edge adj load)
// + 4-edge unroll -> 4x independent loads in flight (was serial dependent chain).
template <int H>
__global__ __launch_bounds__(256, 8) void gather_z_b(
        const int* __restrict__ rowptr, const int* __restrict__ adj,
        const float* __restrict__ alpha, const float* __restrict__ x,
        unsigned short* __restrict__ z, int N) {
    int lane = threadIdx.x & 63;
    int w = threadIdx.x >> 6;
    int wpb = blockDim.x >> 6;
    int wstride = gridDim.x * wpb;
    for (int n = blockIdx.x * wpb + w; n < N; n += wstride) {
        int rbeg = __builtin_amdgcn_readfirstlane(rowptr[n]);
        int rend = __builtin_amdgcn_readfirstlane(rowptr[n + 1]);
        float acc[H];
#pragma unroll
        for (int h = 0; h < H; ++h) acc[h] = 0.f;
        for (int base = rbeg; base < rend; base += 64) {
            int cnt = rend - base; if (cnt > 64) cnt = 64;
            int sv = adj[base + ((lane < cnt) ? lane : 0)];
            int j = 0;
            for (; j + 4 <= cnt; j += 4) {
                int s0 = __shfl(sv, j);
                int s1 = __shfl(sv, j + 1);
                int s2 = __shfl(sv, j + 2);
                int s3 = __shfl(sv, j + 3);
                float x0 = x[(size_t)s0 * 64 + lane];
                float x1 = x[(size_t)s1 * 64 + lane];
                float x2 = x[(size_t)s2 * 64 + lane];
                float x3 = x[(size_t)s3 * 64 + lane];
                const float* a0 = alpha + (size_t)(base + j) * H;
                const float* a1 = a0 + H;
                const float* a2 = a1 + H;
                const float* a3 = a2 + H;
#pragma unroll
                for (int h = 0; h < H; ++h)
                    acc[h] += a0[h] * x0 + a1[h] * x1 + a2[h] * x2 + a3[h] * x3;
            }
            for (; j < cnt; ++j) {
                int s = __shfl(sv, j);
                float xv = x[(size_t)s * 64 + lane];
                const float* al = alpha + (size_t)(base + j) * H;
#pragma unroll
                for (int h = 0; h < H; ++h) acc[h] += al[h] * xv;
            }
        }
#pragma unroll
        for (int h = 0; h < H; ++h)
            z[(size_t)n * (H * 64) + h * 64 + lane] = f2bf(acc[h]);
    }
}

// ---------- pack W[64][C] into per-lane bf16 MFMA B-fragments ----------
__global__ void prep_wfrag(const float* __restrict__ W, unsigned short* __restrict__ F,
                           int C) {
    int total = (C >> 4) * 1024;
    int stride = gridDim.x * blockDim.x;
    for (int idx = blockIdx.x * blockDim.x + threadIdx.x; idx < total; idx += stride) {
        int j = idx & 7;
        int lane = (idx >> 3) & 63;
        int step = (idx >> 9) & 1;
        int CT = idx >> 10;
        int k = ((lane >> 4) << 3) + j + (step << 5);
        int col = (CT << 4) + (lane & 15);
        F[idx] = f2bf(W[(size_t)k * C + col]);
    }
}

// ---------- MFMA per-head projection + relu + head-sum, bf16 A ----------
template <int H>
__global__ __launch_bounds__(256) void gemm_heads_mfma_b(
        const unsigned short* __restrict__ z, const bf16x8* __restrict__ Wf,
        const float* __restrict__ bias, float* __restrict__ out, int N) {
    const int SA = H * 64;
    int lane = threadIdx.x & 63;
    int w = threadIdx.x >> 6;
    int row0 = blockIdx.x * 64 + w * 16;
    int arow = row0 + (lane & 15);
    if (arow > N - 1) arow = N - 1;
    int kb = (lane >> 4) * 8;
    int colL = lane & 15;

    f32x4 o0 = {0,0,0,0}, o1 = {0,0,0,0}, o2 = {0,0,0,0}, o3 = {0,0,0,0};

    for (int h = 0; h < H; ++h) {
        const unsigned short* zr = z + (size_t)arow * SA + h * 64 + kb;
        bf16x8 A0 = *reinterpret_cast<const bf16x8*>(zr);
        bf16x8 A1 = *reinterpret_cast<const bf16x8*>(zr + 32);

        f32x4 acc0 = {0,0,0,0}, acc1 = {0,0,0,0}, acc2 = {0,0,0,0}, acc3 = {0,0,0,0};
#define CT_STEP(accv, ct)                                                            \
        {                                                                            \
            bf16x8 B0 = Wf[((h * 4 + (ct)) * 2 + 0) * 64 + lane];                    \
            bf16x8 B1 = Wf[((h * 4 + (ct)) * 2 + 1) * 64 + lane];                    \
            accv = __builtin_amdgcn_mfma_f32_16x16x32_bf16(A0, B0, accv, 0, 0, 0);   \
            accv = __builtin_amdgcn_mfma_f32_16x16x32_bf16(A1, B1, accv, 0, 0, 0);   \
        }
        CT_STEP(acc0, 0) CT_STEP(acc1, 1) CT_STEP(acc2, 2) CT_STEP(acc3, 3)
#undef CT_STEP

#define EPI(ov, accv, ct)                                                            \
        {                                                                            \
            float bv = bias[h * 64 + (ct) * 16 + colL];                              \
            ov[0] += fmaxf(accv[0] + bv, 0.f);                                       \
            ov[1] += fmaxf(accv[1] + bv, 0.f);                                       \
            ov[2] += fmaxf(accv[2] + bv, 0.f);                                       \
            ov[3] += fmaxf(accv[3] + bv, 0.f);                                       \
        }
        EPI(o0, acc0, 0) EPI(o1, acc1, 1) EPI(o2, acc2, 2) EPI(o3, acc3, 3)
#undef EPI
    }

    int rbase = row0 + (lane >> 4) * 4;
#define ST(ov, ct)                                                                   \
    {                                                                                \
        _Pragma("unroll")                                                            \
        for (int r = 0; r < 4; ++r) {                                                \
            int row = rbase + r;                                                     \
            if (row < N) out[(size_t)row * 64 + (ct) * 16 + colL] = ov[r];           \
        }                                                                            \
    }
    ST(o0, 0) ST(o1, 1) ST(o2, 2) ST(o3, 3)
#undef ST
}

// ---------- MFMA layer-2 GEMM, bf16 A: rst2 = relu(z2[N,64] @ W2 + bias) ----------
__global__ __launch_bounds__(256) void gemm_relu_mfma_b(
        const unsigned short* __restrict__ z, const bf16x8* __restrict__ Wf,
        const float* __restrict__ bias, float* __restrict__ out, int N) {
    int lane = threadIdx.x & 63;
    int w = threadIdx.x >> 6;
    int row0 = blockIdx.x * 64 + w * 16;
    int arow = row0 + (lane & 15);
    if (arow > N - 1) arow = N - 1;
    int kb = (lane >> 4) * 8;
    int colL = lane & 15;

    const unsigned short* zr = z + (size_t)arow * 64 + kb;
    bf16x8 A0 = *reinterpret_cast<const bf16x8*>(zr);
    bf16x8 A1 = *reinterpret_cast<const bf16x8*>(zr + 32);

    int rbase = row0 + (lane >> 4) * 4;
#define DO_CT(ct)                                                                    \
    {                                                                                \
        bf16x8 B0 = Wf[((ct) * 2 + 0) * 64 + lane];                                  \
        bf16x8 B1 = Wf[((ct) * 2 + 1) * 64 + lane];                                  \
        f32x4 acc = {0, 0, 0, 0};                                                    \
        acc = __builtin_amdgcn_mfma_f32_16x16x32_bf16(A0, B0, acc, 0, 0, 0);         \
        acc = __builtin_amdgcn_mfma_f32_16x16x32_bf16(A1, B1, acc, 0, 0, 0);         \
        float bv = bias[(ct) * 16 + colL];                                           \
        _Pragma("unroll")                                                            \
        for (int r = 0; r < 4; ++r) {                                                \
            int row = rbase + r;                                                     \
            if (row < N)                                                             \
                out[(size_t)row * 128 + (ct) * 16 + colL] = fmaxf(acc[r] + bv, 0.f); \
        }                                                                            \
    }
    DO_CT(0) DO_CT(1) DO_CT(2) DO_CT(3) DO_CT(4) DO_CT(5) DO_CT(6) DO_CT(7)
#undef DO_CT
}

// ---------- per-graph column max, both branches: grid (64 graphs, 8 splits) ----------
__global__ __launch_bounds__(128) void graph_max2(const float* __restrict__ rst2,
                                                  const int* __restrict__ gstart,
                                                  float* __restrict__ gm) {
    int g = blockIdx.x;            // 0..63
    int b = g >> 5, gl = g & 31;
    int sp = blockIdx.y;
    int t = threadIdx.x;
    const int* gs = gstart + 33 * b;
    int rb = gs[gl], re = gs[gl + 1];
    float m = -INFINITY;
    for (int r = rb + sp; r < re; r += 8)
        m = fmaxf(m, rst2[(size_t)r * 128 + t]);
    gm[(size_t)((b * 8 + sp) * 32 + gl) * 128 + t] = m;
}

// ---------- head MLP: one block per graph ----------
__global__ __launch_bounds__(256) void mlp_head2(
        const float* __restrict__ gml, const float* __restrict__ gmr,
        const float* __restrict__ W1, const float* __restrict__ b1,
        const float* __restrict__ W2, const float* __restrict__ b2,
        float* __restrict__ out) {
    __shared__ float hcat[256];
    __shared__ float part[256];
    __shared__ float h[128];
    int g = blockIdx.x;
    int t = threadIdx.x;
    {
        const float* gsrc = (t < 128) ? gml : gmr;
        int c = t & 127;
        float m = -INFINITY;
#pragma unroll
        for (int sp = 0; sp < 8; ++sp) m = fmaxf(m, gsrc[sp * 4096 + g * 128 + c]);
        hcat[t < 128 ? c : 128 + c] = fmaxf(m, 0.f);
    }
    __syncthreads();
    {
        int c = t & 127;
        int k0 = (t >> 7) << 7;
        float acc = 0.f;
#pragma unroll 4
        for (int k = 0; k < 128; ++k)
            acc += hcat[k0 + k] * W1[(size_t)(k0 + k) * 128 + c];
        part[t] = acc;
    }
    __syncthreads();
    if (t < 128) h[t] = fmaxf(part[t] + part[t + 128] + b1[t], 0.f);
    __syncthreads();
    if (t < 128) {
        float v = h[t] * W2[t];
        for (int off = 32; off; off >>= 1) v += __shfl_down(v, off);
        if ((t & 63) == 0) part[t >> 6] = v;
    }
    __syncthreads();
    if (t == 0) out[g] = fmaxf(part[0] + part[1] + b2[0], 0.f);
}

// ---------- launch ----------
static inline unsigned nblk_elem(long long total) {
    long long b = (total + 255) / 256;
    if (b > 65535) b = 65535;
    if (b < 1) b = 1;
    return (unsigned)b;
}
static inline unsigned nblk_gather(long long nodes) {
    long long b = (nodes + 3) / 4;
    if (b > 65535) b = 65535;
    if (b < 1) b = 1;
    return (unsigned)b;
}

extern "C" void kernel_launch(void* const* d_in, const int* in_sizes, int n_in,
                              void* d_out, int out_size, void* d_ws, size_t ws_size,
                              hipStream_t stream) {
    const float* lig_x = (const float*)d_in[0];
    const int* lig_src = (const int*)d_in[1];
    const int* lig_dst = (const int*)d_in[2];
    const int* lig_gid = (const int*)d_in[3];
    const float* rec_x = (const float*)d_in[4];
    const int* rec_src = (const int*)d_in[5];
    const int* rec_dst = (const int*)d_in[6];
    const int* rec_gid = (const int*)d_in[7];
    const float* W1l = (const float*)d_in[8];
    const float* al1l = (const float*)d_in[9];
    const float* ar1l = (const float*)d_in[10];
    const float* b1l = (const float*)d_in[11];
    const float* W2l = (const float*)d_in[12];
    const float* al2l = (const float*)d_in[13];
    const float* ar2l = (const float*)d_in[14];
    const float* b2l = (const float*)d_in[15];
    const float* W1r = (const float*)d_in[16];
    const float* al1r = (const float*)d_in[17];
    const float* ar1r = (const float*)d_in[18];
    const float* b1r = (const float*)d_in[19];
    const float* W2r = (const float*)d_in[20];
    const float* al2r = (const float*)d_in[21];
    const float* ar2r = (const float*)d_in[22];
    const float* b2r = (const float*)d_in[23];
    const float* Wlin1 = (const float*)d_in[24];
    const float* blin1 = (const float*)d_in[25];
    const float* Wlin2 = (const float*)d_in[26];
    const float* blin2 = (const float*)d_in[27];

    int Nl = in_sizes[0] / 64, El = in_sizes[1];
    int Nr = in_sizes[4] / 64, Er = in_sizes[5];
    int Nc = Nl + Nr;
    int Ec = El + Er;

    // workspace layout (combined disjoint-union graph)
    char* ws = (char*)d_ws;
    float* xcat = (float*)ws;        ws += (size_t)Nc * 64 * 4;
    unsigned short* zb = (unsigned short*)ws;   ws += (size_t)Nc * 640 * 2;
    unsigned short* z2b = (unsigned short*)ws;  ws += (size_t)Nc * 64 * 2;
    float* h1 = (float*)ws;          ws += (size_t)Nc * 64 * 4;
    float* rst2 = (float*)ws;        ws += (size_t)Nc * 128 * 4;
    float* elb = (float*)ws;         ws += (size_t)Nc * 10 * 4;
    float* erb = (float*)ws;         ws += (size_t)Nc * 10 * 4;
    int* deg = (int*)ws;             ws += (size_t)Nc * 4;
    int* cursor = (int*)ws;          ws += (size_t)Nc * 4;
    int* rowptr = (int*)ws;          ws += (size_t)(Nc + 1) * 4;
    int* adj = (int*)ws;             ws += (size_t)Ec * 4;
    int* dslot = (int*)ws;           ws += (size_t)Ec * 4;
    float* ebuf = (float*)ws;        ws += (size_t)Ec * 10 * 4;
    float* alpha = (float*)ws;       ws += (size_t)Ec * 10 * 4;
    float* gm = (float*)ws;          ws += 2 * 8 * 32 * 128 * 4;
    int* gstart = (int*)ws;          ws += 66 * 4;
    int* bsum = (int*)ws;            ws += 64 * 4;
    float* walr1l = (float*)ws;      ws += 64 * 20 * 4;
    float* walr1r = (float*)ws;      ws += 64 * 20 * 4;
    float* walr2l = (float*)ws;      ws += 64 * 2 * 4;
    float* walr2r = (float*)ws;      ws += 64 * 2 * 4;
    unsigned short* wf1l = (unsigned short*)ws;  ws += 40960 * 2;
    unsigned short* wf1r = (unsigned short*)ws;  ws += 40960 * 2;
    unsigned short* wf2l = (unsigned short*)ws;  ws += 8192 * 2;
    unsigned short* wf2r = (unsigned short*)ws;  ws += 8192 * 2;
    unsigned short* wfa1l = (unsigned short*)ws; ws += 2048 * 2;
    unsigned short* wfa1r = (unsigned short*)ws; ws += 2048 * 2;
    unsigned short* wfa2l = (unsigned short*)ws; ws += 1024 * 2;
    unsigned short* wfa2r = (unsigned short*)ws; ws += 1024 * 2;

    int nb = (Nc + 2047) / 2048;

    // ---- weight prep (input-only deps) ----
    prep_wfrag<<<40, 256, 0, stream>>>(W1l, wf1l, 640);
    prep_wfrag<<<40, 256, 0, stream>>>(W1r, wf1r, 640);
    prep_wfrag<<<8, 256, 0, stream>>>(W2l, wf2l, 128);
    prep_wfrag<<<8, 256, 0, stream>>>(W2r, wf2r, 128);
    fold_attn<<<64, 64, 0, stream>>>(W1l, al1l, ar1l, walr1l, 10, 64);
    fold_attn<<<64, 64, 0, stream>>>(W1r, al1r, ar1r, walr1r, 10, 64);
    fold_attn<<<64, 64, 0, stream>>>(W2l, al2l, ar2l, walr2l, 1, 128);
    fold_attn<<<64, 64, 0, stream>>>(W2r, al2r, ar2r, walr2r, 1, 128);
    prep_walr<<<8, 256, 0, stream>>>(walr1l, wfa1l, 20);
    prep_walr<<<8, 256, 0, stream>>>(walr1r, wfa1r, 20);
    prep_walr<<<4, 256, 0, stream>>>(walr2l, wfa2l, 2);
    prep_walr<<<4, 256, 0, stream>>>(walr2r, wfa2r, 2);

    // ---- combined CSR + graph boundaries ----
    copy_x2<<<nblk_elem((long long)Nc * 16), 256, 0, stream>>>(
        (const float4*)lig_x, Nl * 16, (const float4*)rec_x, Nr * 16, (float4*)xcat);
    hipMemsetAsync(deg, 0, (size_t)Nc * 4, stream);
    count_deg2<<<nblk_elem(Ec), 256, 0, stream>>>(lig_dst, rec_dst, deg, El, Er, Nl);
    scan_local<<<nb, 256, 0, stream>>>(deg, rowptr, bsum, Nc);
    scan_bsum<<<1, 64, 0, stream>>>(bsum, rowptr + Nc, nb);
    scan_add<<<nb, 256, 0, stream>>>(rowptr, bsum, Nc);
    hipMemcpyAsync(cursor, rowptr, (size_t)Nc * 4, hipMemcpyDeviceToDevice, stream);
    fill_adj2<<<nblk_elem(Ec), 256, 0, stream>>>(lig_src, lig_dst, rec_src, rec_dst,
                                                 cursor, adj, dslot, El, Er, Nl);
    gstart_build2<<<nblk_elem(Nc), 256, 0, stream>>>(lig_gid, rec_gid, gstart, Nl, Nr);

    // ---- layer 1: H=10 ----
    attn_mfma<10><<<(Nl + 63) / 64, 256, 0, stream>>>(xcat, (const bf16x8*)wfa1l,
                                                      elb, erb, Nl);
    attn_mfma<10><<<(Nr + 63) / 64, 256, 0, stream>>>(xcat + (size_t)Nl * 64,
                                                      (const bf16x8*)wfa1r,
                                                      elb + (size_t)Nl * 10,
                                                      erb + (size_t)Nl * 10, Nr);
    edge_e<10><<<nblk_elem(Ec), 256, 0, stream>>>(adj, dslot, elb, erb, ebuf, Ec);
    node_norm<10><<<nblk_elem(Nc), 256, 0, stream>>>(rowptr, ebuf, alpha, Nc);
    gather_z_b<10><<<nblk_gather(Nc), 256, 0, stream>>>(rowptr, adj, alpha, xcat, zb, Nc);
    gemm_heads_mfma_b<10><<<(Nl + 63) / 64, 256, 0, stream>>>(zb, (const bf16x8*)wf1l,
                                                              b1l, h1, Nl);
    gemm_heads_mfma_b<10><<<(Nr + 63) / 64, 256, 0, stream>>>(zb + (size_t)Nl * 640,
                                                              (const bf16x8*)wf1r, b1r,
                                                              h1 + (size_t)Nl * 64, Nr);

    // ---- layer 2: H=1 ----
    attn_mfma<1><<<(Nl + 63) / 64, 256, 0, stream>>>(h1, (const bf16x8*)wfa2l,
                                                     elb, erb, Nl);
    attn_mfma<1><<<(Nr + 63) / 64, 256, 0, stream>>>(h1 + (size_t)Nl * 64,
                                                     (const bf16x8*)wfa2r,
                                                     elb + Nl, erb + Nl, Nr);
    edge_e<1><<<nblk_elem(Ec), 256, 0, stream>>>(adj, dslot, elb, erb, ebuf, Ec);
    node_norm<1><<<nblk_elem(Nc), 256, 0, stream>>>(rowptr, ebuf, alpha, Nc);
    gather_z_b<1><<<nblk_gather(Nc), 256, 0, stream>>>(rowptr, adj, alpha, h1, z2b, Nc);
    gemm_relu_mfma_b<<<(Nl + 63) / 64, 256, 0, stream>>>(z2b, (const bf16x8*)wf2l,
                                                         b2l, rst2, Nl);
    gemm_relu_mfma_b<<<(Nr + 63) / 64, 256, 0, stream>>>(z2b + (size_t)Nl * 64,
                                                         (const bf16x8*)wf2r, b2r,
                                                         rst2 + (size_t)Nl * 128, Nr);
    graph_max2<<<dim3(64, 8), 128, 0, stream>>>(rst2, gstart, gm);
    mlp_head2<<<32, 256, 0, stream>>>(gm, gm + 8 * 32 * 128, Wlin1, blin1, Wlin2, blin2,
                                      (float*)d_out);
}

// Round 16
// 351.857 us; speedup vs baseline: 1.6618x; 1.0138x over previous
//
#include <hip/hip_runtime.h>
#include <hip/hip_bf16.h>

typedef short bf16x8 __attribute__((ext_vector_type(8)));
typedef float f32x4 __attribute__((ext_vector_type(4)));

__device__ inline float lrelu(float x) { return x > 0.f ? x : 0.2f * x; }

// fp32 -> bf16 (round-to-nearest-even)
__device__ inline unsigned short f2bf(float f) {
    unsigned u = __float_as_uint(f);
    u = u + 0x7FFFu + ((u >> 16) & 1u);
    return (unsigned short)(u >> 16);
}

// ---------- concat lig_x and rec_x into xcat ----------
__global__ void copy_x2(const float4* __restrict__ a, int na4,
                        const float4* __restrict__ b, int nb4, float4* __restrict__ o) {
    int total = na4 + nb4;
    int stride = gridDim.x * blockDim.x;
    for (int i = blockIdx.x * blockDim.x + threadIdx.x; i < total; i += stride)
        o[i] = (i < na4) ? a[i] : b[i - na4];
}

// ---------- fold attention vectors through W: Walr[k][2H] ----------
__global__ void fold_attn(const float* __restrict__ W, const float* __restrict__ al,
                          const float* __restrict__ ar, float* __restrict__ Walr,
                          int H, int D) {
    int k = blockIdx.x;
    int lane = threadIdx.x;
    int C = H * D;
    for (int h = 0; h < H; ++h) {
        float sl = 0.f, sr = 0.f;
        for (int d = lane; d < D; d += 64) {
            float w = W[(size_t)k * C + h * D + d];
            sl += w * al[h * D + d];
            sr += w * ar[h * D + d];
        }
        for (int off = 32; off; off >>= 1) {
            sl += __shfl_down(sl, off);
            sr += __shfl_down(sr, off);
        }
        if (lane == 0) {
            Walr[k * 2 * H + h] = sl;
            Walr[k * 2 * H + H + h] = sr;
        }
    }
}

// ---------- pack Walr[64][C2] into bf16 MFMA B-fragments, zero-pad cols to 16 ----------
__global__ void prep_walr(const float* __restrict__ Walr, unsigned short* __restrict__ F,
                          int C2) {
    int NCT = (C2 + 15) / 16;
    int total = NCT * 1024;
    int stride = gridDim.x * blockDim.x;
    for (int idx = blockIdx.x * blockDim.x + threadIdx.x; idx < total; idx += stride) {
        int j = idx & 7;
        int lane = (idx >> 3) & 63;
        int step = (idx >> 9) & 1;
        int CT = idx >> 10;
        int k = ((lane >> 4) << 3) + j + (step << 5);
        int col = (CT << 4) + (lane & 15);
        F[idx] = (col < C2) ? f2bf(Walr[k * C2 + col]) : 0;
    }
}

// ---------- el/er via MFMA: x[N,64] @ Walr[64,2H] ----------
template <int H>
__global__ __launch_bounds__(256) void attn_mfma(const float* __restrict__ x,
                                                 const bf16x8* __restrict__ Wf,
                                                 float* __restrict__ el,
                                                 float* __restrict__ er, int N) {
    const int NCT = (2 * H + 15) / 16;
    int lane = threadIdx.x & 63;
    int w = threadIdx.x >> 6;
    int row0 = blockIdx.x * 64 + w * 16;
    int arow = row0 + (lane & 15);
    if (arow > N - 1) arow = N - 1;
    int kb = (lane >> 4) * 8;
    int colL = lane & 15;

    const float* xr = x + (size_t)arow * 64 + kb;
    float4 a0 = *reinterpret_cast<const float4*>(xr);
    float4 a1 = *reinterpret_cast<const float4*>(xr + 4);
    float4 a2 = *reinterpret_cast<const float4*>(xr + 32);
    float4 a3 = *reinterpret_cast<const float4*>(xr + 36);
    bf16x8 A0, A1;
    A0[0] = (short)f2bf(a0.x); A0[1] = (short)f2bf(a0.y);
    A0[2] = (short)f2bf(a0.z); A0[3] = (short)f2bf(a0.w);
    A0[4] = (short)f2bf(a1.x); A0[5] = (short)f2bf(a1.y);
    A0[6] = (short)f2bf(a1.z); A0[7] = (short)f2bf(a1.w);
    A1[0] = (short)f2bf(a2.x); A1[1] = (short)f2bf(a2.y);
    A1[2] = (short)f2bf(a2.z); A1[3] = (short)f2bf(a2.w);
    A1[4] = (short)f2bf(a3.x); A1[5] = (short)f2bf(a3.y);
    A1[6] = (short)f2bf(a3.z); A1[7] = (short)f2bf(a3.w);

    int rbase = row0 + (lane >> 4) * 4;
#pragma unroll
    for (int ct = 0; ct < NCT; ++ct) {
        bf16x8 B0 = Wf[(ct * 2 + 0) * 64 + lane];
        bf16x8 B1 = Wf[(ct * 2 + 1) * 64 + lane];
        f32x4 acc = {0, 0, 0, 0};
        acc = __builtin_amdgcn_mfma_f32_16x16x32_bf16(A0, B0, acc, 0, 0, 0);
        acc = __builtin_amdgcn_mfma_f32_16x16x32_bf16(A1, B1, acc, 0, 0, 0);
        int col = ct * 16 + colL;
#pragma unroll
        for (int r = 0; r < 4; ++r) {
            int row = rbase + r;
            if (row < N) {
                if (col < H) el[(size_t)row * H + col] = acc[r];
                else if (col < 2 * H) er[(size_t)row * H + col - H] = acc[r];
            }
        }
    }
}

// ---------- CSR build over the DISJOINT UNION graph (rec ids offset by Nl) ----------
__global__ void count_deg2(const int* __restrict__ dl, const int* __restrict__ dr,
                           int* __restrict__ deg, int El, int Er, int Nl) {
    int total = El + Er;
    int stride = gridDim.x * blockDim.x;
    for (int i = blockIdx.x * blockDim.x + threadIdx.x; i < total; i += stride) {
        int d = (i < El) ? dl[i] : (dr[i - El] + Nl);
        atomicAdd(&deg[d], 1);
    }
}

__global__ __launch_bounds__(256) void scan_local(const int* __restrict__ deg,
                                                  int* __restrict__ rowptr,
                                                  int* __restrict__ bsum, int N) {
    __shared__ int wsum[4];
    int t = threadIdx.x;
    int base = blockIdx.x * 2048 + t * 8;
    int v[8];
    int s = 0;
#pragma unroll
    for (int i = 0; i < 8; ++i) {
        int idx = base + i;
        v[i] = (idx < N) ? deg[idx] : 0;
        s += v[i];
    }
    int lane = t & 63, w = t >> 6;
    int incl = s;
    for (int off = 1; off < 64; off <<= 1) {
        int o = __shfl_up(incl, off);
        if (lane >= off) incl += o;
    }
    if (lane == 63) wsum[w] = incl;
    __syncthreads();
    int woff = 0;
    for (int i = 0; i < w; ++i) woff += wsum[i];
    int run = woff + incl - s;
#pragma unroll
    for (int i = 0; i < 8; ++i) {
        int idx = base + i;
        if (idx < N) rowptr[idx] = run;
        run += v[i];
    }
    if (t == 255) bsum[blockIdx.x] = woff + incl;
}

__global__ void scan_bsum(int* __restrict__ bsum, int* __restrict__ rowptrN, int nb) {
    int t = threadIdx.x;  // 64 threads
    int v = (t < nb) ? bsum[t] : 0;
    int incl = v;
    for (int off = 1; off < 64; off <<= 1) {
        int o = __shfl_up(incl, off);
        if (t >= off) incl += o;
    }
    if (t < nb) bsum[t] = incl - v;
    if (t == 63) *rowptrN = incl;
}

__global__ __launch_bounds__(256) void scan_add(int* __restrict__ rowptr,
                                                const int* __restrict__ bsum, int N) {
    int off = bsum[blockIdx.x];
    if (off == 0) return;
    int base = blockIdx.x * 2048 + threadIdx.x * 8;
#pragma unroll
    for (int i = 0; i < 8; ++i) {
        int idx = base + i;
        if (idx < N) rowptr[idx] += off;
    }
}

// round-16: fill only adj (single 4B scatter per edge); dslot moved to a
// coalesced expand kernel (was: 2 scattered stores -> 11x write amplification).
__global__ void fill_adj2(const int* __restrict__ sl, const int* __restrict__ dl,
                          const int* __restrict__ sr, const int* __restrict__ dr,
                          int* __restrict__ cursor, int* __restrict__ adj,
                          int El, int Er, int Nl) {
    int total = El + Er;
    int stride = gridDim.x * blockDim.x;
    for (int i = blockIdx.x * blockDim.x + threadIdx.x; i < total; i += stride) {
        int s, d;
        if (i < El) { s = sl[i]; d = dl[i]; }
        else        { s = sr[i - El] + Nl; d = dr[i - El] + Nl; }
        int pos = atomicAdd(&cursor[d], 1);
        adj[pos] = s;
    }
}

// dslot[rowptr[n]..rowptr[n+1]) = n -- contiguous runs, near-coalesced writes.
__global__ __launch_bounds__(256) void dslot_expand(const int* __restrict__ rowptr,
                                                    int* __restrict__ dslot, int N) {
    int stride = gridDim.x * blockDim.x;
    for (int n = blockIdx.x * blockDim.x + threadIdx.x; n < N; n += stride) {
        int rb = rowptr[n], re = rowptr[n + 1];
        for (int j = rb; j < re; ++j) dslot[j] = n;
    }
}

// ---------- graph boundaries for both branches: gs[0..32]=lig, gs[33..65]=rec ----------
__global__ void gstart_build2(const int* __restrict__ gidL, const int* __restrict__ gidR,
                              int* __restrict__ gs, int Nl, int Nr) {
    int Nc = Nl + Nr;
    int stride = gridDim.x * blockDim.x;
    for (int n = blockIdx.x * blockDim.x + threadIdx.x; n < Nc; n += stride) {
        if (n < Nl) {
            int gcur = gidL[n];
            int gprev = (n == 0) ? -1 : gidL[n - 1];
            for (int g = gprev + 1; g <= gcur; ++g) gs[g] = n;
            if (n == Nl - 1)
                for (int g = gcur + 1; g <= 32; ++g) gs[g] = Nl;
        } else {
            int ln = n - Nl;
            int gcur = gidR[ln];
            int gprev = (ln == 0) ? -1 : gidR[ln - 1];
            for (int g = gprev + 1; g <= gcur; ++g) gs[33 + g] = n;
            if (ln == Nr - 1)
                for (int g = gcur + 1; g <= 32; ++g) gs[33 + g] = Nc;
        }
    }
}

// ---------- per-slot raw attention logits (combined edges) ----------
template <int H>
__global__ void edge_e(const int* __restrict__ adj, const int* __restrict__ dslot,
                       const float* __restrict__ el, const float* __restrict__ er,
                       float* __restrict__ e, int E) {
    int stride = gridDim.x * blockDim.x;
    for (int i = blockIdx.x * blockDim.x + threadIdx.x; i < E; i += stride) {
        int s = adj[i], d = dslot[i];
        const float* els = el + (size_t)s * H;
        const float* erd = er + (size_t)d * H;
#pragma unroll
        for (int h = 0; h < H; ++h)
            e[(size_t)i * H + h] = lrelu(els[h] + erd[h]);
    }
}

// ---------- per-node softmax normalize (combined nodes) ----------
template <int H>
__global__ void node_norm(const int* __restrict__ rowptr, const float* __restrict__ e,
                          float* __restrict__ alpha, int N) {
    int stride = gridDim.x * blockDim.x;
    for (int n = blockIdx.x * blockDim.x + threadIdx.x; n < N; n += stride) {
        int rbeg = rowptr[n], rend = rowptr[n + 1];
        if (rbeg == rend) continue;
        float m[H], den[H];
#pragma unroll
        for (int h = 0; h < H; ++h) { m[h] = -INFINITY; den[h] = 0.f; }
        for (int j = rbeg; j < rend; ++j) {
#pragma unroll
            for (int h = 0; h < H; ++h) {
                float ev = e[(size_t)j * H + h];
                float newm = fmaxf(m[h], ev);
                den[h] = den[h] * __expf(m[h] - newm) + __expf(ev - newm);
                m[h] = newm;
            }
        }
        float inv[H];
#pragma unroll
        for (int h = 0; h < H; ++h) inv[h] = 1.f / fmaxf(den[h], 1e-9f);
        for (int j = rbeg; j < rend; ++j) {
#pragma unroll
            for (int h = 0; h < H; ++h)
                alpha[(size_t)j * H + h] = __expf(e[(size_t)j * H + h] - m[h]) * inv[h];
        }
    }
}

// ---------- gather x rows weighted by alpha; z stored bf16 ----------
template <int H>
__global__ __launch_bounds__(256, 8) void gather_z_b(
        const int* __restrict__ rowptr, const int* __restrict__ adj,
        const float* __restrict__ alpha, const float* __restrict__ x,
        unsigned short* __restrict__ z, int N) {
    int lane = threadIdx.x & 63;
    int w = threadIdx.x >> 6;
    int wpb = blockDim.x >> 6;
    int wstride = gridDim.x * wpb;
    for (int n = blockIdx.x * wpb + w; n < N; n += wstride) {
        int rbeg = __builtin_amdgcn_readfirstlane(rowptr[n]);
        int rend = __builtin_amdgcn_readfirstlane(rowptr[n + 1]);
        float acc[H];
#pragma unroll
        for (int h = 0; h < H; ++h) acc[h] = 0.f;
        for (int base = rbeg; base < rend; base += 64) {
            int cnt = rend - base; if (cnt > 64) cnt = 64;
            int sv = adj[base + ((lane < cnt) ? lane : 0)];
            int j = 0;
            for (; j + 4 <= cnt; j += 4) {
                int s0 = __shfl(sv, j);
                int s1 = __shfl(sv, j + 1);
                int s2 = __shfl(sv, j + 2);
                int s3 = __shfl(sv, j + 3);
                float x0 = x[(size_t)s0 * 64 + lane];
                float x1 = x[(size_t)s1 * 64 + lane];
                float x2 = x[(size_t)s2 * 64 + lane];
                float x3 = x[(size_t)s3 * 64 + lane];
                const float* a0 = alpha + (size_t)(base + j) * H;
                const float* a1 = a0 + H;
                const float* a2 = a1 + H;
                const float* a3 = a2 + H;
#pragma unroll
                for (int h = 0; h < H; ++h)
                    acc[h] += a0[h] * x0 + a1[h] * x1 + a2[h] * x2 + a3[h] * x3;
            }
            for (; j < cnt; ++j) {
                int s = __shfl(sv, j);
                float xv = x[(size_t)s * 64 + lane];
                const float* al = alpha + (size_t)(base + j) * H;
#pragma unroll
                for (int h = 0; h < H; ++h) acc[h] += al[h] * xv;
            }
        }
#pragma unroll
        for (int h = 0; h < H; ++h)
            z[(size_t)n * (H * 64) + h * 64 + lane] = f2bf(acc[h]);
    }
}

// ---------- pack W[64][C] into per-lane bf16 MFMA B-fragments ----------
__global__ void prep_wfrag(const float* __restrict__ W, unsigned short* __restrict__ F,
                           int C) {
    int total = (C >> 4) * 1024;
    int stride = gridDim.x * blockDim.x;
    for (int idx = blockIdx.x * blockDim.x + threadIdx.x; idx < total; idx += stride) {
        int j = idx & 7;
        int lane = (idx >> 3) & 63;
        int step = (idx >> 9) & 1;
        int CT = idx >> 10;
        int k = ((lane >> 4) << 3) + j + (step << 5);
        int col = (CT << 4) + (lane & 15);
        F[idx] = f2bf(W[(size_t)k * C + col]);
    }
}

// ---------- MFMA per-head projection + relu + head-sum, bf16 A ----------
template <int H>
__global__ __launch_bounds__(256) void gemm_heads_mfma_b(
        const unsigned short* __restrict__ z, const bf16x8* __restrict__ Wf,
        const float* __restrict__ bias, float* __restrict__ out, int N) {
    const int SA = H * 64;
    int lane = threadIdx.x & 63;
    int w = threadIdx.x >> 6;
    int row0 = blockIdx.x * 64 + w * 16;
    int arow = row0 + (lane & 15);
    if (arow > N - 1) arow = N - 1;
    int kb = (lane >> 4) * 8;
    int colL = lane & 15;

    f32x4 o0 = {0,0,0,0}, o1 = {0,0,0,0}, o2 = {0,0,0,0}, o3 = {0,0,0,0};

    for (int h = 0; h < H; ++h) {
        const unsigned short* zr = z + (size_t)arow * SA + h * 64 + kb;
        bf16x8 A0 = *reinterpret_cast<const bf16x8*>(zr);
        bf16x8 A1 = *reinterpret_cast<const bf16x8*>(zr + 32);

        f32x4 acc0 = {0,0,0,0}, acc1 = {0,0,0,0}, acc2 = {0,0,0,0}, acc3 = {0,0,0,0};
#define CT_STEP(accv, ct)                                                            \
        {                                                                            \
            bf16x8 B0 = Wf[((h * 4 + (ct)) * 2 + 0) * 64 + lane];                    \
            bf16x8 B1 = Wf[((h * 4 + (ct)) * 2 + 1) * 64 + lane];                    \
            accv = __builtin_amdgcn_mfma_f32_16x16x32_bf16(A0, B0, accv, 0, 0, 0);   \
            accv = __builtin_amdgcn_mfma_f32_16x16x32_bf16(A1, B1, accv, 0, 0, 0);   \
        }
        CT_STEP(acc0, 0) CT_STEP(acc1, 1) CT_STEP(acc2, 2) CT_STEP(acc3, 3)
#undef CT_STEP

#define EPI(ov, accv, ct)                                                            \
        {                                                                            \
            float bv = bias[h * 64 + (ct) * 16 + colL];                              \
            ov[0] += fmaxf(accv[0] + bv, 0.f);                                       \
            ov[1] += fmaxf(accv[1] + bv, 0.f);                                       \
            ov[2] += fmaxf(accv[2] + bv, 0.f);                                       \
            ov[3] += fmaxf(accv[3] + bv, 0.f);                                       \
        }
        EPI(o0, acc0, 0) EPI(o1, acc1, 1) EPI(o2, acc2, 2) EPI(o3, acc3, 3)
#undef EPI
    }

    int rbase = row0 + (lane >> 4) * 4;
#define ST(ov, ct)                                                                   \
    {                                                                                \
        _Pragma("unroll")                                                            \
        for (int r = 0; r < 4; ++r) {                                                \
            int row = rbase + r;                                                     \
            if (row < N) out[(size_t)row * 64 + (ct) * 16 + colL] = ov[r];           \
        }                                                                            \
    }
    ST(o0, 0) ST(o1, 1) ST(o2, 2) ST(o3, 3)
#undef ST
}

// ---------- MFMA layer-2 GEMM, bf16 A: rst2 = relu(z2[N,64] @ W2 + bias) ----------
__global__ __launch_bounds__(256) void gemm_relu_mfma_b(
        const unsigned short* __restrict__ z, const bf16x8* __restrict__ Wf,
        const float* __restrict__ bias, float* __restrict__ out, int N) {
    int lane = threadIdx.x & 63;
    int w = threadIdx.x >> 6;
    int row0 = blockIdx.x * 64 + w * 16;
    int arow = row0 + (lane & 15);
    if (arow > N - 1) arow = N - 1;
    int kb = (lane >> 4) * 8;
    int colL = lane & 15;

    const unsigned short* zr = z + (size_t)arow * 64 + kb;
    bf16x8 A0 = *reinterpret_cast<const bf16x8*>(zr);
    bf16x8 A1 = *reinterpret_cast<const bf16x8*>(zr + 32);

    int rbase = row0 + (lane >> 4) * 4;
#define DO_CT(ct)                                                                    \
    {                                                                                \
        bf16x8 B0 = Wf[((ct) * 2 + 0) * 64 + lane];                                  \
        bf16x8 B1 = Wf[((ct) * 2 + 1) * 64 + lane];                                  \
        f32x4 acc = {0, 0, 0, 0};                                                    \
        acc = __builtin_amdgcn_mfma_f32_16x16x32_bf16(A0, B0, acc, 0, 0, 0);         \
        acc = __builtin_amdgcn_mfma_f32_16x16x32_bf16(A1, B1, acc, 0, 0, 0);         \
        float bv = bias[(ct) * 16 + colL];                                           \
        _Pragma("unroll")                                                            \
        for (int r = 0; r < 4; ++r) {                                                \
            int row = rbase + r;                                                     \
            if (row < N)                                                             \
                out[(size_t)row * 128 + (ct) * 16 + colL] = fmaxf(acc[r] + bv, 0.f); \
        }                                                                            \
    }
    DO_CT(0) DO_CT(1) DO_CT(2) DO_CT(3) DO_CT(4) DO_CT(5) DO_CT(6) DO_CT(7)
#undef DO_CT
}

// ---------- per-graph column max, both branches: grid (64 graphs, 8 splits) ----------
__global__ __launch_bounds__(128) void graph_max2(const float* __restrict__ rst2,
                                                  const int* __restrict__ gstart,
                                                  float* __restrict__ gm) {
    int g = blockIdx.x;            // 0..63
    int b = g >> 5, gl = g & 31;
    int sp = blockIdx.y;
    int t = threadIdx.x;
    const int* gs = gstart + 33 * b;
    int rb = gs[gl], re = gs[gl + 1];
    float m = -INFINITY;
    for (int r = rb + sp; r < re; r += 8)
        m = fmaxf(m, rst2[(size_t)r * 128 + t]);
    gm[(size_t)((b * 8 + sp) * 32 + gl) * 128 + t] = m;
}

// ---------- head MLP: one block per graph ----------
__global__ __launch_bounds__(256) void mlp_head2(
        const float* __restrict__ gml, const float* __restrict__ gmr,
        const float* __restrict__ W1, const float* __restrict__ b1,
        const float* __restrict__ W2, const float* __restrict__ b2,
        float* __restrict__ out) {
    __shared__ float hcat[256];
    __shared__ float part[256];
    __shared__ float h[128];
    int g = blockIdx.x;
    int t = threadIdx.x;
    {
        const float* gsrc = (t < 128) ? gml : gmr;
        int c = t & 127;
        float m = -INFINITY;
#pragma unroll
        for (int sp = 0; sp < 8; ++sp) m = fmaxf(m, gsrc[sp * 4096 + g * 128 + c]);
        hcat[t < 128 ? c : 128 + c] = fmaxf(m, 0.f);
    }
    __syncthreads();
    {
        int c = t & 127;
        int k0 = (t >> 7) << 7;
        float acc = 0.f;
#pragma unroll 4
        for (int k = 0; k < 128; ++k)
            acc += hcat[k0 + k] * W1[(size_t)(k0 + k) * 128 + c];
        part[t] = acc;
    }
    __syncthreads();
    if (t < 128) h[t] = fmaxf(part[t] + part[t + 128] + b1[t], 0.f);
    __syncthreads();
    if (t < 128) {
        float v = h[t] * W2[t];
        for (int off = 32; off; off >>= 1) v += __shfl_down(v, off);
        if ((t & 63) == 0) part[t >> 6] = v;
    }
    __syncthreads();
    if (t == 0) out[g] = fmaxf(part[0] + part[1] + b2[0], 0.f);
}

// ---------- launch ----------
static inline unsigned nblk_elem(long long total) {
    long long b = (total + 255) / 256;
    if (b > 65535) b = 65535;
    if (b < 1) b = 1;
    return (unsigned)b;
}
static inline unsigned nblk_gather(long long nodes) {
    long long b = (nodes + 3) / 4;
    if (b > 65535) b = 65535;
    if (b < 1) b = 1;
    return (unsigned)b;
}

extern "C" void kernel_launch(void* const* d_in, const int* in_sizes, int n_in,
                              void* d_out, int out_size, void* d_ws, size_t ws_size,
                              hipStream_t stream) {
    const float* lig_x = (const float*)d_in[0];
    const int* lig_src = (const int*)d_in[1];
    const int* lig_dst = (const int*)d_in[2];
    const int* lig_gid = (const int*)d_in[3];
    const float* rec_x = (const float*)d_in[4];
    const int* rec_src = (const int*)d_in[5];
    const int* rec_dst = (const int*)d_in[6];
    const int* rec_gid = (const int*)d_in[7];
    const float* W1l = (const float*)d_in[8];
    const float* al1l = (const float*)d_in[9];
    const float* ar1l = (const float*)d_in[10];
    const float* b1l = (const float*)d_in[11];
    const float* W2l = (const float*)d_in[12];
    const float* al2l = (const float*)d_in[13];
    const float* ar2l = (const float*)d_in[14];
    const float* b2l = (const float*)d_in[15];
    const float* W1r = (const float*)d_in[16];
    const float* al1r = (const float*)d_in[17];
    const float* ar1r = (const float*)d_in[18];
    const float* b1r = (const float*)d_in[19];
    const float* W2r = (const float*)d_in[20];
    const float* al2r = (const float*)d_in[21];
    const float* ar2r = (const float*)d_in[22];
    const float* b2r = (const float*)d_in[23];
    const float* Wlin1 = (const float*)d_in[24];
    const float* blin1 = (const float*)d_in[25];
    const float* Wlin2 = (const float*)d_in[26];
    const float* blin2 = (const float*)d_in[27];

    int Nl = in_sizes[0] / 64, El = in_sizes[1];
    int Nr = in_sizes[4] / 64, Er = in_sizes[5];
    int Nc = Nl + Nr;
    int Ec = El + Er;

    // workspace layout (combined disjoint-union graph)
    char* ws = (char*)d_ws;
    float* xcat = (float*)ws;        ws += (size_t)Nc * 64 * 4;
    unsigned short* zb = (unsigned short*)ws;   ws += (size_t)Nc * 640 * 2;
    unsigned short* z2b = (unsigned short*)ws;  ws += (size_t)Nc * 64 * 2;
    float* h1 = (float*)ws;          ws += (size_t)Nc * 64 * 4;
    float* rst2 = (float*)ws;        ws += (size_t)Nc * 128 * 4;
    float* elb = (float*)ws;         ws += (size_t)Nc * 10 * 4;
    float* erb = (float*)ws;         ws += (size_t)Nc * 10 * 4;
    int* deg = (int*)ws;             ws += (size_t)Nc * 4;
    int* cursor = (int*)ws;          ws += (size_t)Nc * 4;
    int* rowptr = (int*)ws;          ws += (size_t)(Nc + 1) * 4;
    int* adj = (int*)ws;             ws += (size_t)Ec * 4;
    int* dslot = (int*)ws;           ws += (size_t)Ec * 4;
    float* ebuf = (float*)ws;        ws += (size_t)Ec * 10 * 4;
    float* alpha = (float*)ws;       ws += (size_t)Ec * 10 * 4;
    float* gm = (float*)ws;          ws += 2 * 8 * 32 * 128 * 4;
    int* gstart = (int*)ws;          ws += 66 * 4;
    int* bsum = (int*)ws;            ws += 64 * 4;
    float* walr1l = (float*)ws;      ws += 64 * 20 * 4;
    float* walr1r = (float*)ws;      ws += 64 * 20 * 4;
    float* walr2l = (float*)ws;      ws += 64 * 2 * 4;
    float* walr2r = (float*)ws;      ws += 64 * 2 * 4;
    unsigned short* wf1l = (unsigned short*)ws;  ws += 40960 * 2;
    unsigned short* wf1r = (unsigned short*)ws;  ws += 40960 * 2;
    unsigned short* wf2l = (unsigned short*)ws;  ws += 8192 * 2;
    unsigned short* wf2r = (unsigned short*)ws;  ws += 8192 * 2;
    unsigned short* wfa1l = (unsigned short*)ws; ws += 2048 * 2;
    unsigned short* wfa1r = (unsigned short*)ws; ws += 2048 * 2;
    unsigned short* wfa2l = (unsigned short*)ws; ws += 1024 * 2;
    unsigned short* wfa2r = (unsigned short*)ws; ws += 1024 * 2;

    int nb = (Nc + 2047) / 2048;

    // ---- weight prep (input-only deps) ----
    prep_wfrag<<<40, 256, 0, stream>>>(W1l, wf1l, 640);
    prep_wfrag<<<40, 256, 0, stream>>>(W1r, wf1r, 640);
    prep_wfrag<<<8, 256, 0, stream>>>(W2l, wf2l, 128);
    prep_wfrag<<<8, 256, 0, stream>>>(W2r, wf2r, 128);
    fold_attn<<<64, 64, 0, stream>>>(W1l, al1l, ar1l, walr1l, 10, 64);
    fold_attn<<<64, 64, 0, stream>>>(W1r, al1r, ar1r, walr1r, 10, 64);
    fold_attn<<<64, 64, 0, stream>>>(W2l, al2l, ar2l, walr2l, 1, 128);
    fold_attn<<<64, 64, 0, stream>>>(W2r, al2r, ar2r, walr2r, 1, 128);
    prep_walr<<<8, 256, 0, stream>>>(walr1l, wfa1l, 20);
    prep_walr<<<8, 256, 0, stream>>>(walr1r, wfa1r, 20);
    prep_walr<<<4, 256, 0, stream>>>(walr2l, wfa2l, 2);
    prep_walr<<<4, 256, 0, stream>>>(walr2r, wfa2r, 2);

    // ---- combined CSR + graph boundaries ----
    copy_x2<<<nblk_elem((long long)Nc * 16), 256, 0, stream>>>(
        (const float4*)lig_x, Nl * 16, (const float4*)rec_x, Nr * 16, (float4*)xcat);
    hipMemsetAsync(deg, 0, (size_t)Nc * 4, stream);
    count_deg2<<<nblk_elem(Ec), 256, 0, stream>>>(lig_dst, rec_dst, deg, El, Er, Nl);
    scan_local<<<nb, 256, 0, stream>>>(deg, rowptr, bsum, Nc);
    scan_bsum<<<1, 64, 0, stream>>>(bsum, rowptr + Nc, nb);
    scan_add<<<nb, 256, 0, stream>>>(rowptr, bsum, Nc);
    hipMemcpyAsync(cursor, rowptr, (size_t)Nc * 4, hipMemcpyDeviceToDevice, stream);
    fill_adj2<<<nblk_elem(Ec), 256, 0, stream>>>(lig_src, lig_dst, rec_src, rec_dst,
                                                 cursor, adj, El, Er, Nl);
    dslot_expand<<<nblk_elem(Nc), 256, 0, stream>>>(rowptr, dslot, Nc);
    gstart_build2<<<nblk_elem(Nc), 256, 0, stream>>>(lig_gid, rec_gid, gstart, Nl, Nr);

    // ---- layer 1: H=10 ----
    attn_mfma<10><<<(Nl + 63) / 64, 256, 0, stream>>>(xcat, (const bf16x8*)wfa1l,
                                                      elb, erb, Nl);
    attn_mfma<10><<<(Nr + 63) / 64, 256, 0, stream>>>(xcat + (size_t)Nl * 64,
                                                      (const bf16x8*)wfa1r,
                                                      elb + (size_t)Nl * 10,
                                                      erb + (size_t)Nl * 10, Nr);
    edge_e<10><<<nblk_elem(Ec), 256, 0, stream>>>(adj, dslot, elb, erb, ebuf, Ec);
    node_norm<10><<<nblk_elem(Nc), 256, 0, stream>>>(rowptr, ebuf, alpha, Nc);
    gather_z_b<10><<<nblk_gather(Nc), 256, 0, stream>>>(rowptr, adj, alpha, xcat, zb, Nc);
    gemm_heads_mfma_b<10><<<(Nl + 63) / 64, 256, 0, stream>>>(zb, (const bf16x8*)wf1l,
                                                              b1l, h1, Nl);
    gemm_heads_mfma_b<10><<<(Nr + 63) / 64, 256, 0, stream>>>(zb + (size_t)Nl * 640,
                                                              (const bf16x8*)wf1r, b1r,
                                                              h1 + (size_t)Nl * 64, Nr);

    // ---- layer 2: H=1 ----
    attn_mfma<1><<<(Nl + 63) / 64, 256, 0, stream>>>(h1, (const bf16x8*)wfa2l,
                                                     elb, erb, Nl);
    attn_mfma<1><<<(Nr + 63) / 64, 256, 0, stream>>>(h1 + (size_t)Nl * 64,
                                                     (const bf16x8*)wfa2r,
                                                     elb + Nl, erb + Nl, Nr);
    edge_e<1><<<nblk_elem(Ec), 256, 0, stream>>>(adj, dslot, elb, erb, ebuf, Ec);
    node_norm<1><<<nblk_elem(Nc), 256, 0, stream>>>(rowptr, ebuf, alpha, Nc);
    gather_z_b<1><<<nblk_gather(Nc), 256, 0, stream>>>(rowptr, adj, alpha, h1, z2b, Nc);
    gemm_relu_mfma_b<<<(Nl + 63) / 64, 256, 0, stream>>>(z2b, (const bf16x8*)wf2l,
                                                         b2l, rst2, Nl);
    gemm_relu_mfma_b<<<(Nr + 63) / 64, 256, 0, stream>>>(z2b + (size_t)Nl * 64,
                                                         (const bf16x8*)wf2r, b2r,
                                                         rst2 + (size_t)Nl * 128, Nr);
    graph_max2<<<dim3(64, 8), 128, 0, stream>>>(rst2, gstart, gm);
    mlp_head2<<<32, 256, 0, stream>>>(gm, gm + 8 * 32 * 128, Wlin1, blin1, Wlin2, blin2,
                                      (float*)d_out);
}

// Round 17
// 301.307 us; speedup vs baseline: 1.9406x; 1.1678x over previous
//
#include <hip/hip_runtime.h>
#include <hip/hip_bf16.h>

typedef short bf16x8 __attribute__((ext_vector_type(8)));
typedef float f32x4 __attribute__((ext_vector_type(4)));

__device__ inline float lrelu(float x) { return x > 0.f ? x : 0.2f * x; }

// fp32 -> bf16 (round-to-nearest-even)
__device__ inline unsigned short f2bf(float f) {
    unsigned u = __float_as_uint(f);
    u = u + 0x7FFFu + ((u >> 16) & 1u);
    return (unsigned short)(u >> 16);
}

// ---------- merged init: concat x, zero deg, build gstart ----------
__global__ void init_misc(const float4* __restrict__ xl, int nl4,
                          const float4* __restrict__ xr, int nr4,
                          float4* __restrict__ xcat, int* __restrict__ deg,
                          const int* __restrict__ gidL, const int* __restrict__ gidR,
                          int* __restrict__ gs, int Nl, int Nr) {
    int Nc = Nl + Nr;
    int stride = gridDim.x * blockDim.x;
    int tid = blockIdx.x * blockDim.x + threadIdx.x;
    for (int i = tid; i < nl4 + nr4; i += stride)
        xcat[i] = (i < nl4) ? xl[i] : xr[i - nl4];
    for (int i = tid; i < Nc; i += stride) deg[i] = 0;
    for (int n = tid; n < Nc; n += stride) {
        if (n < Nl) {
            int gcur = gidL[n];
            int gprev = (n == 0) ? -1 : gidL[n - 1];
            for (int g = gprev + 1; g <= gcur; ++g) gs[g] = n;
            if (n == Nl - 1)
                for (int g = gcur + 1; g <= 32; ++g) gs[g] = Nl;
        } else {
            int ln = n - Nl;
            int gcur = gidR[ln];
            int gprev = (ln == 0) ? -1 : gidR[ln - 1];
            for (int g = gprev + 1; g <= gcur; ++g) gs[33 + g] = n;
            if (ln == Nr - 1)
                for (int g = gcur + 1; g <= 32; ++g) gs[33 + g] = Nc;
        }
    }
}

// ---------- merged fold_attn for all 4 weight sets: blockIdx.y = cfg ----------
__global__ void fold_all(const float* __restrict__ W1l, const float* __restrict__ al1l,
                         const float* __restrict__ ar1l, float* __restrict__ o1l,
                         const float* __restrict__ W1r, const float* __restrict__ al1r,
                         const float* __restrict__ ar1r, float* __restrict__ o1r,
                         const float* __restrict__ W2l, const float* __restrict__ al2l,
                         const float* __restrict__ ar2l, float* __restrict__ o2l,
                         const float* __restrict__ W2r, const float* __restrict__ al2r,
                         const float* __restrict__ ar2r, float* __restrict__ o2r) {
    const float *W, *al, *ar;
    float* o;
    int H, D;
    switch (blockIdx.y) {
        case 0: W = W1l; al = al1l; ar = ar1l; o = o1l; H = 10; D = 64; break;
        case 1: W = W1r; al = al1r; ar = ar1r; o = o1r; H = 10; D = 64; break;
        case 2: W = W2l; al = al2l; ar = ar2l; o = o2l; H = 1; D = 128; break;
        default: W = W2r; al = al2r; ar = ar2r; o = o2r; H = 1; D = 128; break;
    }
    int k = blockIdx.x;
    int lane = threadIdx.x;
    int C = H * D;
    for (int h = 0; h < H; ++h) {
        float sl = 0.f, sr = 0.f;
        for (int d = lane; d < D; d += 64) {
            float w = W[(size_t)k * C + h * D + d];
            sl += w * al[h * D + d];
            sr += w * ar[h * D + d];
        }
        for (int off = 32; off; off >>= 1) {
            sl += __shfl_down(sl, off);
            sr += __shfl_down(sr, off);
        }
        if (lane == 0) {
            o[k * 2 * H + h] = sl;
            o[k * 2 * H + H + h] = sr;
        }
    }
}

// ---------- merged prep_walr for all 4 sets ----------
__global__ void prep_walr_all(const float* __restrict__ w1l, const float* __restrict__ w1r,
                              const float* __restrict__ w2l, const float* __restrict__ w2r,
                              unsigned short* __restrict__ f1l, unsigned short* __restrict__ f1r,
                              unsigned short* __restrict__ f2l, unsigned short* __restrict__ f2r) {
    int stride = gridDim.x * blockDim.x;
    for (int idx0 = blockIdx.x * blockDim.x + threadIdx.x; idx0 < 6144; idx0 += stride) {
        const float* Walr;
        unsigned short* F;
        int C2, idx;
        if (idx0 < 2048)      { Walr = w1l; F = f1l; C2 = 20; idx = idx0; }
        else if (idx0 < 4096) { Walr = w1r; F = f1r; C2 = 20; idx = idx0 - 2048; }
        else if (idx0 < 5120) { Walr = w2l; F = f2l; C2 = 2;  idx = idx0 - 4096; }
        else                  { Walr = w2r; F = f2r; C2 = 2;  idx = idx0 - 5120; }
        int j = idx & 7;
        int lane = (idx >> 3) & 63;
        int step = (idx >> 9) & 1;
        int CT = idx >> 10;
        int k = ((lane >> 4) << 3) + j + (step << 5);
        int col = (CT << 4) + (lane & 15);
        F[idx] = (col < C2) ? f2bf(Walr[k * C2 + col]) : 0;
    }
}

// ---------- merged prep_wfrag for all 4 weight matrices ----------
__global__ void wfrag_all(const float* __restrict__ W1l, const float* __restrict__ W1r,
                          const float* __restrict__ W2l, const float* __restrict__ W2r,
                          unsigned short* __restrict__ f1l, unsigned short* __restrict__ f1r,
                          unsigned short* __restrict__ f2l, unsigned short* __restrict__ f2r) {
    int stride = gridDim.x * blockDim.x;
    for (int idx0 = blockIdx.x * blockDim.x + threadIdx.x; idx0 < 98304; idx0 += stride) {
        const float* W;
        unsigned short* F;
        int C, idx;
        if (idx0 < 40960)      { W = W1l; F = f1l; C = 640; idx = idx0; }
        else if (idx0 < 81920) { W = W1r; F = f1r; C = 640; idx = idx0 - 40960; }
        else if (idx0 < 90112) { W = W2l; F = f2l; C = 128; idx = idx0 - 81920; }
        else                   { W = W2r; F = f2r; C = 128; idx = idx0 - 90112; }
        int j = idx & 7;
        int lane = (idx >> 3) & 63;
        int step = (idx >> 9) & 1;
        int CT = idx >> 10;
        int k = ((lane >> 4) << 3) + j + (step << 5);
        int col = (CT << 4) + (lane & 15);
        F[idx] = f2bf(W[(size_t)k * C + col]);
    }
}

// ---------- el/er via MFMA, lig+rec merged (block split at nbl) ----------
template <int H>
__global__ __launch_bounds__(256) void attn_mfma2(const float* __restrict__ x,
                                                  const bf16x8* __restrict__ Wfl,
                                                  const bf16x8* __restrict__ Wfr,
                                                  float* __restrict__ el,
                                                  float* __restrict__ er,
                                                  int Nl, int Nc, int nbl) {
    const int NCT = (2 * H + 15) / 16;
    int lane = threadIdx.x & 63;
    int w = threadIdx.x >> 6;
    int b = blockIdx.x;
    const bf16x8* Wf;
    int row0, rend_;
    if (b < nbl) { Wf = Wfl; row0 = b * 64 + w * 16; rend_ = Nl; }
    else         { Wf = Wfr; row0 = Nl + (b - nbl) * 64 + w * 16; rend_ = Nc; }
    int arow = row0 + (lane & 15);
    if (arow > rend_ - 1) arow = rend_ - 1;
    int kb = (lane >> 4) * 8;
    int colL = lane & 15;

    const float* xr = x + (size_t)arow * 64 + kb;
    float4 a0 = *reinterpret_cast<const float4*>(xr);
    float4 a1 = *reinterpret_cast<const float4*>(xr + 4);
    float4 a2 = *reinterpret_cast<const float4*>(xr + 32);
    float4 a3 = *reinterpret_cast<const float4*>(xr + 36);
    bf16x8 A0, A1;
    A0[0] = (short)f2bf(a0.x); A0[1] = (short)f2bf(a0.y);
    A0[2] = (short)f2bf(a0.z); A0[3] = (short)f2bf(a0.w);
    A0[4] = (short)f2bf(a1.x); A0[5] = (short)f2bf(a1.y);
    A0[6] = (short)f2bf(a1.z); A0[7] = (short)f2bf(a1.w);
    A1[0] = (short)f2bf(a2.x); A1[1] = (short)f2bf(a2.y);
    A1[2] = (short)f2bf(a2.z); A1[3] = (short)f2bf(a2.w);
    A1[4] = (short)f2bf(a3.x); A1[5] = (short)f2bf(a3.y);
    A1[6] = (short)f2bf(a3.z); A1[7] = (short)f2bf(a3.w);

    int rbase = row0 + (lane >> 4) * 4;
#pragma unroll
    for (int ct = 0; ct < NCT; ++ct) {
        bf16x8 B0 = Wf[(ct * 2 + 0) * 64 + lane];
        bf16x8 B1 = Wf[(ct * 2 + 1) * 64 + lane];
        f32x4 acc = {0, 0, 0, 0};
        acc = __builtin_amdgcn_mfma_f32_16x16x32_bf16(A0, B0, acc, 0, 0, 0);
        acc = __builtin_amdgcn_mfma_f32_16x16x32_bf16(A1, B1, acc, 0, 0, 0);
        int col = ct * 16 + colL;
#pragma unroll
        for (int r = 0; r < 4; ++r) {
            int row = rbase + r;
            if (row < rend_) {
                if (col < H) el[(size_t)row * H + col] = acc[r];
                else if (col < 2 * H) er[(size_t)row * H + col - H] = acc[r];
            }
        }
    }
}

// ---------- CSR: count ----------
__global__ void count_deg2(const int* __restrict__ dl, const int* __restrict__ dr,
                           int* __restrict__ deg, int El, int Er, int Nl) {
    int total = El + Er;
    int stride = gridDim.x * blockDim.x;
    for (int i = blockIdx.x * blockDim.x + threadIdx.x; i < total; i += stride) {
        int d = (i < El) ? dl[i] : (dr[i - El] + Nl);
        atomicAdd(&deg[d], 1);
    }
}

__global__ __launch_bounds__(256) void scan_local(const int* __restrict__ deg,
                                                  int* __restrict__ rowptr,
                                                  int* __restrict__ bsum, int N) {
    __shared__ int wsum[4];
    int t = threadIdx.x;
    int base = blockIdx.x * 2048 + t * 8;
    int v[8];
    int s = 0;
#pragma unroll
    for (int i = 0; i < 8; ++i) {
        int idx = base + i;
        v[i] = (idx < N) ? deg[idx] : 0;
        s += v[i];
    }
    int lane = t & 63, w = t >> 6;
    int incl = s;
    for (int off = 1; off < 64; off <<= 1) {
        int o = __shfl_up(incl, off);
        if (lane >= off) incl += o;
    }
    if (lane == 63) wsum[w] = incl;
    __syncthreads();
    int woff = 0;
    for (int i = 0; i < w; ++i) woff += wsum[i];
    int run = woff + incl - s;
#pragma unroll
    for (int i = 0; i < 8; ++i) {
        int idx = base + i;
        if (idx < N) rowptr[idx] = run;
        run += v[i];
    }
    if (t == 255) bsum[blockIdx.x] = woff + incl;
}

__global__ void scan_bsum(int* __restrict__ bsum, int* __restrict__ rowptrN, int nb) {
    int t = threadIdx.x;  // 64 threads
    int v = (t < nb) ? bsum[t] : 0;
    int incl = v;
    for (int off = 1; off < 64; off <<= 1) {
        int o = __shfl_up(incl, off);
        if (t >= off) incl += o;
    }
    if (t < nb) bsum[t] = incl - v;
    if (t == 63) *rowptrN = incl;
}

// round-17: fused scan_add + cursor copy + dslot expand (3 dispatches -> 1)
__global__ __launch_bounds__(256) void scan_add_fused(int* __restrict__ rowptr,
                                                      const int* __restrict__ bsum,
                                                      const int* __restrict__ deg,
                                                      int* __restrict__ cursor,
                                                      int* __restrict__ dslot, int N) {
    int off = bsum[blockIdx.x];
    int base = blockIdx.x * 2048 + threadIdx.x * 8;
#pragma unroll
    for (int i = 0; i < 8; ++i) {
        int idx = base + i;
        if (idx < N) {
            int rp = rowptr[idx] + off;
            rowptr[idx] = rp;
            cursor[idx] = rp;
            int dg = deg[idx];
            for (int j = rp; j < rp + dg; ++j) dslot[j] = idx;
        }
    }
}

__global__ void fill_adj2(const int* __restrict__ sl, const int* __restrict__ dl,
                          const int* __restrict__ sr, const int* __restrict__ dr,
                          int* __restrict__ cursor, int* __restrict__ adj,
                          int El, int Er, int Nl) {
    int total = El + Er;
    int stride = gridDim.x * blockDim.x;
    for (int i = blockIdx.x * blockDim.x + threadIdx.x; i < total; i += stride) {
        int s, d;
        if (i < El) { s = sl[i]; d = dl[i]; }
        else        { s = sr[i - El] + Nl; d = dr[i - El] + Nl; }
        int pos = atomicAdd(&cursor[d], 1);
        adj[pos] = s;
    }
}

// ---------- per-slot raw attention logits ----------
template <int H>
__global__ void edge_e(const int* __restrict__ adj, const int* __restrict__ dslot,
                       const float* __restrict__ el, const float* __restrict__ er,
                       float* __restrict__ e, int E) {
    int stride = gridDim.x * blockDim.x;
    for (int i = blockIdx.x * blockDim.x + threadIdx.x; i < E; i += stride) {
        int s = adj[i], d = dslot[i];
        const float* els = el + (size_t)s * H;
        const float* erd = er + (size_t)d * H;
#pragma unroll
        for (int h = 0; h < H; ++h)
            e[(size_t)i * H + h] = lrelu(els[h] + erd[h]);
    }
}

// ---------- per-node softmax normalize ----------
template <int H>
__global__ void node_norm(const int* __restrict__ rowptr, const float* __restrict__ e,
                          float* __restrict__ alpha, int N) {
    int stride = gridDim.x * blockDim.x;
    for (int n = blockIdx.x * blockDim.x + threadIdx.x; n < N; n += stride) {
        int rbeg = rowptr[n], rend = rowptr[n + 1];
        if (rbeg == rend) continue;
        float m[H], den[H];
#pragma unroll
        for (int h = 0; h < H; ++h) { m[h] = -INFINITY; den[h] = 0.f; }
        for (int j = rbeg; j < rend; ++j) {
#pragma unroll
            for (int h = 0; h < H; ++h) {
                float ev = e[(size_t)j * H + h];
                float newm = fmaxf(m[h], ev);
                den[h] = den[h] * __expf(m[h] - newm) + __expf(ev - newm);
                m[h] = newm;
            }
        }
        float inv[H];
#pragma unroll
        for (int h = 0; h < H; ++h) inv[h] = 1.f / fmaxf(den[h], 1e-9f);
        for (int j = rbeg; j < rend; ++j) {
#pragma unroll
            for (int h = 0; h < H; ++h)
                alpha[(size_t)j * H + h] = __expf(e[(size_t)j * H + h] - m[h]) * inv[h];
        }
    }
}

// ---------- gather x rows weighted by alpha; z stored bf16 ----------
template <int H>
__global__ __launch_bounds__(256, 8) void gather_z_b(
        const int* __restrict__ rowptr, const int* __restrict__ adj,
        const float* __restrict__ alpha, const float* __restrict__ x,
        unsigned short* __restrict__ z, int N) {
    int lane = threadIdx.x & 63;
    int w = threadIdx.x >> 6;
    int wpb = blockDim.x >> 6;
    int wstride = gridDim.x * wpb;
    for (int n = blockIdx.x * wpb + w; n < N; n += wstride) {
        int rbeg = __builtin_amdgcn_readfirstlane(rowptr[n]);
        int rend = __builtin_amdgcn_readfirstlane(rowptr[n + 1]);
        float acc[H];
#pragma unroll
        for (int h = 0; h < H; ++h) acc[h] = 0.f;
        for (int base = rbeg; base < rend; base += 64) {
            int cnt = rend - base; if (cnt > 64) cnt = 64;
            int sv = adj[base + ((lane < cnt) ? lane : 0)];
            int j = 0;
            for (; j + 4 <= cnt; j += 4) {
                int s0 = __shfl(sv, j);
                int s1 = __shfl(sv, j + 1);
                int s2 = __shfl(sv, j + 2);
                int s3 = __shfl(sv, j + 3);
                float x0 = x[(size_t)s0 * 64 + lane];
                float x1 = x[(size_t)s1 * 64 + lane];
                float x2 = x[(size_t)s2 * 64 + lane];
                float x3 = x[(size_t)s3 * 64 + lane];
                const float* a0 = alpha + (size_t)(base + j) * H;
                const float* a1 = a0 + H;
                const float* a2 = a1 + H;
                const float* a3 = a2 + H;
#pragma unroll
                for (int h = 0; h < H; ++h)
                    acc[h] += a0[h] * x0 + a1[h] * x1 + a2[h] * x2 + a3[h] * x3;
            }
            for (; j < cnt; ++j) {
                int s = __shfl(sv, j);
                float xv = x[(size_t)s * 64 + lane];
                const float* al = alpha + (size_t)(base + j) * H;
#pragma unroll
                for (int h = 0; h < H; ++h) acc[h] += al[h] * xv;
            }
        }
#pragma unroll
        for (int h = 0; h < H; ++h)
            z[(size_t)n * (H * 64) + h * 64 + lane] = f2bf(acc[h]);
    }
}

// ---------- MFMA per-head projection + relu + head-sum, lig+rec merged ----------
template <int H>
__global__ __launch_bounds__(256) void gemm_heads2(
        const unsigned short* __restrict__ z, const bf16x8* __restrict__ Wfl,
        const bf16x8* __restrict__ Wfr, const float* __restrict__ bl,
        const float* __restrict__ br, float* __restrict__ out,
        int Nl, int Nc, int nbl) {
    const int SA = H * 64;
    int lane = threadIdx.x & 63;
    int w = threadIdx.x >> 6;
    int b = blockIdx.x;
    const bf16x8* Wf;
    const float* bias;
    int row0, rend_;
    if (b < nbl) { Wf = Wfl; bias = bl; row0 = b * 64 + w * 16; rend_ = Nl; }
    else         { Wf = Wfr; bias = br; row0 = Nl + (b - nbl) * 64 + w * 16; rend_ = Nc; }
    int arow = row0 + (lane & 15);
    if (arow > rend_ - 1) arow = rend_ - 1;
    int kb = (lane >> 4) * 8;
    int colL = lane & 15;

    f32x4 o0 = {0,0,0,0}, o1 = {0,0,0,0}, o2 = {0,0,0,0}, o3 = {0,0,0,0};

    for (int h = 0; h < H; ++h) {
        const unsigned short* zr = z + (size_t)arow * SA + h * 64 + kb;
        bf16x8 A0 = *reinterpret_cast<const bf16x8*>(zr);
        bf16x8 A1 = *reinterpret_cast<const bf16x8*>(zr + 32);

        f32x4 acc0 = {0,0,0,0}, acc1 = {0,0,0,0}, acc2 = {0,0,0,0}, acc3 = {0,0,0,0};
#define CT_STEP(accv, ct)                                                            \
        {                                                                            \
            bf16x8 B0 = Wf[((h * 4 + (ct)) * 2 + 0) * 64 + lane];                    \
            bf16x8 B1 = Wf[((h * 4 + (ct)) * 2 + 1) * 64 + lane];                    \
            accv = __builtin_amdgcn_mfma_f32_16x16x32_bf16(A0, B0, accv, 0, 0, 0);   \
            accv = __builtin_amdgcn_mfma_f32_16x16x32_bf16(A1, B1, accv, 0, 0, 0);   \
        }
        CT_STEP(acc0, 0) CT_STEP(acc1, 1) CT_STEP(acc2, 2) CT_STEP(acc3, 3)
#undef CT_STEP

#define EPI(ov, accv, ct)                                                            \
        {                                                                            \
            float bv = bias[h * 64 + (ct) * 16 + colL];                              \
            ov[0] += fmaxf(accv[0] + bv, 0.f);                                       \
            ov[1] += fmaxf(accv[1] + bv, 0.f);                                       \
            ov[2] += fmaxf(accv[2] + bv, 0.f);                                       \
            ov[3] += fmaxf(accv[3] + bv, 0.f);                                       \
        }
        EPI(o0, acc0, 0) EPI(o1, acc1, 1) EPI(o2, acc2, 2) EPI(o3, acc3, 3)
#undef EPI
    }

    int rbase = row0 + (lane >> 4) * 4;
#define ST(ov, ct)                                                                   \
    {                                                                                \
        _Pragma("unroll")                                                            \
        for (int r = 0; r < 4; ++r) {                                                \
            int row = rbase + r;                                                     \
            if (row < rend_) out[(size_t)row * 64 + (ct) * 16 + colL] = ov[r];       \
        }                                                                            \
    }
    ST(o0, 0) ST(o1, 1) ST(o2, 2) ST(o3, 3)
#undef ST
}

// ---------- MFMA layer-2 GEMM, lig+rec merged ----------
__global__ __launch_bounds__(256) void gemm_relu2(
        const unsigned short* __restrict__ z, const bf16x8* __restrict__ Wfl,
        const bf16x8* __restrict__ Wfr, const float* __restrict__ bl,
        const float* __restrict__ br, float* __restrict__ out,
        int Nl, int Nc, int nbl) {
    int lane = threadIdx.x & 63;
    int w = threadIdx.x >> 6;
    int b = blockIdx.x;
    const bf16x8* Wf;
    const float* bias;
    int row0, rend_;
    if (b < nbl) { Wf = Wfl; bias = bl; row0 = b * 64 + w * 16; rend_ = Nl; }
    else         { Wf = Wfr; bias = br; row0 = Nl + (b - nbl) * 64 + w * 16; rend_ = Nc; }
    int arow = row0 + (lane & 15);
    if (arow > rend_ - 1) arow = rend_ - 1;
    int kb = (lane >> 4) * 8;
    int colL = lane & 15;

    const unsigned short* zr = z + (size_t)arow * 64 + kb;
    bf16x8 A0 = *reinterpret_cast<const bf16x8*>(zr);
    bf16x8 A1 = *reinterpret_cast<const bf16x8*>(zr + 32);

    int rbase = row0 + (lane >> 4) * 4;
#define DO_CT(ct)                                                                    \
    {                                                                                \
        bf16x8 B0 = Wf[((ct) * 2 + 0) * 64 + lane];                                  \
        bf16x8 B1 = Wf[((ct) * 2 + 1) * 64 + lane];                                  \
        f32x4 acc = {0, 0, 0, 0};                                                    \
        acc = __builtin_amdgcn_mfma_f32_16x16x32_bf16(A0, B0, acc, 0, 0, 0);         \
        acc = __builtin_amdgcn_mfma_f32_16x16x32_bf16(A1, B1, acc, 0, 0, 0);         \
        float bv = bias[(ct) * 16 + colL];                                           \
        _Pragma("unroll")                                                            \
        for (int r = 0; r < 4; ++r) {                                                \
            int row = rbase + r;                                                     \
            if (row < rend_)                                                         \
                out[(size_t)row * 128 + (ct) * 16 + colL] = fmaxf(acc[r] + bv, 0.f); \
        }                                                                            \
    }
    DO_CT(0) DO_CT(1) DO_CT(2) DO_CT(3) DO_CT(4) DO_CT(5) DO_CT(6) DO_CT(7)
#undef DO_CT
}

// ---------- per-graph column max, both branches ----------
__global__ __launch_bounds__(128) void graph_max2(const float* __restrict__ rst2,
                                                  const int* __restrict__ gstart,
                                                  float* __restrict__ gm) {
    int g = blockIdx.x;            // 0..63
    int b = g >> 5, gl = g & 31;
    int sp = blockIdx.y;
    int t = threadIdx.x;
    const int* gs = gstart + 33 * b;
    int rb = gs[gl], re = gs[gl + 1];
    float m = -INFINITY;
    for (int r = rb + sp; r < re; r += 8)
        m = fmaxf(m, rst2[(size_t)r * 128 + t]);
    gm[(size_t)((b * 8 + sp) * 32 + gl) * 128 + t] = m;
}

// ---------- head MLP: one block per graph ----------
__global__ __launch_bounds__(256) void mlp_head2(
        const float* __restrict__ gml, const float* __restrict__ gmr,
        const float* __restrict__ W1, const float* __restrict__ b1,
        const float* __restrict__ W2, const float* __restrict__ b2,
        float* __restrict__ out) {
    __shared__ float hcat[256];
    __shared__ float part[256];
    __shared__ float h[128];
    int g = blockIdx.x;
    int t = threadIdx.x;
    {
        const float* gsrc = (t < 128) ? gml : gmr;
        int c = t & 127;
        float m = -INFINITY;
#pragma unroll
        for (int sp = 0; sp < 8; ++sp) m = fmaxf(m, gsrc[sp * 4096 + g * 128 + c]);
        hcat[t < 128 ? c : 128 + c] = fmaxf(m, 0.f);
    }
    __syncthreads();
    {
        int c = t & 127;
        int k0 = (t >> 7) << 7;
        float acc = 0.f;
#pragma unroll 4
        for (int k = 0; k < 128; ++k)
            acc += hcat[k0 + k] * W1[(size_t)(k0 + k) * 128 + c];
        part[t] = acc;
    }
    __syncthreads();
    if (t < 128) h[t] = fmaxf(part[t] + part[t + 128] + b1[t], 0.f);
    __syncthreads();
    if (t < 128) {
        float v = h[t] * W2[t];
        for (int off = 32; off; off >>= 1) v += __shfl_down(v, off);
        if ((t & 63) == 0) part[t >> 6] = v;
    }
    __syncthreads();
    if (t == 0) out[g] = fmaxf(part[0] + part[1] + b2[0], 0.f);
}

// ---------- launch ----------
static inline unsigned nblk_elem(long long total) {
    long long b = (total + 255) / 256;
    if (b > 65535) b = 65535;
    if (b < 1) b = 1;
    return (unsigned)b;
}
static inline unsigned nblk_gather(long long nodes) {
    long long b = (nodes + 3) / 4;
    if (b > 65535) b = 65535;
    if (b < 1) b = 1;
    return (unsigned)b;
}

extern "C" void kernel_launch(void* const* d_in, const int* in_sizes, int n_in,
                              void* d_out, int out_size, void* d_ws, size_t ws_size,
                              hipStream_t stream) {
    const float* lig_x = (const float*)d_in[0];
    const int* lig_src = (const int*)d_in[1];
    const int* lig_dst = (const int*)d_in[2];
    const int* lig_gid = (const int*)d_in[3];
    const float* rec_x = (const float*)d_in[4];
    const int* rec_src = (const int*)d_in[5];
    const int* rec_dst = (const int*)d_in[6];
    const int* rec_gid = (const int*)d_in[7];
    const float* W1l = (const float*)d_in[8];
    const float* al1l = (const float*)d_in[9];
    const float* ar1l = (const float*)d_in[10];
    const float* b1l = (const float*)d_in[11];
    const float* W2l = (const float*)d_in[12];
    const float* al2l = (const float*)d_in[13];
    const float* ar2l = (const float*)d_in[14];
    const float* b2l = (const float*)d_in[15];
    const float* W1r = (const float*)d_in[16];
    const float* al1r = (const float*)d_in[17];
    const float* ar1r = (const float*)d_in[18];
    const float* b1r = (const float*)d_in[19];
    const float* W2r = (const float*)d_in[20];
    const float* al2r = (const float*)d_in[21];
    const float* ar2r = (const float*)d_in[22];
    const float* b2r = (const float*)d_in[23];
    const float* Wlin1 = (const float*)d_in[24];
    const float* blin1 = (const float*)d_in[25];
    const float* Wlin2 = (const float*)d_in[26];
    const float* blin2 = (const float*)d_in[27];

    int Nl = in_sizes[0] / 64, El = in_sizes[1];
    int Nr = in_sizes[4] / 64, Er = in_sizes[5];
    int Nc = Nl + Nr;
    int Ec = El + Er;
    int nbl = (Nl + 63) / 64;
    int nbr = (Nr + 63) / 64;

    // workspace layout (combined disjoint-union graph)
    char* ws = (char*)d_ws;
    float* xcat = (float*)ws;        ws += (size_t)Nc * 64 * 4;
    unsigned short* zb = (unsigned short*)ws;   ws += (size_t)Nc * 640 * 2;
    unsigned short* z2b = (unsigned short*)ws;  ws += (size_t)Nc * 64 * 2;
    float* h1 = (float*)ws;          ws += (size_t)Nc * 64 * 4;
    float* rst2 = (float*)ws;        ws += (size_t)Nc * 128 * 4;
    float* elb = (float*)ws;         ws += (size_t)Nc * 10 * 4;
    float* erb = (float*)ws;         ws += (size_t)Nc * 10 * 4;
    int* deg = (int*)ws;             ws += (size_t)Nc * 4;
    int* cursor = (int*)ws;          ws += (size_t)Nc * 4;
    int* rowptr = (int*)ws;          ws += (size_t)(Nc + 1) * 4;
    int* adj = (int*)ws;             ws += (size_t)Ec * 4;
    int* dslot = (int*)ws;           ws += (size_t)Ec * 4;
    float* ebuf = (float*)ws;        ws += (size_t)Ec * 10 * 4;
    float* alpha = (float*)ws;       ws += (size_t)Ec * 10 * 4;
    float* gm = (float*)ws;          ws += 2 * 8 * 32 * 128 * 4;
    int* gstart = (int*)ws;          ws += 66 * 4;
    int* bsum = (int*)ws;            ws += 64 * 4;
    float* walr1l = (float*)ws;      ws += 64 * 20 * 4;
    float* walr1r = (float*)ws;      ws += 64 * 20 * 4;
    float* walr2l = (float*)ws;      ws += 64 * 2 * 4;
    float* walr2r = (float*)ws;      ws += 64 * 2 * 4;
    unsigned short* wf1l = (unsigned short*)ws;  ws += 40960 * 2;
    unsigned short* wf1r = (unsigned short*)ws;  ws += 40960 * 2;
    unsigned short* wf2l = (unsigned short*)ws;  ws += 8192 * 2;
    unsigned short* wf2r = (unsigned short*)ws;  ws += 8192 * 2;
    unsigned short* wfa1l = (unsigned short*)ws; ws += 2048 * 2;
    unsigned short* wfa1r = (unsigned short*)ws; ws += 2048 * 2;
    unsigned short* wfa2l = (unsigned short*)ws; ws += 1024 * 2;
    unsigned short* wfa2r = (unsigned short*)ws; ws += 1024 * 2;

    int nb = (Nc + 2047) / 2048;

    // ---- weight prep: 3 launches ----
    wfrag_all<<<96, 256, 0, stream>>>(W1l, W1r, W2l, W2r, wf1l, wf1r, wf2l, wf2r);
    fold_all<<<dim3(64, 4), 64, 0, stream>>>(W1l, al1l, ar1l, walr1l,
                                             W1r, al1r, ar1r, walr1r,
                                             W2l, al2l, ar2l, walr2l,
                                             W2r, al2r, ar2r, walr2r);
    prep_walr_all<<<24, 256, 0, stream>>>(walr1l, walr1r, walr2l, walr2r,
                                          wfa1l, wfa1r, wfa2l, wfa2r);

    // ---- combined CSR + graph boundaries: 6 launches ----
    init_misc<<<nblk_elem((long long)Nc * 16), 256, 0, stream>>>(
        (const float4*)lig_x, Nl * 16, (const float4*)rec_x, Nr * 16, (float4*)xcat,
        deg, lig_gid, rec_gid, gstart, Nl, Nr);
    count_deg2<<<nblk_elem(Ec), 256, 0, stream>>>(lig_dst, rec_dst, deg, El, Er, Nl);
    scan_local<<<nb, 256, 0, stream>>>(deg, rowptr, bsum, Nc);
    scan_bsum<<<1, 64, 0, stream>>>(bsum, rowptr + Nc, nb);
    scan_add_fused<<<nb, 256, 0, stream>>>(rowptr, bsum, deg, cursor, dslot, Nc);
    fill_adj2<<<nblk_elem(Ec), 256, 0, stream>>>(lig_src, lig_dst, rec_src, rec_dst,
                                                 cursor, adj, El, Er, Nl);

    // ---- layer 1: H=10 ----
    attn_mfma2<10><<<nbl + nbr, 256, 0, stream>>>(xcat, (const bf16x8*)wfa1l,
                                                  (const bf16x8*)wfa1r, elb, erb,
                                                  Nl, Nc, nbl);
    edge_e<10><<<nblk_elem(Ec), 256, 0, stream>>>(adj, dslot, elb, erb, ebuf, Ec);
    node_norm<10><<<nblk_elem(Nc), 256, 0, stream>>>(rowptr, ebuf, alpha, Nc);
    gather_z_b<10><<<nblk_gather(Nc), 256, 0, stream>>>(rowptr, adj, alpha, xcat, zb, Nc);
    gemm_heads2<10><<<nbl + nbr, 256, 0, stream>>>(zb, (const bf16x8*)wf1l,
                                                   (const bf16x8*)wf1r, b1l, b1r,
                                                   h1, Nl, Nc, nbl);

    // ---- layer 2: H=1 ----
    attn_mfma2<1><<<nbl + nbr, 256, 0, stream>>>(h1, (const bf16x8*)wfa2l,
                                                 (const bf16x8*)wfa2r, elb, erb,
                                                 Nl, Nc, nbl);
    edge_e<1><<<nblk_elem(Ec), 256, 0, stream>>>(adj, dslot, elb, erb, ebuf, Ec);
    node_norm<1><<<nblk_elem(Nc), 256, 0, stream>>>(rowptr, ebuf, alpha, Nc);
    gather_z_b<1><<<nblk_gather(Nc), 256, 0, stream>>>(rowptr, adj, alpha, h1, z2b, Nc);
    gemm_relu2<<<nbl + nbr, 256, 0, stream>>>(z2b, (const bf16x8*)wf2l,
                                              (const bf16x8*)wf2r, b2l, b2r,
                                              rst2, Nl, Nc, nbl);
    graph_max2<<<dim3(64, 8), 128, 0, stream>>>(rst2, gstart, gm);
    mlp_head2<<<32, 256, 0, stream>>>(gm, gm + 8 * 32 * 128, Wlin1, blin1, Wlin2, blin2,
                                      (float*)d_out);
}